// Round 8
// baseline (623.230 us; speedup 1.0000x reference)
//
#include <hip/hip_runtime.h>

namespace {
constexpr int kS   = 1024;
constexpr int kD   = 512;
constexpr int kH   = 8;
constexpr int kDFF = 2048;
constexpr int kNF  = 85;   // D//6
}

typedef __attribute__((ext_vector_type(8))) short bhalf8_t;    // 8x16-bit in 4 VGPRs
typedef _Float16 half8_t __attribute__((ext_vector_type(8)));
typedef __attribute__((ext_vector_type(4))) float f32x4_t;

// ---------------- helpers ----------------
__device__ __forceinline__ float wave_sum(float v) {
#pragma unroll
    for (int o = 1; o < 64; o <<= 1) v += __shfl_xor(v, o, 64);
    return v;
}
__device__ __forceinline__ unsigned short f2bf(float f) {   // RNE fp32->bf16
    unsigned u = __float_as_uint(f);
    u = (u + 0x7FFF + ((u >> 16) & 1)) >> 16;
    return (unsigned short)u;
}
__device__ __forceinline__ float bf2f(unsigned short h) {
    return __uint_as_float(((unsigned)h) << 16);
}
__device__ __forceinline__ unsigned short f2h(float f) {    // RNE fp32->fp16
    _Float16 h = (_Float16)f;
    return __builtin_bit_cast(unsigned short, h);
}

// ---------------- input projection + positional encoding ----------------
__global__ __launch_bounds__(256)
void input_pe_k(const float* __restrict__ feat, const float* __restrict__ pos,
                const float* __restrict__ fb, const float* __restrict__ in_w,
                const float* __restrict__ in_b, float* __restrict__ x)
{
    int s = blockIdx.x;
    int t = threadIdx.x;
    __shared__ float f[64];
    if (t < 64) f[t] = feat[s * 64 + t];
    __syncthreads();
    float acc0 = in_b[t], acc1 = in_b[t + 256];
#pragma unroll 8
    for (int c = 0; c < 64; ++c) {
        float fv = f[c];
        acc0 = fmaf(fv, in_w[c * kD + t], acc0);
        acc1 = fmaf(fv, in_w[c * kD + 256 + t], acc1);
    }
    float pe0 = 0.f, pe1 = 0.f;
    {
        int d = t;
        if (d < 6 * kNF) {
            int seg = d / kNF, idx = d - seg * kNF;
            float cs = pos[s * 3 + (seg >> 1)] * fb[idx];
            pe0 = (seg & 1) ? cosf(cs) : sinf(cs);
        }
        d = t + 256;
        if (d < 6 * kNF) {
            int seg = d / kNF, idx = d - seg * kNF;
            float cs = pos[s * 3 + (seg >> 1)] * fb[idx];
            pe1 = (seg & 1) ? cosf(cs) : sinf(cs);
        }
    }
    x[s * kD + t]       = acc0 + pe0;
    x[s * kD + 256 + t] = acc1 + pe1;
}

// ---------------- pairwise distance matrix ----------------
__global__ __launch_bounds__(256)
void dist_k(const float* __restrict__ pos, float* __restrict__ dist)
{
    int i = blockIdx.x;
    float px = pos[i * 3], py = pos[i * 3 + 1], pz = pos[i * 3 + 2];
    for (int j = threadIdx.x; j < kS; j += 256) {
        float dx = px - pos[j * 3], dy = py - pos[j * 3 + 1], dz = pz - pos[j * 3 + 2];
        float sq = dx * dx + dy * dy + dz * dz;
        dist[(long)i * kS + j] = sq > 0.f ? sqrtf(sq) : 0.f;
    }
}

// ---------------- exact PWL factorization of the distance-bias MLP ----------------
__global__ __launch_bounds__(256)
void pwl_build_k(const float* __restrict__ a_, const float* __restrict__ b_,
                 const float* __restrict__ w2, const float* __restrict__ b2,
                 float* __restrict__ bp_out, float* __restrict__ Atab, float* __restrict__ Btab)
{
    int l = blockIdx.x;
    a_ += l * 128; b_ += l * 128; w2 += l * 1024; b2 += l * 8;
    bp_out += l * 128; Atab += l * 1040; Btab += l * 1040;

    __shared__ float key[128], av[128], bv[128], sw2[1024], sb2[8];
    int t = threadIdx.x;
    for (int i = t; i < 1024; i += 256) sw2[i] = w2[i];
    if (t < 8) sb2[t] = b2[t];
    if (t < 128) {
        float a = a_[t], b = b_[t];
        av[t] = a; bv[t] = b;
        key[t] = (a != 0.f) ? (-b / a) : 3.0e38f;
    }
    __syncthreads();
    for (int ksz = 2; ksz <= 128; ksz <<= 1) {
        for (int j = ksz >> 1; j > 0; j >>= 1) {
            if (t < 128) {
                int ixj = t ^ j;
                if (ixj > t) {
                    bool up = ((t & ksz) == 0);
                    float x0 = key[t], x1 = key[ixj];
                    if ((x0 > x1) == up) { key[t] = x1; key[ixj] = x0; }
                }
            }
            __syncthreads();
        }
    }
    if (t < 128) bp_out[t] = key[t];
    __syncthreads();
    for (int task = t; task < 129 * 8; task += 256) {
        int seg = task >> 3, h = task & 7;
        float m;
        if (seg == 0)        m = key[0] - 1.0f;
        else if (seg == 128) m = key[127] + 1.0f;
        else                 m = 0.5f * (key[seg - 1] + key[seg]);
        float A = 0.f, B = 0.f;
        for (int c = 0; c < 128; ++c) {
            float a = av[c], b = bv[c];
            if (fmaf(a, m, b) > 0.f) {
                float w = sw2[c * 8 + h];
                A = fmaf(a, w, A);
                B = fmaf(b, w, B);
            }
        }
        Atab[seg * 8 + h] = A;
        Btab[seg * 8 + h] = B + sb2[h];
    }
}

// ---------------- fp32 -> bf16 3-term split, row-major (order0 [hi|lo|hi]) ------
__global__ __launch_bounds__(256)
void split3_rm_k(const float* __restrict__ in, unsigned short* __restrict__ out,
                 int total, int kshift, int ldin)
{
    long i = ((long)blockIdx.x * 256 + threadIdx.x) * 4;
    if (i >= total) return;
    int K = 1 << kshift;
    int m = (int)(i >> kshift), k = (int)(i & (K - 1));
    float4 v = *reinterpret_cast<const float4*>(in + (long)m * ldin + k);
    unsigned short h[4], lo[4];
    float fv[4] = {v.x, v.y, v.z, v.w};
#pragma unroll
    for (int j = 0; j < 4; ++j) {
        h[j] = f2bf(fv[j]);
        lo[j] = f2bf(fv[j] - bf2f(h[j]));
    }
    unsigned short* op = out + (long)m * (3 * K) + k;
    ushort4 hv = make_ushort4(h[0], h[1], h[2], h[3]);
    *reinterpret_cast<ushort4*>(op)         = hv;
    *reinterpret_cast<ushort4*>(op + K)     = make_ushort4(lo[0], lo[1], lo[2], lo[3]);
    *reinterpret_cast<ushort4*>(op + 2 * K) = hv;
}

// ---------------- fp32 K x N -> bf16 N x 3K transpose-split (weights, [hi|hi|lo]) --
__global__ __launch_bounds__(256)
void split3_tr_k(const float* __restrict__ in, unsigned short* __restrict__ out,
                 int K, int N, long szIn, long szOut)
{
    __shared__ float tile[32][33];
    int z = blockIdx.z;
    in  += (long)z * szIn;
    out += (long)z * szOut;
    int k0 = blockIdx.x * 32, n0 = blockIdx.y * 32;
    int t = threadIdx.x;
    int r = t >> 3, c4 = (t & 7) * 4;
    float4 v = *reinterpret_cast<const float4*>(&in[(long)(k0 + r) * N + n0 + c4]);
    tile[r][c4] = v.x; tile[r][c4 + 1] = v.y; tile[r][c4 + 2] = v.z; tile[r][c4 + 3] = v.w;
    __syncthreads();
    int nr = t >> 3, kq = (t & 7) * 4;
    unsigned short h[4], lo[4];
#pragma unroll
    for (int j = 0; j < 4; ++j) {
        float f = tile[kq + j][nr];
        h[j] = f2bf(f);
        lo[j] = f2bf(f - bf2f(h[j]));
    }
    unsigned short* op = out + (long)(n0 + nr) * (3 * K) + k0 + kq;
    ushort4 hv = make_ushort4(h[0], h[1], h[2], h[3]);
    *reinterpret_cast<ushort4*>(op)         = hv;
    *reinterpret_cast<ushort4*>(op + K)     = hv;
    *reinterpret_cast<ushort4*>(op + 2 * K) = make_ushort4(lo[0], lo[1], lo[2], lo[3]);
}

// ---------------- fp32 K x N -> f16 N x K transpose with scale (V matrix) -------
__global__ __launch_bounds__(256)
void tr_f16_k(const float* __restrict__ in, unsigned short* __restrict__ out,
              int K, int N, float scl)
{
    __shared__ float tile[32][33];
    int k0 = blockIdx.x * 32, n0 = blockIdx.y * 32;
    int t = threadIdx.x;
    int r = t >> 3, c4 = (t & 7) * 4;
    float4 v = *reinterpret_cast<const float4*>(&in[(long)(k0 + r) * N + n0 + c4]);
    tile[r][c4] = v.x; tile[r][c4 + 1] = v.y; tile[r][c4 + 2] = v.z; tile[r][c4 + 3] = v.w;
    __syncthreads();
    int nr = t >> 3, kq = (t & 7) * 4;
    unsigned short h[4];
#pragma unroll
    for (int j = 0; j < 4; ++j) h[j] = f2h(tile[kq + j][nr] * scl);
    *reinterpret_cast<ushort4*>(&out[(long)(n0 + nr) * K + k0 + kq]) =
        make_ushort4(h[0], h[1], h[2], h[3]);
}

// ---------------- 16-bit MFMA GEMM (bf16), split-K partial writer ----------------
__global__ __launch_bounds__(256, 2)
void bgemm_k(const unsigned short* __restrict__ A,
             const unsigned short* __restrict__ B0, const unsigned short* __restrict__ B1,
             const unsigned short* __restrict__ B2,
             int M, int N, int K, int lda, int ldb,
             long sA, int splitk,
             float* __restrict__ Cpart)
{
    constexpr int BKp = 40;
    int tid = threadIdx.x;
    int bz = blockIdx.z;
    int z  = bz / splitk;
    int ks = bz - z * splitk;

    const unsigned short* Ap = A + (long)z * sA + (long)ks * K;
    const unsigned short* Bp = ((z == 1) ? B1 : (z == 2) ? B2 : B0) + (long)ks * K;

    __shared__ unsigned short As[128 * BKp];
    __shared__ unsigned short Bs[128 * BKp];

    int bm = blockIdx.x * 128;
    int bn = blockIdx.y * 128;
    int w = tid >> 6, lane = tid & 63, quad = lane >> 4, l16 = lane & 15;
    int wm = (w >> 1) * 64;
    int wn = (w & 1) * 64;

    int ar = tid >> 1, ac = (tid & 1) * 16;

    f32x4_t acc[4][4] = {};
    bhalf8_t aS0, aS1, bS0, bS1;

    auto ldgA = [&](int k0) {
        const unsigned short* p = Ap + (long)(bm + ar) * lda + k0 + ac;
        aS0 = *reinterpret_cast<const bhalf8_t*>(p);
        aS1 = *reinterpret_cast<const bhalf8_t*>(p + 8);
    };
    auto ldgB = [&](int k0) {
        const unsigned short* p = Bp + (long)(bn + ar) * ldb + k0 + ac;
        bS0 = *reinterpret_cast<const bhalf8_t*>(p);
        bS1 = *reinterpret_cast<const bhalf8_t*>(p + 8);
    };

    ldgA(0); ldgB(0);

    for (int k0 = 0; k0 < K; k0 += 32) {
        *reinterpret_cast<bhalf8_t*>(&As[ar * BKp + ac])     = aS0;
        *reinterpret_cast<bhalf8_t*>(&As[ar * BKp + ac + 8]) = aS1;
        *reinterpret_cast<bhalf8_t*>(&Bs[ar * BKp + ac])     = bS0;
        *reinterpret_cast<bhalf8_t*>(&Bs[ar * BKp + ac + 8]) = bS1;
        __syncthreads();
        if (k0 + 32 < K) { ldgA(k0 + 32); ldgB(k0 + 32); }
        bhalf8_t af[4], bf[4];
#pragma unroll
        for (int i = 0; i < 4; ++i)
            af[i] = *reinterpret_cast<const bhalf8_t*>(&As[(wm + i * 16 + l16) * BKp + quad * 8]);
#pragma unroll
        for (int j = 0; j < 4; ++j)
            bf[j] = *reinterpret_cast<const bhalf8_t*>(&Bs[(wn + j * 16 + l16) * BKp + quad * 8]);
#pragma unroll
        for (int i = 0; i < 4; ++i)
#pragma unroll
            for (int j = 0; j < 4; ++j)
                acc[i][j] = __builtin_amdgcn_mfma_f32_16x16x32_bf16(af[i], bf[j], acc[i][j], 0, 0, 0);
        __syncthreads();
    }

    float* Cp = Cpart + (long)bz * M * N;
#pragma unroll
    for (int i = 0; i < 4; ++i)
#pragma unroll
        for (int j = 0; j < 4; ++j)
#pragma unroll
            for (int r = 0; r < 4; ++r) {
                int m = bm + wm + i * 16 + quad * 4 + r;
                int n = bn + wn + j * 16 + l16;
                Cp[(long)m * N + n] = acc[i][j][r];
            }
}

// ---------------- flash partial: one wave = (32 Q-rows, 128 keys, 1 head) --------
// No cross-wave coupling; single tile so no online update. Writes partial
// O (x2^24-scaled), rowmax m, rowsum l for the merge kernel.
__global__ __launch_bounds__(64)
void flash_part_k(const unsigned short* __restrict__ qb3, const unsigned short* __restrict__ kb3,
                  const unsigned short* __restrict__ vtb, const float* __restrict__ dist,
                  const float* __restrict__ bp, const float* __restrict__ Atab,
                  const float* __restrict__ Btab,
                  float* __restrict__ po, float* __restrict__ pm, float* __restrict__ pl)
{
    __shared__ unsigned short Ps[32 * 136];
    __shared__ float bps_s[128], Ah[129], Bh[129];

    int tid = threadIdx.x;          // 0..63
    int qb = blockIdx.x;            // 32 Q-blocks
    int h  = blockIdx.y;            // 8 heads
    int z  = blockIdx.z;            // 8 key-slices
    int bm = qb * 32;
    int k0 = z * 128;

    const unsigned short* Qh = qb3 + (long)h * 196608;
    const unsigned short* Kh = kb3 + (long)h * 196608;
    const unsigned short* Vh = vtb + (long)h * 65536;

    bps_s[tid]      = bp[tid];
    bps_s[tid + 64] = bp[tid + 64];
    Ah[tid]      = Atab[tid * 8 + h];
    Ah[tid + 64] = Atab[(tid + 64) * 8 + h];
    Bh[tid]      = Btab[tid * 8 + h];
    Bh[tid + 64] = Btab[(tid + 64) * 8 + h];
    if (tid == 0) { Ah[128] = Atab[1024 + h]; Bh[128] = Btab[1024 + h]; }
    __syncthreads();

    int quad = tid >> 4, l16 = tid & 15;

    // Q fragments (rows bm..bm+31, K=192 3-split)
    bhalf8_t aq[2][6];
#pragma unroll
    for (int mb = 0; mb < 2; ++mb)
#pragma unroll
        for (int kq = 0; kq < 6; ++kq)
            aq[mb][kq] = *reinterpret_cast<const bhalf8_t*>(
                &Qh[(long)(bm + mb * 16 + l16) * 192 + kq * 32 + quad * 8]);

    // QK^T: scores 32x128, K fragments straight from global (L2-hot)
    f32x4_t sacc[2][8] = {};
#pragma unroll
    for (int kq = 0; kq < 6; ++kq) {
        bhalf8_t bk[8];
#pragma unroll
        for (int nb = 0; nb < 8; ++nb)
            bk[nb] = *reinterpret_cast<const bhalf8_t*>(
                &Kh[(long)(k0 + nb * 16 + l16) * 192 + kq * 32 + quad * 8]);
#pragma unroll
        for (int mb = 0; mb < 2; ++mb)
#pragma unroll
            for (int nb = 0; nb < 8; ++nb)
                sacc[mb][nb] = __builtin_amdgcn_mfma_f32_16x16x32_bf16(aq[mb][kq], bk[nb], sacc[mb][nb], 0, 0, 0);
    }

    // scale + PWL bias (in place), row max
    float m_r[2][4] = {{-3.0e38f, -3.0e38f, -3.0e38f, -3.0e38f},
                       {-3.0e38f, -3.0e38f, -3.0e38f, -3.0e38f}};
#pragma unroll
    for (int mb = 0; mb < 2; ++mb)
#pragma unroll
        for (int nb = 0; nb < 8; ++nb)
#pragma unroll
            for (int r = 0; r < 4; ++r) {
                int gm = bm + mb * 16 + quad * 4 + r;
                int gn = k0 + nb * 16 + l16;
                float t = dist[(long)gm * kS + gn];
                int lo = 0, hi2 = 128;
                while (lo < hi2) { int mid = (lo + hi2) >> 1; if (bps_s[mid] < t) lo = mid + 1; else hi2 = mid; }
                float s = fmaf(sacc[mb][nb][r], 0.125f, fmaf(Ah[lo], t, Bh[lo]));
                sacc[mb][nb][r] = s;
                m_r[mb][r] = fmaxf(m_r[mb][r], s);
            }
#pragma unroll
    for (int mb = 0; mb < 2; ++mb)
#pragma unroll
        for (int r = 0; r < 4; ++r) {
            float m_ = m_r[mb][r];
#pragma unroll
            for (int off = 1; off < 16; off <<= 1) m_ = fmaxf(m_, __shfl_xor(m_, off, 64));
            m_r[mb][r] = m_;
        }

    // P = exp(s-m) -> LDS (x2^14 f16), row sums
    float l_r[2][4];
#pragma unroll
    for (int mb = 0; mb < 2; ++mb)
#pragma unroll
        for (int r = 0; r < 4; ++r) {
            int row = mb * 16 + quad * 4 + r;
            float mN = m_r[mb][r];
            float s_ = 0.f;
#pragma unroll
            for (int nb = 0; nb < 8; ++nb) {
                float p = __expf(sacc[mb][nb][r] - mN);
                Ps[row * 136 + nb * 16 + l16] = f2h(p * 16384.f);
                s_ += p;
            }
#pragma unroll
            for (int off = 1; off < 16; off <<= 1) s_ += __shfl_xor(s_, off, 64);
            l_r[mb][r] = s_;
        }

    long sbase = (((long)z * 8 + h) * 32 + qb) * 32;
    if (l16 == 0) {
#pragma unroll
        for (int mb = 0; mb < 2; ++mb)
#pragma unroll
            for (int r = 0; r < 4; ++r) {
                int row = mb * 16 + quad * 4 + r;
                pm[sbase + row] = m_r[mb][r];
                pl[sbase + row] = l_r[mb][r];
            }
    }
    __syncthreads();

    // PV: O(32x64) = P(32x128) @ V-slice, f16 MFMA, V from global
    f32x4_t oacc[2][4] = {};
#pragma unroll
    for (int kq2 = 0; kq2 < 4; ++kq2) {
        bhalf8_t ap[2];
#pragma unroll
        for (int mb = 0; mb < 2; ++mb)
            ap[mb] = *reinterpret_cast<const bhalf8_t*>(&Ps[(mb * 16 + l16) * 136 + kq2 * 32 + quad * 8]);
#pragma unroll
        for (int j2 = 0; j2 < 4; ++j2) {
            bhalf8_t bv = *reinterpret_cast<const bhalf8_t*>(
                &Vh[(long)(j2 * 16 + l16) * 1024 + k0 + kq2 * 32 + quad * 8]);
#pragma unroll
            for (int mb = 0; mb < 2; ++mb)
                oacc[mb][j2] = __builtin_amdgcn_mfma_f32_16x16x32_f16(
                    __builtin_bit_cast(half8_t, ap[mb]), __builtin_bit_cast(half8_t, bv),
                    oacc[mb][j2], 0, 0, 0);
        }
    }

    float* pob = po + sbase * 64;
#pragma unroll
    for (int mb = 0; mb < 2; ++mb)
#pragma unroll
        for (int j2 = 0; j2 < 4; ++j2)
#pragma unroll
            for (int r = 0; r < 4; ++r)
                pob[(mb * 16 + quad * 4 + r) * 64 + j2 * 16 + l16] = oacc[mb][j2][r];
}

// ---------------- flash merge: combine 8 key-slice partials, write aob 3-split ---
__global__ __launch_bounds__(256)
void flash_merge_k(const float* __restrict__ po, const float* __restrict__ pm,
                   const float* __restrict__ pl, unsigned short* __restrict__ aob)
{
    int t = blockIdx.x * 256 + threadIdx.x;   // 65536 = 8h * 32qb * 32row * 8chunks
    int c8  = t & 7;
    int row = (t >> 3) & 31;
    int qb  = (t >> 8) & 31;
    int h   = t >> 13;
    long sidx = (((long)h * 32) + qb) * 32 + row;   // per-z stride 8192

    float m[8];
    float M = -3.0e38f;
#pragma unroll
    for (int z = 0; z < 8; ++z) { m[z] = pm[z * 8192 + sidx]; M = fmaxf(M, m[z]); }
    float w[8], lt = 0.f;
#pragma unroll
    for (int z = 0; z < 8; ++z) {
        w[z] = __expf(m[z] - M);
        lt = fmaf(pl[z * 8192 + sidx], w[z], lt);
    }
    float acc[8] = {};
#pragma unroll
    for (int z = 0; z < 8; ++z) {
        const float* p = po + (z * 8192 + sidx) * 64 + c8 * 8;
        float4 a = *reinterpret_cast<const float4*>(p);
        float4 b = *reinterpret_cast<const float4*>(p + 4);
        acc[0] = fmaf(a.x, w[z], acc[0]); acc[1] = fmaf(a.y, w[z], acc[1]);
        acc[2] = fmaf(a.z, w[z], acc[2]); acc[3] = fmaf(a.w, w[z], acc[3]);
        acc[4] = fmaf(b.x, w[z], acc[4]); acc[5] = fmaf(b.y, w[z], acc[5]);
        acc[6] = fmaf(b.z, w[z], acc[6]); acc[7] = fmaf(b.w, w[z], acc[7]);
    }
    float inv = 1.f / (16777216.f * lt);
    unsigned short hi[8], lo[8];
#pragma unroll
    for (int j = 0; j < 8; ++j) {
        float val = acc[j] * inv;
        hi[j] = f2bf(val);
        lo[j] = f2bf(val - bf2f(hi[j]));
    }
    long base = ((long)qb * 32 + row) * 1536 + h * 64 + c8 * 8;
    *reinterpret_cast<ushort4*>(&aob[base])        = make_ushort4(hi[0], hi[1], hi[2], hi[3]);
    *reinterpret_cast<ushort4*>(&aob[base + 4])    = make_ushort4(hi[4], hi[5], hi[6], hi[7]);
    *reinterpret_cast<ushort4*>(&aob[base + 512])  = make_ushort4(lo[0], lo[1], lo[2], lo[3]);
    *reinterpret_cast<ushort4*>(&aob[base + 516])  = make_ushort4(lo[4], lo[5], lo[6], lo[7]);
    *reinterpret_cast<ushort4*>(&aob[base + 1024]) = make_ushort4(hi[0], hi[1], hi[2], hi[3]);
    *reinterpret_cast<ushort4*>(&aob[base + 1028]) = make_ushort4(hi[4], hi[5], hi[6], hi[7]);
}

// ---------------- QKV split-K reduce: bias + direct 3-split to qb3/kb3, v f32 ----
__global__ __launch_bounds__(256)
void reduce_qkv_k(const float* __restrict__ part,
                  unsigned short* __restrict__ qb3, unsigned short* __restrict__ kb3,
                  float* __restrict__ v,
                  const float* __restrict__ qbias, const float* __restrict__ kbias,
                  const float* __restrict__ vbias)
{
    int z = blockIdx.y;
    const long MN = (long)kS * kD;
    long idx = ((long)blockIdx.x * 256 + threadIdx.x) * 4;
    const float* pz = part + (long)z * 4 * MN + idx;
    float4 s = *reinterpret_cast<const float4*>(pz);
#pragma unroll
    for (int t = 1; t < 4; ++t) {
        float4 vv = *reinterpret_cast<const float4*>(pz + (long)t * MN);
        s.x += vv.x; s.y += vv.y; s.z += vv.z; s.w += vv.w;
    }
    int m = (int)(idx >> 9), n = (int)(idx & 511);
    const float* bzp = (z == 1) ? kbias : (z == 2) ? vbias : qbias;
    s.x += bzp[n]; s.y += bzp[n + 1]; s.z += bzp[n + 2]; s.w += bzp[n + 3];
    if (z == 2) {
        *reinterpret_cast<float4*>(v + idx) = s;
        return;
    }
    float fv[4] = {s.x, s.y, s.z, s.w};
    unsigned short h[4], lo[4];
#pragma unroll
    for (int j = 0; j < 4; ++j) {
        h[j] = f2bf(fv[j]);
        lo[j] = f2bf(fv[j] - bf2f(h[j]));
    }
    int head = n >> 6, hc = n & 63;
    unsigned short* dst = ((z == 1) ? kb3 : qb3) + (long)head * 196608 + (long)m * 192 + hc;
    ushort4 hv = make_ushort4(h[0], h[1], h[2], h[3]);
    ushort4 lv = make_ushort4(lo[0], lo[1], lo[2], lo[3]);
    *reinterpret_cast<ushort4*>(dst) = hv;
    if (z == 0) {  // A-side [hi|lo|hi]
        *reinterpret_cast<ushort4*>(dst + 64)  = lv;
        *reinterpret_cast<ushort4*>(dst + 128) = hv;
    } else {       // B-side [hi|hi|lo]
        *reinterpret_cast<ushort4*>(dst + 64)  = hv;
        *reinterpret_cast<ushort4*>(dst + 128) = lv;
    }
}

// ---------------- generic split-K reduce -> f32 (+bias) ----------------
__global__ __launch_bounds__(256)
void reduce_k(const float* __restrict__ part, float* __restrict__ C,
              const float* __restrict__ bias, int N, int splitk)
{
    const long MN = (long)kS * N;
    long idx = ((long)blockIdx.x * 256 + threadIdx.x) * 4;
    const float* pz = part + idx;
    float4 s = *reinterpret_cast<const float4*>(pz);
    for (int t = 1; t < splitk; ++t) {
        float4 v = *reinterpret_cast<const float4*>(pz + (long)t * MN);
        s.x += v.x; s.y += v.y; s.z += v.z; s.w += v.w;
    }
    int n = (int)(idx % N);
    s.x += bias[n]; s.y += bias[n + 1]; s.z += bias[n + 2]; s.w += bias[n + 3];
    *reinterpret_cast<float4*>(C + idx) = s;
}

// ---------------- FFN1 reduce: bias + relu + direct 3-split to hb ----------------
__global__ __launch_bounds__(256)
void reduce3_k(const float* __restrict__ part, unsigned short* __restrict__ hb,
               const float* __restrict__ bias, int splitk)
{
    const long MN = (long)kS * kDFF;
    long idx = ((long)blockIdx.x * 256 + threadIdx.x) * 4;
    const float* pz = part + idx;
    float4 s = *reinterpret_cast<const float4*>(pz);
    for (int t = 1; t < splitk; ++t) {
        float4 v = *reinterpret_cast<const float4*>(pz + (long)t * MN);
        s.x += v.x; s.y += v.y; s.z += v.z; s.w += v.w;
    }
    int m = (int)(idx >> 11), n = (int)(idx & 2047);
    float fv[4] = {fmaxf(s.x + bias[n], 0.f), fmaxf(s.y + bias[n + 1], 0.f),
                   fmaxf(s.z + bias[n + 2], 0.f), fmaxf(s.w + bias[n + 3], 0.f)};
    unsigned short h[4], lo[4];
#pragma unroll
    for (int j = 0; j < 4; ++j) {
        h[j] = f2bf(fv[j]);
        lo[j] = f2bf(fv[j] - bf2f(h[j]));
    }
    unsigned short* dst = hb + (long)m * 6144 + n;
    ushort4 hv = make_ushort4(h[0], h[1], h[2], h[3]);
    *reinterpret_cast<ushort4*>(dst)        = hv;
    *reinterpret_cast<ushort4*>(dst + 2048) = make_ushort4(lo[0], lo[1], lo[2], lo[3]);
    *reinterpret_cast<ushort4*>(dst + 4096) = hv;
}

// ---------------- residual add + layernorm (in place on x, + 3-split xb) --------
__global__ __launch_bounds__(256)
void add_ln_k(float* __restrict__ x, const float* __restrict__ y,
              const float* __restrict__ g, const float* __restrict__ b,
              unsigned short* __restrict__ xb)
{
    __shared__ float sm[4];
    int row = blockIdx.x, t = threadIdx.x;
    float* xr = x + (long)row * kD;
    const float* yr = y + (long)row * kD;
    float s0 = xr[t] + yr[t];
    float s1 = xr[t + 256] + yr[t + 256];
    float sum = wave_sum(s0 + s1);
    if ((t & 63) == 0) sm[t >> 6] = sum;
    __syncthreads();
    sum = sm[0] + sm[1] + sm[2] + sm[3];
    float mu = sum * (1.f / kD);
    float d0 = s0 - mu, d1 = s1 - mu;
    __syncthreads();
    float vs = wave_sum(d0 * d0 + d1 * d1);
    if ((t & 63) == 0) sm[t >> 6] = vs;
    __syncthreads();
    vs = sm[0] + sm[1] + sm[2] + sm[3];
    float rs = rsqrtf(vs * (1.f / kD) + 1e-5f);
    float o0 = fmaf(d0 * rs, g[t], b[t]);
    float o1 = fmaf(d1 * rs, g[t + 256], b[t + 256]);
    xr[t]       = o0;
    xr[t + 256] = o1;
    unsigned short h0 = f2bf(o0), l0 = f2bf(o0 - bf2f(h0));
    unsigned short h1 = f2bf(o1), l1 = f2bf(o1 - bf2f(h1));
    unsigned short* xrow = xb + (long)row * 1536;
    xrow[t]            = h0;  xrow[t + 256]        = h1;
    xrow[t + 512]      = l0;  xrow[t + 768]        = l1;
    xrow[t + 1024]     = h0;  xrow[t + 1280]       = h1;
}

// ---------------- mean-pool partials ----------------
__global__ __launch_bounds__(256)
void pool_k(const float* __restrict__ x, float* __restrict__ partial)
{
    int col = blockIdx.x * 256 + threadIdx.x;
    int rb = blockIdx.y;
    float s = 0.f;
    for (int r = rb * 128; r < rb * 128 + 128; ++r) s += x[(long)r * kD + col];
    partial[rb * kD + col] = s;
}

// ---------------- classifier head ----------------
__global__ __launch_bounds__(256)
void head_k(const float* __restrict__ partial,
            const float* __restrict__ c1w, const float* __restrict__ c1b,
            const float* __restrict__ c2w, const float* __restrict__ c2b,
            float* __restrict__ out)
{
    __shared__ float pooled[kD];
    __shared__ float h1[256];
    int t = threadIdx.x;
    for (int d = t; d < kD; d += 256) {
        float s = 0.f;
        for (int r = 0; r < 8; ++r) s += partial[r * kD + d];
        pooled[d] = s * (1.0f / kS);
    }
    __syncthreads();
    float acc = c1b[t];
    for (int f = 0; f < kD; ++f) acc = fmaf(pooled[f], c1w[f * 256 + t], acc);
    h1[t] = fmaxf(acc, 0.f);
    __syncthreads();
    if (t < 10) {
        float o = c2b[t];
        for (int f = 0; f < 256; ++f) o = fmaf(h1[f], c2w[f * 10 + t], o);
        out[t] = o;
    }
}

// ---------------- launch ----------------
extern "C" void kernel_launch(void* const* d_in, const int* in_sizes, int n_in,
                              void* d_out, int out_size, void* d_ws, size_t ws_size,
                              hipStream_t stream)
{
    (void)in_sizes; (void)n_in; (void)out_size; (void)ws_size;
    const float* features = (const float*)d_in[0];
    const float* positions= (const float*)d_in[1];
    const float* fb       = (const float*)d_in[2];
    const float* in_w     = (const float*)d_in[3];
    const float* in_b     = (const float*)d_in[4];
    const float* qw  = (const float*)d_in[5];
    const float* qb  = (const float*)d_in[6];
    const float* kw  = (const float*)d_in[7];
    const float* kb  = (const float*)d_in[8];
    const float* vw  = (const float*)d_in[9];
    const float* vb  = (const float*)d_in[10];
    const float* ow  = (const float*)d_in[11];
    const float* ob  = (const float*)d_in[12];
    const float* db1w= (const float*)d_in[13];
    const float* db1b= (const float*)d_in[14];
    const float* db2w= (const float*)d_in[15];
    const float* db2b= (const float*)d_in[16];
    const float* n1g = (const float*)d_in[17];
    const float* n1b = (const float*)d_in[18];
    const float* n2g = (const float*)d_in[19];
    const float* n2b = (const float*)d_in[20];
    const float* f1w = (const float*)d_in[21];
    const float* f1b = (const float*)d_in[22];
    const float* f2w = (const float*)d_in[23];
    const float* f2b = (const float*)d_in[24];
    const float* c1w = (const float*)d_in[25];
    const float* c1b = (const float*)d_in[26];
    const float* c2w = (const float*)d_in[27];
    const float* c2b = (const float*)d_in[28];

    float* ws = (float*)d_ws;
    const long SD = (long)kS * kD;            // 524288
    float* x      = ws;
    float* v      = ws + 1 * SD;
    float* y      = ws + 2 * SD;
    float* dist   = ws + 3 * SD;              // 2*SD
    float* part   = ws + 5 * SD;              // 12*SD scratch (QKV partials / flash partials)
    float* bpw    = ws + 17 * SD;
    float* Atab   = bpw + 256;
    float* Btab   = Atab + 2080;
    float* partial= Btab + 2080;

    // flash partial overlays inside `part` (dead between QKV-reduce and O-proj)
    float* po = part;                          // 8*8*32*32*64 = 4,194,304 floats
    float* pmv = part + 4194304;               // 65536
    float* plv = pmv + 65536;                  // 65536

    unsigned short* ub = (unsigned short*)(ws + 17 * SD + 8512);
    unsigned short* xb   = ub;                       // 1024*1536
    unsigned short* aob  = xb   + 1572864;           // 1024*1536
    unsigned short* qb3  = aob  + 1572864;           // 8*1024*192
    unsigned short* kb3  = qb3  + 1572864;
    unsigned short* vtb  = kb3  + 1572864;           // 512*1024 (f16)
    unsigned short* hb   = vtb  + 524288;            // 1024*6144
    unsigned short* qwb  = hb   + 6291456;           // 2 x 512*1536
    unsigned short* kwb  = qwb  + 1572864;
    unsigned short* vwb  = kwb  + 1572864;
    unsigned short* owb  = vwb  + 1572864;
    unsigned short* f1wb = owb  + 1572864;           // 2 x 2048*1536
    unsigned short* f2wb = f1wb + 6291456;           // 2 x 512*6144

    input_pe_k<<<kS, 256, 0, stream>>>(features, positions, fb, in_w, in_b, x);
    dist_k<<<kS, 256, 0, stream>>>(positions, dist);
    pwl_build_k<<<2, 256, 0, stream>>>(db1w, db1b, db2w, db2b, bpw, Atab, Btab);
    split3_rm_k<<<512, 256, 0, stream>>>(x, xb, 524288, 9, 512);

    split3_tr_k<<<dim3(16, 16, 2), 256, 0, stream>>>(qw, qwb, 512, 512, 262144, 786432);
    split3_tr_k<<<dim3(16, 16, 2), 256, 0, stream>>>(kw, kwb, 512, 512, 262144, 786432);
    split3_tr_k<<<dim3(16, 16, 2), 256, 0, stream>>>(vw, vwb, 512, 512, 262144, 786432);
    split3_tr_k<<<dim3(16, 16, 2), 256, 0, stream>>>(ow, owb, 512, 512, 262144, 786432);
    split3_tr_k<<<dim3(16, 64, 2), 256, 0, stream>>>(f1w, f1wb, 512, 2048, 1048576, 3145728);
    split3_tr_k<<<dim3(64, 16, 2), 256, 0, stream>>>(f2w, f2wb, 2048, 512, 1048576, 3145728);

    for (int l = 0; l < 2; ++l) {
        // QKV: A=xb (1024x1536), split-K x4 -> partials; reduce fuses bias + q/k 3-split
        bgemm_k<<<dim3(8, 4, 12), 256, 0, stream>>>(
            xb, qwb + l * 786432, kwb + l * 786432, vwb + l * 786432,
            1024, 512, 384, 1536, 1536, 0, 4, part);
        reduce_qkv_k<<<dim3(512, 3), 256, 0, stream>>>(
            part, qb3, kb3, v, qb + l * kD, kb + l * kD, vb + l * kD);
        tr_f16_k<<<dim3(32, 16), 256, 0, stream>>>(v, vtb, 1024, 512, 1024.f);

        // fused attention: K-split partials + merge -> aob (3-split)
        flash_part_k<<<dim3(32, 8, 8), 64, 0, stream>>>(
            qb3, kb3, vtb, dist, bpw + l * 128, Atab + l * 1040, Btab + l * 1040,
            po, pmv, plv);
        flash_merge_k<<<256, 256, 0, stream>>>(po, pmv, plv, aob);

        // O-proj: split-K x8
        bgemm_k<<<dim3(8, 4, 8), 256, 0, stream>>>(
            aob, owb + l * 786432, owb + l * 786432, owb + l * 786432,
            1024, 512, 192, 1536, 1536, 0, 8, part);
        reduce_k<<<512, 256, 0, stream>>>(part, y, ob + l * kD, 512, 8);
        add_ln_k<<<kS, 256, 0, stream>>>(x, y, n1g + l * kD, n1b + l * kD, xb);

        // FFN1: split-K x2, reduce fuses bias+relu+3-split -> hb
        bgemm_k<<<dim3(8, 16, 2), 256, 0, stream>>>(
            xb, f1wb + l * 3145728, f1wb + l * 3145728, f1wb + l * 3145728,
            1024, 2048, 768, 1536, 1536, 0, 2, part);
        reduce3_k<<<2048, 256, 0, stream>>>(part, hb, f1b + l * kDFF, 2);

        // FFN2: split-K x8
        bgemm_k<<<dim3(8, 4, 8), 256, 0, stream>>>(
            hb, f2wb + l * 3145728, f2wb + l * 3145728, f2wb + l * 3145728,
            1024, 512, 768, 6144, 6144, 0, 8, part);
        reduce_k<<<512, 256, 0, stream>>>(part, y, f2b + l * kD, 512, 8);
        add_ln_k<<<kS, 256, 0, stream>>>(x, y, n2g + l * kD, n2b + l * kD, xb);
    }

    pool_k<<<dim3(2, 8), 256, 0, stream>>>(x, partial);
    head_k<<<1, 256, 0, stream>>>(partial, c1w, c1b, c2w, c2b, (float*)d_out);
}

// Round 9
// 549.691 us; speedup vs baseline: 1.1338x; 1.1338x over previous
//
#include <hip/hip_runtime.h>

namespace {
constexpr int kS   = 1024;
constexpr int kD   = 512;
constexpr int kH   = 8;
constexpr int kDFF = 2048;
constexpr int kNF  = 85;   // D//6
}

typedef __attribute__((ext_vector_type(8))) short bhalf8_t;    // 8x16-bit in 4 VGPRs
typedef _Float16 half8_t __attribute__((ext_vector_type(8)));
typedef __attribute__((ext_vector_type(4))) float f32x4_t;

// ---------------- helpers ----------------
__device__ __forceinline__ float wave_sum(float v) {
#pragma unroll
    for (int o = 1; o < 64; o <<= 1) v += __shfl_xor(v, o, 64);
    return v;
}
__device__ __forceinline__ unsigned short f2bf(float f) {   // RNE fp32->bf16
    unsigned u = __float_as_uint(f);
    u = (u + 0x7FFF + ((u >> 16) & 1)) >> 16;
    return (unsigned short)u;
}
__device__ __forceinline__ float bf2f(unsigned short h) {
    return __uint_as_float(((unsigned)h) << 16);
}
__device__ __forceinline__ unsigned short f2h(float f) {    // RNE fp32->fp16
    _Float16 h = (_Float16)f;
    return __builtin_bit_cast(unsigned short, h);
}
__device__ __forceinline__ float h2f(unsigned short u) {
    return (float)__builtin_bit_cast(_Float16, u);
}

// ---------------- input projection + positional encoding ----------------
__global__ __launch_bounds__(256)
void input_pe_k(const float* __restrict__ feat, const float* __restrict__ pos,
                const float* __restrict__ fb, const float* __restrict__ in_w,
                const float* __restrict__ in_b, float* __restrict__ x)
{
    int s = blockIdx.x;
    int t = threadIdx.x;
    __shared__ float f[64];
    if (t < 64) f[t] = feat[s * 64 + t];
    __syncthreads();
    float acc0 = in_b[t], acc1 = in_b[t + 256];
#pragma unroll 8
    for (int c = 0; c < 64; ++c) {
        float fv = f[c];
        acc0 = fmaf(fv, in_w[c * kD + t], acc0);
        acc1 = fmaf(fv, in_w[c * kD + 256 + t], acc1);
    }
    float pe0 = 0.f, pe1 = 0.f;
    {
        int d = t;
        if (d < 6 * kNF) {
            int seg = d / kNF, idx = d - seg * kNF;
            float cs = pos[s * 3 + (seg >> 1)] * fb[idx];
            pe0 = (seg & 1) ? cosf(cs) : sinf(cs);
        }
        d = t + 256;
        if (d < 6 * kNF) {
            int seg = d / kNF, idx = d - seg * kNF;
            float cs = pos[s * 3 + (seg >> 1)] * fb[idx];
            pe1 = (seg & 1) ? cosf(cs) : sinf(cs);
        }
    }
    x[s * kD + t]       = acc0 + pe0;
    x[s * kD + 256 + t] = acc1 + pe1;
}

// ---------------- pairwise distance matrix ----------------
__global__ __launch_bounds__(256)
void dist_k(const float* __restrict__ pos, float* __restrict__ dist)
{
    int i = blockIdx.x;
    float px = pos[i * 3], py = pos[i * 3 + 1], pz = pos[i * 3 + 2];
    for (int j = threadIdx.x; j < kS; j += 256) {
        float dx = px - pos[j * 3], dy = py - pos[j * 3 + 1], dz = pz - pos[j * 3 + 2];
        float sq = dx * dx + dy * dy + dz * dz;
        dist[(long)i * kS + j] = sq > 0.f ? sqrtf(sq) : 0.f;
    }
}

// ---------------- exact PWL factorization of the distance-bias MLP ----------------
__global__ __launch_bounds__(256)
void pwl_build_k(const float* __restrict__ a_, const float* __restrict__ b_,
                 const float* __restrict__ w2, const float* __restrict__ b2,
                 float* __restrict__ bp_out, float* __restrict__ Atab, float* __restrict__ Btab)
{
    int l = blockIdx.x;
    a_ += l * 128; b_ += l * 128; w2 += l * 1024; b2 += l * 8;
    bp_out += l * 128; Atab += l * 1040; Btab += l * 1040;

    __shared__ float key[128], av[128], bv[128], sw2[1024], sb2[8];
    int t = threadIdx.x;
    for (int i = t; i < 1024; i += 256) sw2[i] = w2[i];
    if (t < 8) sb2[t] = b2[t];
    if (t < 128) {
        float a = a_[t], b = b_[t];
        av[t] = a; bv[t] = b;
        key[t] = (a != 0.f) ? (-b / a) : 3.0e38f;
    }
    __syncthreads();
    for (int ksz = 2; ksz <= 128; ksz <<= 1) {
        for (int j = ksz >> 1; j > 0; j >>= 1) {
            if (t < 128) {
                int ixj = t ^ j;
                if (ixj > t) {
                    bool up = ((t & ksz) == 0);
                    float x0 = key[t], x1 = key[ixj];
                    if ((x0 > x1) == up) { key[t] = x1; key[ixj] = x0; }
                }
            }
            __syncthreads();
        }
    }
    if (t < 128) bp_out[t] = key[t];
    __syncthreads();
    for (int task = t; task < 129 * 8; task += 256) {
        int seg = task >> 3, h = task & 7;
        float m;
        if (seg == 0)        m = key[0] - 1.0f;
        else if (seg == 128) m = key[127] + 1.0f;
        else                 m = 0.5f * (key[seg - 1] + key[seg]);
        float A = 0.f, B = 0.f;
        for (int c = 0; c < 128; ++c) {
            float a = av[c], b = bv[c];
            if (fmaf(a, m, b) > 0.f) {
                float w = sw2[c * 8 + h];
                A = fmaf(a, w, A);
                B = fmaf(b, w, B);
            }
        }
        Atab[seg * 8 + h] = A;
        Btab[seg * 8 + h] = B + sb2[h];
    }
}

// ---------------- per-layer bias map: bias_h(i,j) -> f16, removes PWL from flash --
__global__ __launch_bounds__(256)
void biasmap_k(const float* __restrict__ dist, const float* __restrict__ bp,
               const float* __restrict__ Atab, const float* __restrict__ Btab,
               unsigned short* __restrict__ bmap)
{
    __shared__ float bps[128], Ah[129], Bh[129];
    int h = blockIdx.y;
    int t = threadIdx.x;
    if (t < 128) bps[t] = bp[t];
    if (t < 129) { Ah[t] = Atab[t * 8 + h]; Bh[t] = Btab[t * 8 + h]; }
    __syncthreads();
    long i = ((long)blockIdx.x * 256 + t) * 4;
    float4 d4 = *reinterpret_cast<const float4*>(dist + i);
    float dv[4] = {d4.x, d4.y, d4.z, d4.w};
    unsigned short o[4];
#pragma unroll
    for (int j = 0; j < 4; ++j) {
        float tv = dv[j];
        int lo = 0, hi = 128;
        while (lo < hi) { int mid = (lo + hi) >> 1; if (bps[mid] < tv) lo = mid + 1; else hi = mid; }
        o[j] = f2h(fmaf(Ah[lo], tv, Bh[lo]));
    }
    *reinterpret_cast<ushort4*>(bmap + (long)h * 1048576 + i) =
        make_ushort4(o[0], o[1], o[2], o[3]);
}

// ---------------- fp32 -> bf16 3-term split, row-major (order0 [hi|lo|hi]) ------
__global__ __launch_bounds__(256)
void split3_rm_k(const float* __restrict__ in, unsigned short* __restrict__ out,
                 int total, int kshift, int ldin)
{
    long i = ((long)blockIdx.x * 256 + threadIdx.x) * 4;
    if (i >= total) return;
    int K = 1 << kshift;
    int m = (int)(i >> kshift), k = (int)(i & (K - 1));
    float4 v = *reinterpret_cast<const float4*>(in + (long)m * ldin + k);
    unsigned short h[4], lo[4];
    float fv[4] = {v.x, v.y, v.z, v.w};
#pragma unroll
    for (int j = 0; j < 4; ++j) {
        h[j] = f2bf(fv[j]);
        lo[j] = f2bf(fv[j] - bf2f(h[j]));
    }
    unsigned short* op = out + (long)m * (3 * K) + k;
    ushort4 hv = make_ushort4(h[0], h[1], h[2], h[3]);
    *reinterpret_cast<ushort4*>(op)         = hv;
    *reinterpret_cast<ushort4*>(op + K)     = make_ushort4(lo[0], lo[1], lo[2], lo[3]);
    *reinterpret_cast<ushort4*>(op + 2 * K) = hv;
}

// ---------------- fp32 K x N -> bf16 N x 3K transpose-split (weights, [hi|hi|lo]) --
__global__ __launch_bounds__(256)
void split3_tr_k(const float* __restrict__ in, unsigned short* __restrict__ out,
                 int K, int N, long szIn, long szOut)
{
    __shared__ float tile[32][33];
    int z = blockIdx.z;
    in  += (long)z * szIn;
    out += (long)z * szOut;
    int k0 = blockIdx.x * 32, n0 = blockIdx.y * 32;
    int t = threadIdx.x;
    int r = t >> 3, c4 = (t & 7) * 4;
    float4 v = *reinterpret_cast<const float4*>(&in[(long)(k0 + r) * N + n0 + c4]);
    tile[r][c4] = v.x; tile[r][c4 + 1] = v.y; tile[r][c4 + 2] = v.z; tile[r][c4 + 3] = v.w;
    __syncthreads();
    int nr = t >> 3, kq = (t & 7) * 4;
    unsigned short h[4], lo[4];
#pragma unroll
    for (int j = 0; j < 4; ++j) {
        float f = tile[kq + j][nr];
        h[j] = f2bf(f);
        lo[j] = f2bf(f - bf2f(h[j]));
    }
    unsigned short* op = out + (long)(n0 + nr) * (3 * K) + k0 + kq;
    ushort4 hv = make_ushort4(h[0], h[1], h[2], h[3]);
    *reinterpret_cast<ushort4*>(op)         = hv;
    *reinterpret_cast<ushort4*>(op + K)     = hv;
    *reinterpret_cast<ushort4*>(op + 2 * K) = make_ushort4(lo[0], lo[1], lo[2], lo[3]);
}

// ---------------- fp32 K x N -> f16 N x K transpose with scale (V matrix) -------
__global__ __launch_bounds__(256)
void tr_f16_k(const float* __restrict__ in, unsigned short* __restrict__ out,
              int K, int N, float scl)
{
    __shared__ float tile[32][33];
    int k0 = blockIdx.x * 32, n0 = blockIdx.y * 32;
    int t = threadIdx.x;
    int r = t >> 3, c4 = (t & 7) * 4;
    float4 v = *reinterpret_cast<const float4*>(&in[(long)(k0 + r) * N + n0 + c4]);
    tile[r][c4] = v.x; tile[r][c4 + 1] = v.y; tile[r][c4 + 2] = v.z; tile[r][c4 + 3] = v.w;
    __syncthreads();
    int nr = t >> 3, kq = (t & 7) * 4;
    unsigned short h[4];
#pragma unroll
    for (int j = 0; j < 4; ++j) h[j] = f2h(tile[kq + j][nr] * scl);
    *reinterpret_cast<ushort4*>(&out[(long)(n0 + nr) * K + k0 + kq]) =
        make_ushort4(h[0], h[1], h[2], h[3]);
}

// ---------------- 16-bit MFMA GEMM (bf16), split-K partial writer ----------------
__global__ __launch_bounds__(256, 2)
void bgemm_k(const unsigned short* __restrict__ A,
             const unsigned short* __restrict__ B0, const unsigned short* __restrict__ B1,
             const unsigned short* __restrict__ B2,
             int M, int N, int K, int lda, int ldb,
             long sA, int splitk,
             float* __restrict__ Cpart)
{
    constexpr int BKp = 40;
    int tid = threadIdx.x;
    int bz = blockIdx.z;
    int z  = bz / splitk;
    int ks = bz - z * splitk;

    const unsigned short* Ap = A + (long)z * sA + (long)ks * K;
    const unsigned short* Bp = ((z == 1) ? B1 : (z == 2) ? B2 : B0) + (long)ks * K;

    __shared__ unsigned short As[128 * BKp];
    __shared__ unsigned short Bs[128 * BKp];

    int bm = blockIdx.x * 128;
    int bn = blockIdx.y * 128;
    int w = tid >> 6, lane = tid & 63, quad = lane >> 4, l16 = lane & 15;
    int wm = (w >> 1) * 64;
    int wn = (w & 1) * 64;

    int ar = tid >> 1, ac = (tid & 1) * 16;

    f32x4_t acc[4][4] = {};
    bhalf8_t aS0, aS1, bS0, bS1;

    auto ldgA = [&](int k0) {
        const unsigned short* p = Ap + (long)(bm + ar) * lda + k0 + ac;
        aS0 = *reinterpret_cast<const bhalf8_t*>(p);
        aS1 = *reinterpret_cast<const bhalf8_t*>(p + 8);
    };
    auto ldgB = [&](int k0) {
        const unsigned short* p = Bp + (long)(bn + ar) * ldb + k0 + ac;
        bS0 = *reinterpret_cast<const bhalf8_t*>(p);
        bS1 = *reinterpret_cast<const bhalf8_t*>(p + 8);
    };

    ldgA(0); ldgB(0);

    for (int k0 = 0; k0 < K; k0 += 32) {
        *reinterpret_cast<bhalf8_t*>(&As[ar * BKp + ac])     = aS0;
        *reinterpret_cast<bhalf8_t*>(&As[ar * BKp + ac + 8]) = aS1;
        *reinterpret_cast<bhalf8_t*>(&Bs[ar * BKp + ac])     = bS0;
        *reinterpret_cast<bhalf8_t*>(&Bs[ar * BKp + ac + 8]) = bS1;
        __syncthreads();
        if (k0 + 32 < K) { ldgA(k0 + 32); ldgB(k0 + 32); }
        bhalf8_t af[4], bf[4];
#pragma unroll
        for (int i = 0; i < 4; ++i)
            af[i] = *reinterpret_cast<const bhalf8_t*>(&As[(wm + i * 16 + l16) * BKp + quad * 8]);
#pragma unroll
        for (int j = 0; j < 4; ++j)
            bf[j] = *reinterpret_cast<const bhalf8_t*>(&Bs[(wn + j * 16 + l16) * BKp + quad * 8]);
#pragma unroll
        for (int i = 0; i < 4; ++i)
#pragma unroll
            for (int j = 0; j < 4; ++j)
                acc[i][j] = __builtin_amdgcn_mfma_f32_16x16x32_bf16(af[i], bf[j], acc[i][j], 0, 0, 0);
        __syncthreads();
    }

    float* Cp = Cpart + (long)bz * M * N;
#pragma unroll
    for (int i = 0; i < 4; ++i)
#pragma unroll
        for (int j = 0; j < 4; ++j)
#pragma unroll
            for (int r = 0; r < 4; ++r) {
                int m = bm + wm + i * 16 + quad * 4 + r;
                int n = bn + wn + j * 16 + l16;
                Cp[(long)m * N + n] = acc[i][j][r];
            }
}

// ---------------- flash partial: one wave = (16 Q-rows, 128 keys, 1 head) --------
// Bias from precomputed f16 biasmap. Writes partial O (x2^24), rowmax m, rowsum l.
__global__ __launch_bounds__(64)
void flash_part_k(const unsigned short* __restrict__ qb3, const unsigned short* __restrict__ kb3,
                  const unsigned short* __restrict__ vtb, const unsigned short* __restrict__ bmap,
                  float* __restrict__ po, float* __restrict__ pm, float* __restrict__ pl)
{
    __shared__ unsigned short Ps[16 * 136];

    int tid = threadIdx.x;          // 0..63
    int qb = blockIdx.x;            // 64 Q-blocks of 16 rows
    int h  = blockIdx.y;            // 8 heads
    int z  = blockIdx.z;            // 8 key-slices of 128
    int bm = qb * 16;
    int k0 = z * 128;

    const unsigned short* Qh = qb3 + (long)h * 196608;
    const unsigned short* Kh = kb3 + (long)h * 196608;
    const unsigned short* Vh = vtb + (long)h * 65536;
    const unsigned short* Bm = bmap + (long)h * 1048576;

    int quad = tid >> 4, l16 = tid & 15;

    // Q fragments (rows bm..bm+15, K=192 3-split)
    bhalf8_t aq[6];
#pragma unroll
    for (int kq = 0; kq < 6; ++kq)
        aq[kq] = *reinterpret_cast<const bhalf8_t*>(
            &Qh[(long)(bm + l16) * 192 + kq * 32 + quad * 8]);

    // QK^T: scores 16x128, K fragments straight from global (L2-hot)
    f32x4_t sacc[8] = {};
#pragma unroll
    for (int kq = 0; kq < 6; ++kq) {
        bhalf8_t bk[8];
#pragma unroll
        for (int nb = 0; nb < 8; ++nb)
            bk[nb] = *reinterpret_cast<const bhalf8_t*>(
                &Kh[(long)(k0 + nb * 16 + l16) * 192 + kq * 32 + quad * 8]);
#pragma unroll
        for (int nb = 0; nb < 8; ++nb)
            sacc[nb] = __builtin_amdgcn_mfma_f32_16x16x32_bf16(aq[kq], bk[nb], sacc[nb], 0, 0, 0);
    }

    // scale + bias (from f16 map), row max over 128 cols
    float m_r[4] = {-3.0e38f, -3.0e38f, -3.0e38f, -3.0e38f};
#pragma unroll
    for (int nb = 0; nb < 8; ++nb)
#pragma unroll
        for (int r = 0; r < 4; ++r) {
            int gm = bm + quad * 4 + r;
            int gn = k0 + nb * 16 + l16;
            float bias = h2f(Bm[(long)gm * kS + gn]);
            float s = fmaf(sacc[nb][r], 0.125f, bias);
            sacc[nb][r] = s;
            m_r[r] = fmaxf(m_r[r], s);
        }
#pragma unroll
    for (int r = 0; r < 4; ++r) {
        float m_ = m_r[r];
#pragma unroll
        for (int off = 1; off < 16; off <<= 1) m_ = fmaxf(m_, __shfl_xor(m_, off, 64));
        m_r[r] = m_;
    }

    // P = exp(s-m) -> LDS (x2^14 f16), row sums
    float l_r[4];
#pragma unroll
    for (int r = 0; r < 4; ++r) {
        int row = quad * 4 + r;
        float mN = m_r[r];
        float s_ = 0.f;
#pragma unroll
        for (int nb = 0; nb < 8; ++nb) {
            float p = __expf(sacc[nb][r] - mN);
            Ps[row * 136 + nb * 16 + l16] = f2h(p * 16384.f);
            s_ += p;
        }
#pragma unroll
        for (int off = 1; off < 16; off <<= 1) s_ += __shfl_xor(s_, off, 64);
        l_r[r] = s_;
    }

    long sbase = (((long)z * 8 + h) * 64 + qb) * 16;   // per-z stride 8192
    if (l16 == 0) {
#pragma unroll
        for (int r = 0; r < 4; ++r) {
            pm[sbase + quad * 4 + r] = m_r[r];
            pl[sbase + quad * 4 + r] = l_r[r];
        }
    }
    __syncthreads();

    // PV: O(16x64) = P(16x128) @ V-slice, f16 MFMA, V from global
    f32x4_t oacc[4] = {};
#pragma unroll
    for (int kq2 = 0; kq2 < 4; ++kq2) {
        bhalf8_t ap = *reinterpret_cast<const bhalf8_t*>(&Ps[l16 * 136 + kq2 * 32 + quad * 8]);
#pragma unroll
        for (int j2 = 0; j2 < 4; ++j2) {
            bhalf8_t bv = *reinterpret_cast<const bhalf8_t*>(
                &Vh[(long)(j2 * 16 + l16) * 1024 + k0 + kq2 * 32 + quad * 8]);
            oacc[j2] = __builtin_amdgcn_mfma_f32_16x16x32_f16(
                __builtin_bit_cast(half8_t, ap), __builtin_bit_cast(half8_t, bv),
                oacc[j2], 0, 0, 0);
        }
    }

    float* pob = po + sbase * 64;
#pragma unroll
    for (int j2 = 0; j2 < 4; ++j2)
#pragma unroll
        for (int r = 0; r < 4; ++r)
            pob[(quad * 4 + r) * 64 + j2 * 16 + l16] = oacc[j2][r];
}

// ---------------- flash merge: combine 8 key-slice partials, write aob 3-split ---
__global__ __launch_bounds__(256)
void flash_merge_k(const float* __restrict__ po, const float* __restrict__ pm,
                   const float* __restrict__ pl, unsigned short* __restrict__ aob)
{
    int t = blockIdx.x * 256 + threadIdx.x;   // 65536 = 8h * 64qb * 16row * 8chunks
    int c8  = t & 7;
    int row = (t >> 3) & 15;
    int qb  = (t >> 7) & 63;
    int h   = t >> 13;
    long sidx = (((long)h * 64) + qb) * 16 + row;   // per-z stride 8192

    float m[8];
    float M = -3.0e38f;
#pragma unroll
    for (int z = 0; z < 8; ++z) { m[z] = pm[z * 8192 + sidx]; M = fmaxf(M, m[z]); }
    float w[8], lt = 0.f;
#pragma unroll
    for (int z = 0; z < 8; ++z) {
        w[z] = __expf(m[z] - M);
        lt = fmaf(pl[z * 8192 + sidx], w[z], lt);
    }
    float acc[8] = {};
#pragma unroll
    for (int z = 0; z < 8; ++z) {
        const float* p = po + (z * 8192 + sidx) * 64 + c8 * 8;
        float4 a = *reinterpret_cast<const float4*>(p);
        float4 b = *reinterpret_cast<const float4*>(p + 4);
        acc[0] = fmaf(a.x, w[z], acc[0]); acc[1] = fmaf(a.y, w[z], acc[1]);
        acc[2] = fmaf(a.z, w[z], acc[2]); acc[3] = fmaf(a.w, w[z], acc[3]);
        acc[4] = fmaf(b.x, w[z], acc[4]); acc[5] = fmaf(b.y, w[z], acc[5]);
        acc[6] = fmaf(b.z, w[z], acc[6]); acc[7] = fmaf(b.w, w[z], acc[7]);
    }
    float inv = 1.f / (16777216.f * lt);
    unsigned short hi[8], lo[8];
#pragma unroll
    for (int j = 0; j < 8; ++j) {
        float val = acc[j] * inv;
        hi[j] = f2bf(val);
        lo[j] = f2bf(val - bf2f(hi[j]));
    }
    long base = ((long)qb * 16 + row) * 1536 + h * 64 + c8 * 8;
    *reinterpret_cast<ushort4*>(&aob[base])        = make_ushort4(hi[0], hi[1], hi[2], hi[3]);
    *reinterpret_cast<ushort4*>(&aob[base + 4])    = make_ushort4(hi[4], hi[5], hi[6], hi[7]);
    *reinterpret_cast<ushort4*>(&aob[base + 512])  = make_ushort4(lo[0], lo[1], lo[2], lo[3]);
    *reinterpret_cast<ushort4*>(&aob[base + 516])  = make_ushort4(lo[4], lo[5], lo[6], lo[7]);
    *reinterpret_cast<ushort4*>(&aob[base + 1024]) = make_ushort4(hi[0], hi[1], hi[2], hi[3]);
    *reinterpret_cast<ushort4*>(&aob[base + 1028]) = make_ushort4(hi[4], hi[5], hi[6], hi[7]);
}

// ---------------- QKV split-K reduce: bias + direct 3-split to qb3/kb3, v f32 ----
__global__ __launch_bounds__(256)
void reduce_qkv_k(const float* __restrict__ part,
                  unsigned short* __restrict__ qb3, unsigned short* __restrict__ kb3,
                  float* __restrict__ v,
                  const float* __restrict__ qbias, const float* __restrict__ kbias,
                  const float* __restrict__ vbias)
{
    int z = blockIdx.y;
    const long MN = (long)kS * kD;
    long idx = ((long)blockIdx.x * 256 + threadIdx.x) * 4;
    const float* pz = part + (long)z * 4 * MN + idx;
    float4 s = *reinterpret_cast<const float4*>(pz);
#pragma unroll
    for (int t = 1; t < 4; ++t) {
        float4 vv = *reinterpret_cast<const float4*>(pz + (long)t * MN);
        s.x += vv.x; s.y += vv.y; s.z += vv.z; s.w += vv.w;
    }
    int m = (int)(idx >> 9), n = (int)(idx & 511);
    const float* bzp = (z == 1) ? kbias : (z == 2) ? vbias : qbias;
    s.x += bzp[n]; s.y += bzp[n + 1]; s.z += bzp[n + 2]; s.w += bzp[n + 3];
    if (z == 2) {
        *reinterpret_cast<float4*>(v + idx) = s;
        return;
    }
    float fv[4] = {s.x, s.y, s.z, s.w};
    unsigned short h[4], lo[4];
#pragma unroll
    for (int j = 0; j < 4; ++j) {
        h[j] = f2bf(fv[j]);
        lo[j] = f2bf(fv[j] - bf2f(h[j]));
    }
    int head = n >> 6, hc = n & 63;
    unsigned short* dst = ((z == 1) ? kb3 : qb3) + (long)head * 196608 + (long)m * 192 + hc;
    ushort4 hv = make_ushort4(h[0], h[1], h[2], h[3]);
    ushort4 lv = make_ushort4(lo[0], lo[1], lo[2], lo[3]);
    *reinterpret_cast<ushort4*>(dst) = hv;
    if (z == 0) {  // A-side [hi|lo|hi]
        *reinterpret_cast<ushort4*>(dst + 64)  = lv;
        *reinterpret_cast<ushort4*>(dst + 128) = hv;
    } else {       // B-side [hi|hi|lo]
        *reinterpret_cast<ushort4*>(dst + 64)  = hv;
        *reinterpret_cast<ushort4*>(dst + 128) = lv;
    }
}

// ---------------- generic split-K reduce -> f32 (+bias) ----------------
__global__ __launch_bounds__(256)
void reduce_k(const float* __restrict__ part, float* __restrict__ C,
              const float* __restrict__ bias, int N, int splitk)
{
    const long MN = (long)kS * N;
    long idx = ((long)blockIdx.x * 256 + threadIdx.x) * 4;
    const float* pz = part + idx;
    float4 s = *reinterpret_cast<const float4*>(pz);
    for (int t = 1; t < splitk; ++t) {
        float4 v = *reinterpret_cast<const float4*>(pz + (long)t * MN);
        s.x += v.x; s.y += v.y; s.z += v.z; s.w += v.w;
    }
    int n = (int)(idx % N);
    s.x += bias[n]; s.y += bias[n + 1]; s.z += bias[n + 2]; s.w += bias[n + 3];
    *reinterpret_cast<float4*>(C + idx) = s;
}

// ---------------- FFN1 reduce: bias + relu + direct 3-split to hb ----------------
__global__ __launch_bounds__(256)
void reduce3_k(const float* __restrict__ part, unsigned short* __restrict__ hb,
               const float* __restrict__ bias, int splitk)
{
    const long MN = (long)kS * kDFF;
    long idx = ((long)blockIdx.x * 256 + threadIdx.x) * 4;
    const float* pz = part + idx;
    float4 s = *reinterpret_cast<const float4*>(pz);
    for (int t = 1; t < splitk; ++t) {
        float4 v = *reinterpret_cast<const float4*>(pz + (long)t * MN);
        s.x += v.x; s.y += v.y; s.z += v.z; s.w += v.w;
    }
    int m = (int)(idx >> 11), n = (int)(idx & 2047);
    float fv[4] = {fmaxf(s.x + bias[n], 0.f), fmaxf(s.y + bias[n + 1], 0.f),
                   fmaxf(s.z + bias[n + 2], 0.f), fmaxf(s.w + bias[n + 3], 0.f)};
    unsigned short h[4], lo[4];
#pragma unroll
    for (int j = 0; j < 4; ++j) {
        h[j] = f2bf(fv[j]);
        lo[j] = f2bf(fv[j] - bf2f(h[j]));
    }
    unsigned short* dst = hb + (long)m * 6144 + n;
    ushort4 hv = make_ushort4(h[0], h[1], h[2], h[3]);
    *reinterpret_cast<ushort4*>(dst)        = hv;
    *reinterpret_cast<ushort4*>(dst + 2048) = make_ushort4(lo[0], lo[1], lo[2], lo[3]);
    *reinterpret_cast<ushort4*>(dst + 4096) = hv;
}

// ---------------- residual add + layernorm (in place on x, + 3-split xb) --------
__global__ __launch_bounds__(256)
void add_ln_k(float* __restrict__ x, const float* __restrict__ y,
              const float* __restrict__ g, const float* __restrict__ b,
              unsigned short* __restrict__ xb)
{
    __shared__ float sm[4];
    int row = blockIdx.x, t = threadIdx.x;
    float* xr = x + (long)row * kD;
    const float* yr = y + (long)row * kD;
    float s0 = xr[t] + yr[t];
    float s1 = xr[t + 256] + yr[t + 256];
    float sum = wave_sum(s0 + s1);
    if ((t & 63) == 0) sm[t >> 6] = sum;
    __syncthreads();
    sum = sm[0] + sm[1] + sm[2] + sm[3];
    float mu = sum * (1.f / kD);
    float d0 = s0 - mu, d1 = s1 - mu;
    __syncthreads();
    float vs = wave_sum(d0 * d0 + d1 * d1);
    if ((t & 63) == 0) sm[t >> 6] = vs;
    __syncthreads();
    vs = sm[0] + sm[1] + sm[2] + sm[3];
    float rs = rsqrtf(vs * (1.f / kD) + 1e-5f);
    float o0 = fmaf(d0 * rs, g[t], b[t]);
    float o1 = fmaf(d1 * rs, g[t + 256], b[t + 256]);
    xr[t]       = o0;
    xr[t + 256] = o1;
    unsigned short h0 = f2bf(o0), l0 = f2bf(o0 - bf2f(h0));
    unsigned short h1 = f2bf(o1), l1 = f2bf(o1 - bf2f(h1));
    unsigned short* xrow = xb + (long)row * 1536;
    xrow[t]            = h0;  xrow[t + 256]        = h1;
    xrow[t + 512]      = l0;  xrow[t + 768]        = l1;
    xrow[t + 1024]     = h0;  xrow[t + 1280]       = h1;
}

// ---------------- mean-pool partials ----------------
__global__ __launch_bounds__(256)
void pool_k(const float* __restrict__ x, float* __restrict__ partial)
{
    int col = blockIdx.x * 256 + threadIdx.x;
    int rb = blockIdx.y;
    float s = 0.f;
    for (int r = rb * 128; r < rb * 128 + 128; ++r) s += x[(long)r * kD + col];
    partial[rb * kD + col] = s;
}

// ---------------- classifier head ----------------
__global__ __launch_bounds__(256)
void head_k(const float* __restrict__ partial,
            const float* __restrict__ c1w, const float* __restrict__ c1b,
            const float* __restrict__ c2w, const float* __restrict__ c2b,
            float* __restrict__ out)
{
    __shared__ float pooled[kD];
    __shared__ float h1[256];
    int t = threadIdx.x;
    for (int d = t; d < kD; d += 256) {
        float s = 0.f;
        for (int r = 0; r < 8; ++r) s += partial[r * kD + d];
        pooled[d] = s * (1.0f / kS);
    }
    __syncthreads();
    float acc = c1b[t];
    for (int f = 0; f < kD; ++f) acc = fmaf(pooled[f], c1w[f * 256 + t], acc);
    h1[t] = fmaxf(acc, 0.f);
    __syncthreads();
    if (t < 10) {
        float o = c2b[t];
        for (int f = 0; f < 256; ++f) o = fmaf(h1[f], c2w[f * 10 + t], o);
        out[t] = o;
    }
}

// ---------------- launch ----------------
extern "C" void kernel_launch(void* const* d_in, const int* in_sizes, int n_in,
                              void* d_out, int out_size, void* d_ws, size_t ws_size,
                              hipStream_t stream)
{
    (void)in_sizes; (void)n_in; (void)out_size; (void)ws_size;
    const float* features = (const float*)d_in[0];
    const float* positions= (const float*)d_in[1];
    const float* fb       = (const float*)d_in[2];
    const float* in_w     = (const float*)d_in[3];
    const float* in_b     = (const float*)d_in[4];
    const float* qw  = (const float*)d_in[5];
    const float* qb  = (const float*)d_in[6];
    const float* kw  = (const float*)d_in[7];
    const float* kb  = (const float*)d_in[8];
    const float* vw  = (const float*)d_in[9];
    const float* vb  = (const float*)d_in[10];
    const float* ow  = (const float*)d_in[11];
    const float* ob  = (const float*)d_in[12];
    const float* db1w= (const float*)d_in[13];
    const float* db1b= (const float*)d_in[14];
    const float* db2w= (const float*)d_in[15];
    const float* db2b= (const float*)d_in[16];
    const float* n1g = (const float*)d_in[17];
    const float* n1b = (const float*)d_in[18];
    const float* n2g = (const float*)d_in[19];
    const float* n2b = (const float*)d_in[20];
    const float* f1w = (const float*)d_in[21];
    const float* f1b = (const float*)d_in[22];
    const float* f2w = (const float*)d_in[23];
    const float* f2b = (const float*)d_in[24];
    const float* c1w = (const float*)d_in[25];
    const float* c1b = (const float*)d_in[26];
    const float* c2w = (const float*)d_in[27];
    const float* c2b = (const float*)d_in[28];

    float* ws = (float*)d_ws;
    const long SD = (long)kS * kD;            // 524288
    float* x      = ws;
    float* v      = ws + 1 * SD;
    float* y      = ws + 2 * SD;
    float* dist   = ws + 3 * SD;              // 2*SD
    float* part   = ws + 5 * SD;              // 12*SD scratch (QKV partials / flash partials)
    float* bpw    = ws + 17 * SD;
    float* Atab   = bpw + 256;
    float* Btab   = Atab + 2080;
    float* partial= Btab + 2080;

    // flash partial overlays inside `part` (dead between QKV-reduce and O-proj)
    float* po = part;                          // 8*8*64*16*64 = 4,194,304 floats
    float* pmv = part + 4194304;               // 65536
    float* plv = pmv + 65536;                  // 65536

    unsigned short* ub = (unsigned short*)(ws + 17 * SD + 8512);
    unsigned short* xb   = ub;                       // 1024*1536
    unsigned short* aob  = xb   + 1572864;           // 1024*1536
    unsigned short* qb3  = aob  + 1572864;           // 8*1024*192
    unsigned short* kb3  = qb3  + 1572864;
    unsigned short* vtb  = kb3  + 1572864;           // 512*1024 (f16)
    unsigned short* hb   = vtb  + 524288;            // 1024*6144
    unsigned short* qwb  = hb   + 6291456;           // 2 x 512*1536
    unsigned short* kwb  = qwb  + 1572864;
    unsigned short* vwb  = kwb  + 1572864;
    unsigned short* owb  = vwb  + 1572864;
    unsigned short* f1wb = owb  + 1572864;           // 2 x 2048*1536
    unsigned short* f2wb = f1wb + 6291456;           // 2 x 512*6144
    unsigned short* bmap = f2wb + 6291456;           // 8*1024*1024 f16 bias map

    input_pe_k<<<kS, 256, 0, stream>>>(features, positions, fb, in_w, in_b, x);
    dist_k<<<kS, 256, 0, stream>>>(positions, dist);
    pwl_build_k<<<2, 256, 0, stream>>>(db1w, db1b, db2w, db2b, bpw, Atab, Btab);
    split3_rm_k<<<512, 256, 0, stream>>>(x, xb, 524288, 9, 512);

    split3_tr_k<<<dim3(16, 16, 2), 256, 0, stream>>>(qw, qwb, 512, 512, 262144, 786432);
    split3_tr_k<<<dim3(16, 16, 2), 256, 0, stream>>>(kw, kwb, 512, 512, 262144, 786432);
    split3_tr_k<<<dim3(16, 16, 2), 256, 0, stream>>>(vw, vwb, 512, 512, 262144, 786432);
    split3_tr_k<<<dim3(16, 16, 2), 256, 0, stream>>>(ow, owb, 512, 512, 262144, 786432);
    split3_tr_k<<<dim3(16, 64, 2), 256, 0, stream>>>(f1w, f1wb, 512, 2048, 1048576, 3145728);
    split3_tr_k<<<dim3(64, 16, 2), 256, 0, stream>>>(f2w, f2wb, 2048, 512, 1048576, 3145728);

    for (int l = 0; l < 2; ++l) {
        // per-layer bias map (f16) — hoists PWL out of flash
        biasmap_k<<<dim3(1024, 8), 256, 0, stream>>>(
            dist, bpw + l * 128, Atab + l * 1040, Btab + l * 1040, bmap);

        // QKV: A=xb (1024x1536), split-K x4 -> partials; reduce fuses bias + q/k 3-split
        bgemm_k<<<dim3(8, 4, 12), 256, 0, stream>>>(
            xb, qwb + l * 786432, kwb + l * 786432, vwb + l * 786432,
            1024, 512, 384, 1536, 1536, 0, 4, part);
        reduce_qkv_k<<<dim3(512, 3), 256, 0, stream>>>(
            part, qb3, kb3, v, qb + l * kD, kb + l * kD, vb + l * kD);
        tr_f16_k<<<dim3(32, 16), 256, 0, stream>>>(v, vtb, 1024, 512, 1024.f);

        // fused attention: K-split partials + merge -> aob (3-split)
        flash_part_k<<<dim3(64, 8, 8), 64, 0, stream>>>(
            qb3, kb3, vtb, bmap, po, pmv, plv);
        flash_merge_k<<<256, 256, 0, stream>>>(po, pmv, plv, aob);

        // O-proj: split-K x8
        bgemm_k<<<dim3(8, 4, 8), 256, 0, stream>>>(
            aob, owb + l * 786432, owb + l * 786432, owb + l * 786432,
            1024, 512, 192, 1536, 1536, 0, 8, part);
        reduce_k<<<512, 256, 0, stream>>>(part, y, ob + l * kD, 512, 8);
        add_ln_k<<<kS, 256, 0, stream>>>(x, y, n1g + l * kD, n1b + l * kD, xb);

        // FFN1: split-K x2, reduce fuses bias+relu+3-split -> hb
        bgemm_k<<<dim3(8, 16, 2), 256, 0, stream>>>(
            xb, f1wb + l * 3145728, f1wb + l * 3145728, f1wb + l * 3145728,
            1024, 2048, 768, 1536, 1536, 0, 2, part);
        reduce3_k<<<2048, 256, 0, stream>>>(part, hb, f1b + l * kDFF, 2);

        // FFN2: split-K x8
        bgemm_k<<<dim3(8, 4, 8), 256, 0, stream>>>(
            hb, f2wb + l * 3145728, f2wb + l * 3145728, f2wb + l * 3145728,
            1024, 512, 768, 6144, 6144, 0, 8, part);
        reduce_k<<<512, 256, 0, stream>>>(part, y, f2b + l * kD, 512, 8);
        add_ln_k<<<kS, 256, 0, stream>>>(x, y, n2g + l * kD, n2b + l * kD, xb);
    }

    pool_k<<<dim3(2, 8), 256, 0, stream>>>(x, partial);
    head_k<<<1, 256, 0, stream>>>(partial, c1w, c1b, c2w, c2b, (float*)d_out);
}

// Round 10
// 492.425 us; speedup vs baseline: 1.2656x; 1.1163x over previous
//
#include <hip/hip_runtime.h>

namespace {
constexpr int kS   = 1024;
constexpr int kD   = 512;
constexpr int kH   = 8;
constexpr int kDFF = 2048;
constexpr int kNF  = 85;   // D//6
}

typedef __attribute__((ext_vector_type(8))) short bhalf8_t;    // 8x16-bit in 4 VGPRs
typedef _Float16 half8_t __attribute__((ext_vector_type(8)));
typedef __attribute__((ext_vector_type(4))) float f32x4_t;

// ---------------- helpers ----------------
__device__ __forceinline__ float wave_sum(float v) {
#pragma unroll
    for (int o = 1; o < 64; o <<= 1) v += __shfl_xor(v, o, 64);
    return v;
}
__device__ __forceinline__ unsigned short f2bf(float f) {   // RNE fp32->bf16
    unsigned u = __float_as_uint(f);
    u = (u + 0x7FFF + ((u >> 16) & 1)) >> 16;
    return (unsigned short)u;
}
__device__ __forceinline__ float bf2f(unsigned short h) {
    return __uint_as_float(((unsigned)h) << 16);
}
__device__ __forceinline__ unsigned short f2h(float f) {    // RNE fp32->fp16
    _Float16 h = (_Float16)f;
    return __builtin_bit_cast(unsigned short, h);
}
__device__ __forceinline__ float h2f(unsigned short u) {
    return (float)__builtin_bit_cast(_Float16, u);
}

// ---------------- input projection + positional encoding ----------------
__global__ __launch_bounds__(256)
void input_pe_k(const float* __restrict__ feat, const float* __restrict__ pos,
                const float* __restrict__ fb, const float* __restrict__ in_w,
                const float* __restrict__ in_b, float* __restrict__ x)
{
    int s = blockIdx.x;
    int t = threadIdx.x;
    __shared__ float f[64];
    if (t < 64) f[t] = feat[s * 64 + t];
    __syncthreads();
    float acc0 = in_b[t], acc1 = in_b[t + 256];
#pragma unroll 8
    for (int c = 0; c < 64; ++c) {
        float fv = f[c];
        acc0 = fmaf(fv, in_w[c * kD + t], acc0);
        acc1 = fmaf(fv, in_w[c * kD + 256 + t], acc1);
    }
    float pe0 = 0.f, pe1 = 0.f;
    {
        int d = t;
        if (d < 6 * kNF) {
            int seg = d / kNF, idx = d - seg * kNF;
            float cs = pos[s * 3 + (seg >> 1)] * fb[idx];
            pe0 = (seg & 1) ? cosf(cs) : sinf(cs);
        }
        d = t + 256;
        if (d < 6 * kNF) {
            int seg = d / kNF, idx = d - seg * kNF;
            float cs = pos[s * 3 + (seg >> 1)] * fb[idx];
            pe1 = (seg & 1) ? cosf(cs) : sinf(cs);
        }
    }
    x[s * kD + t]       = acc0 + pe0;
    x[s * kD + 256 + t] = acc1 + pe1;
}

// ---------------- pairwise distance matrix ----------------
__global__ __launch_bounds__(256)
void dist_k(const float* __restrict__ pos, float* __restrict__ dist)
{
    int i = blockIdx.x;
    float px = pos[i * 3], py = pos[i * 3 + 1], pz = pos[i * 3 + 2];
    for (int j = threadIdx.x; j < kS; j += 256) {
        float dx = px - pos[j * 3], dy = py - pos[j * 3 + 1], dz = pz - pos[j * 3 + 2];
        float sq = dx * dx + dy * dy + dz * dz;
        dist[(long)i * kS + j] = sq > 0.f ? sqrtf(sq) : 0.f;
    }
}

// ---------------- PWL: sort breakpoints only (tiny) ----------------
__global__ __launch_bounds__(128)
void pwl_sort_k(const float* __restrict__ a_, const float* __restrict__ b_,
                float* __restrict__ bp_out)
{
    int l = blockIdx.x;
    a_ += l * 128; b_ += l * 128; bp_out += l * 128;
    __shared__ float key[128];
    int t = threadIdx.x;
    float a = a_[t], b = b_[t];
    key[t] = (a != 0.f) ? (-b / a) : 3.0e38f;
    __syncthreads();
    for (int ksz = 2; ksz <= 128; ksz <<= 1) {
        for (int j = ksz >> 1; j > 0; j >>= 1) {
            int ixj = t ^ j;
            if (ixj > t) {
                bool up = ((t & ksz) == 0);
                float x0 = key[t], x1 = key[ixj];
                if ((x0 > x1) == up) { key[t] = x1; key[ixj] = x0; }
            }
            __syncthreads();
        }
    }
    bp_out[t] = key[t];
}

// ---------------- PWL: per-segment table build, parallel over (seg, layer) ------
// block = 256: thread t handles head h = t&7, channel-group cg = t>>3 (4 ch each);
// shuffle + LDS reduce over the 32 groups.
__global__ __launch_bounds__(256)
void pwl_tab_k(const float* __restrict__ a_, const float* __restrict__ b_,
               const float* __restrict__ w2, const float* __restrict__ b2,
               const float* __restrict__ bp, float* __restrict__ Atab,
               float* __restrict__ Btab)
{
    int l = blockIdx.y;
    int seg = blockIdx.x;   // 0..128
    a_ += l * 128; b_ += l * 128; w2 += l * 1024; b2 += l * 8;
    bp += l * 128; Atab += l * 1040; Btab += l * 1040;

    float m;
    if (seg == 0)        m = bp[0] - 1.0f;
    else if (seg == 128) m = bp[127] + 1.0f;
    else                 m = 0.5f * (bp[seg - 1] + bp[seg]);

    int t = threadIdx.x;
    int h = t & 7, cg = t >> 3;   // cg 0..31
    float A = 0.f, B = 0.f;
#pragma unroll
    for (int j = 0; j < 4; ++j) {
        int c = cg * 4 + j;
        float a = a_[c], b = b_[c];
        if (fmaf(a, m, b) > 0.f) {
            float w = w2[c * 8 + h];
            A = fmaf(a, w, A);
            B = fmaf(b, w, B);
        }
    }
#pragma unroll
    for (int off = 8; off < 64; off <<= 1) {
        A += __shfl_xor(A, off, 64);
        B += __shfl_xor(B, off, 64);
    }
    __shared__ float sA[4][8], sB[4][8];
    int w = t >> 6, lane = t & 63;
    if (lane < 8) { sA[w][lane] = A; sB[w][lane] = B; }
    __syncthreads();
    if (t < 8) {
        float At = sA[0][t] + sA[1][t] + sA[2][t] + sA[3][t];
        float Bt = sB[0][t] + sB[1][t] + sB[2][t] + sB[3][t];
        Atab[seg * 8 + t] = At;
        Btab[seg * 8 + t] = Bt + b2[t];
    }
}

// ---------------- per-layer bias map: one search -> all 8 heads ----------------
__global__ __launch_bounds__(256)
void biasmap_k(const float* __restrict__ dist, const float* __restrict__ bp,
               const float* __restrict__ Atab, const float* __restrict__ Btab,
               unsigned short* __restrict__ bmap)
{
    __shared__ float bps[128], Ah[1032], Bh[1032];
    int t = threadIdx.x;
    if (t < 128) bps[t] = bp[t];
    for (int i = t; i < 1032; i += 256) { Ah[i] = Atab[i]; Bh[i] = Btab[i]; }
    __syncthreads();
    long i = ((long)blockIdx.x * 256 + t) * 4;
    float4 d4 = *reinterpret_cast<const float4*>(dist + i);
    float dv[4] = {d4.x, d4.y, d4.z, d4.w};
    int seg[4];
#pragma unroll
    for (int j = 0; j < 4; ++j) {
        float tv = dv[j];
        int lo = 0, hi = 128;
        while (lo < hi) { int mid = (lo + hi) >> 1; if (bps[mid] < tv) lo = mid + 1; else hi = mid; }
        seg[j] = lo;
    }
#pragma unroll
    for (int h = 0; h < 8; ++h) {
        unsigned short o[4];
#pragma unroll
        for (int j = 0; j < 4; ++j)
            o[j] = f2h(fmaf(Ah[seg[j] * 8 + h], dv[j], Bh[seg[j] * 8 + h]));
        *reinterpret_cast<ushort4*>(bmap + (long)h * 1048576 + i) =
            make_ushort4(o[0], o[1], o[2], o[3]);
    }
}

// ---------------- fp32 -> bf16 3-term split, row-major (order0 [hi|lo|hi]) ------
__global__ __launch_bounds__(256)
void split3_rm_k(const float* __restrict__ in, unsigned short* __restrict__ out,
                 int total, int kshift, int ldin)
{
    long i = ((long)blockIdx.x * 256 + threadIdx.x) * 4;
    if (i >= total) return;
    int K = 1 << kshift;
    int m = (int)(i >> kshift), k = (int)(i & (K - 1));
    float4 v = *reinterpret_cast<const float4*>(in + (long)m * ldin + k);
    unsigned short h[4], lo[4];
    float fv[4] = {v.x, v.y, v.z, v.w};
#pragma unroll
    for (int j = 0; j < 4; ++j) {
        h[j] = f2bf(fv[j]);
        lo[j] = f2bf(fv[j] - bf2f(h[j]));
    }
    unsigned short* op = out + (long)m * (3 * K) + k;
    ushort4 hv = make_ushort4(h[0], h[1], h[2], h[3]);
    *reinterpret_cast<ushort4*>(op)         = hv;
    *reinterpret_cast<ushort4*>(op + K)     = make_ushort4(lo[0], lo[1], lo[2], lo[3]);
    *reinterpret_cast<ushort4*>(op + 2 * K) = hv;
}

// ---------------- fp32 K x N -> bf16 N x 3K transpose-split (weights, [hi|hi|lo]) --
__global__ __launch_bounds__(256)
void split3_tr_k(const float* __restrict__ in, unsigned short* __restrict__ out,
                 int K, int N, long szIn, long szOut)
{
    __shared__ float tile[32][33];
    int z = blockIdx.z;
    in  += (long)z * szIn;
    out += (long)z * szOut;
    int k0 = blockIdx.x * 32, n0 = blockIdx.y * 32;
    int t = threadIdx.x;
    int r = t >> 3, c4 = (t & 7) * 4;
    float4 v = *reinterpret_cast<const float4*>(&in[(long)(k0 + r) * N + n0 + c4]);
    tile[r][c4] = v.x; tile[r][c4 + 1] = v.y; tile[r][c4 + 2] = v.z; tile[r][c4 + 3] = v.w;
    __syncthreads();
    int nr = t >> 3, kq = (t & 7) * 4;
    unsigned short h[4], lo[4];
#pragma unroll
    for (int j = 0; j < 4; ++j) {
        float f = tile[kq + j][nr];
        h[j] = f2bf(f);
        lo[j] = f2bf(f - bf2f(h[j]));
    }
    unsigned short* op = out + (long)(n0 + nr) * (3 * K) + k0 + kq;
    ushort4 hv = make_ushort4(h[0], h[1], h[2], h[3]);
    *reinterpret_cast<ushort4*>(op)         = hv;
    *reinterpret_cast<ushort4*>(op + K)     = hv;
    *reinterpret_cast<ushort4*>(op + 2 * K) = make_ushort4(lo[0], lo[1], lo[2], lo[3]);
}

// ---------------- fp32 K x N -> f16 N x K transpose with scale (V matrix) -------
__global__ __launch_bounds__(256)
void tr_f16_k(const float* __restrict__ in, unsigned short* __restrict__ out,
              int K, int N, float scl)
{
    __shared__ float tile[32][33];
    int k0 = blockIdx.x * 32, n0 = blockIdx.y * 32;
    int t = threadIdx.x;
    int r = t >> 3, c4 = (t & 7) * 4;
    float4 v = *reinterpret_cast<const float4*>(&in[(long)(k0 + r) * N + n0 + c4]);
    tile[r][c4] = v.x; tile[r][c4 + 1] = v.y; tile[r][c4 + 2] = v.z; tile[r][c4 + 3] = v.w;
    __syncthreads();
    int nr = t >> 3, kq = (t & 7) * 4;
    unsigned short h[4];
#pragma unroll
    for (int j = 0; j < 4; ++j) h[j] = f2h(tile[kq + j][nr] * scl);
    *reinterpret_cast<ushort4*>(&out[(long)(n0 + nr) * K + k0 + kq]) =
        make_ushort4(h[0], h[1], h[2], h[3]);
}

// ---------------- 16-bit MFMA GEMM (bf16), split-K partial writer ----------------
__global__ __launch_bounds__(256, 2)
void bgemm_k(const unsigned short* __restrict__ A,
             const unsigned short* __restrict__ B0, const unsigned short* __restrict__ B1,
             const unsigned short* __restrict__ B2,
             int M, int N, int K, int lda, int ldb,
             long sA, int splitk,
             float* __restrict__ Cpart)
{
    constexpr int BKp = 40;
    int tid = threadIdx.x;
    int bz = blockIdx.z;
    int z  = bz / splitk;
    int ks = bz - z * splitk;

    const unsigned short* Ap = A + (long)z * sA + (long)ks * K;
    const unsigned short* Bp = ((z == 1) ? B1 : (z == 2) ? B2 : B0) + (long)ks * K;

    __shared__ unsigned short As[128 * BKp];
    __shared__ unsigned short Bs[128 * BKp];

    int bm = blockIdx.x * 128;
    int bn = blockIdx.y * 128;
    int w = tid >> 6, lane = tid & 63, quad = lane >> 4, l16 = lane & 15;
    int wm = (w >> 1) * 64;
    int wn = (w & 1) * 64;

    int ar = tid >> 1, ac = (tid & 1) * 16;

    f32x4_t acc[4][4] = {};
    bhalf8_t aS0, aS1, bS0, bS1;

    auto ldgA = [&](int k0) {
        const unsigned short* p = Ap + (long)(bm + ar) * lda + k0 + ac;
        aS0 = *reinterpret_cast<const bhalf8_t*>(p);
        aS1 = *reinterpret_cast<const bhalf8_t*>(p + 8);
    };
    auto ldgB = [&](int k0) {
        const unsigned short* p = Bp + (long)(bn + ar) * ldb + k0 + ac;
        bS0 = *reinterpret_cast<const bhalf8_t*>(p);
        bS1 = *reinterpret_cast<const bhalf8_t*>(p + 8);
    };

    ldgA(0); ldgB(0);

    for (int k0 = 0; k0 < K; k0 += 32) {
        *reinterpret_cast<bhalf8_t*>(&As[ar * BKp + ac])     = aS0;
        *reinterpret_cast<bhalf8_t*>(&As[ar * BKp + ac + 8]) = aS1;
        *reinterpret_cast<bhalf8_t*>(&Bs[ar * BKp + ac])     = bS0;
        *reinterpret_cast<bhalf8_t*>(&Bs[ar * BKp + ac + 8]) = bS1;
        __syncthreads();
        if (k0 + 32 < K) { ldgA(k0 + 32); ldgB(k0 + 32); }
        bhalf8_t af[4], bf[4];
#pragma unroll
        for (int i = 0; i < 4; ++i)
            af[i] = *reinterpret_cast<const bhalf8_t*>(&As[(wm + i * 16 + l16) * BKp + quad * 8]);
#pragma unroll
        for (int j = 0; j < 4; ++j)
            bf[j] = *reinterpret_cast<const bhalf8_t*>(&Bs[(wn + j * 16 + l16) * BKp + quad * 8]);
#pragma unroll
        for (int i = 0; i < 4; ++i)
#pragma unroll
            for (int j = 0; j < 4; ++j)
                acc[i][j] = __builtin_amdgcn_mfma_f32_16x16x32_bf16(af[i], bf[j], acc[i][j], 0, 0, 0);
        __syncthreads();
    }

    float* Cp = Cpart + (long)bz * M * N;
#pragma unroll
    for (int i = 0; i < 4; ++i)
#pragma unroll
        for (int j = 0; j < 4; ++j)
#pragma unroll
            for (int r = 0; r < 4; ++r) {
                int m = bm + wm + i * 16 + quad * 4 + r;
                int n = bn + wn + j * 16 + l16;
                Cp[(long)m * N + n] = acc[i][j][r];
            }
}

// ---------------- flash partial: one wave = (16 Q-rows, 128 keys, 1 head) --------
__global__ __launch_bounds__(64)
void flash_part_k(const unsigned short* __restrict__ qb3, const unsigned short* __restrict__ kb3,
                  const unsigned short* __restrict__ vtb, const unsigned short* __restrict__ bmap,
                  float* __restrict__ po, float* __restrict__ pm, float* __restrict__ pl)
{
    __shared__ unsigned short Ps[16 * 136];

    int tid = threadIdx.x;          // 0..63
    int qb = blockIdx.x;            // 64 Q-blocks of 16 rows
    int h  = blockIdx.y;            // 8 heads
    int z  = blockIdx.z;            // 8 key-slices of 128
    int bm = qb * 16;
    int k0 = z * 128;

    const unsigned short* Qh = qb3 + (long)h * 196608;
    const unsigned short* Kh = kb3 + (long)h * 196608;
    const unsigned short* Vh = vtb + (long)h * 65536;
    const unsigned short* Bm = bmap + (long)h * 1048576;

    int quad = tid >> 4, l16 = tid & 15;

    // Q fragments (rows bm..bm+15, K=192 3-split)
    bhalf8_t aq[6];
#pragma unroll
    for (int kq = 0; kq < 6; ++kq)
        aq[kq] = *reinterpret_cast<const bhalf8_t*>(
            &Qh[(long)(bm + l16) * 192 + kq * 32 + quad * 8]);

    // QK^T: scores 16x128, K fragments straight from global (L2-hot)
    f32x4_t sacc[8] = {};
#pragma unroll
    for (int kq = 0; kq < 6; ++kq) {
        bhalf8_t bk[8];
#pragma unroll
        for (int nb = 0; nb < 8; ++nb)
            bk[nb] = *reinterpret_cast<const bhalf8_t*>(
                &Kh[(long)(k0 + nb * 16 + l16) * 192 + kq * 32 + quad * 8]);
#pragma unroll
        for (int nb = 0; nb < 8; ++nb)
            sacc[nb] = __builtin_amdgcn_mfma_f32_16x16x32_bf16(aq[kq], bk[nb], sacc[nb], 0, 0, 0);
    }

    // scale + bias (from f16 map), row max over 128 cols
    float m_r[4] = {-3.0e38f, -3.0e38f, -3.0e38f, -3.0e38f};
#pragma unroll
    for (int nb = 0; nb < 8; ++nb)
#pragma unroll
        for (int r = 0; r < 4; ++r) {
            int gm = bm + quad * 4 + r;
            int gn = k0 + nb * 16 + l16;
            float bias = h2f(Bm[(long)gm * kS + gn]);
            float s = fmaf(sacc[nb][r], 0.125f, bias);
            sacc[nb][r] = s;
            m_r[r] = fmaxf(m_r[r], s);
        }
#pragma unroll
    for (int r = 0; r < 4; ++r) {
        float m_ = m_r[r];
#pragma unroll
        for (int off = 1; off < 16; off <<= 1) m_ = fmaxf(m_, __shfl_xor(m_, off, 64));
        m_r[r] = m_;
    }

    // P = exp(s-m) -> LDS (x2^14 f16), row sums
    float l_r[4];
#pragma unroll
    for (int r = 0; r < 4; ++r) {
        int row = quad * 4 + r;
        float mN = m_r[r];
        float s_ = 0.f;
#pragma unroll
        for (int nb = 0; nb < 8; ++nb) {
            float p = __expf(sacc[nb][r] - mN);
            Ps[row * 136 + nb * 16 + l16] = f2h(p * 16384.f);
            s_ += p;
        }
#pragma unroll
        for (int off = 1; off < 16; off <<= 1) s_ += __shfl_xor(s_, off, 64);
        l_r[r] = s_;
    }

    long sbase = (((long)z * 8 + h) * 64 + qb) * 16;   // per-z stride 8192
    if (l16 == 0) {
#pragma unroll
        for (int r = 0; r < 4; ++r) {
            pm[sbase + quad * 4 + r] = m_r[r];
            pl[sbase + quad * 4 + r] = l_r[r];
        }
    }
    __syncthreads();

    // PV: O(16x64) = P(16x128) @ V-slice, f16 MFMA, V from global
    f32x4_t oacc[4] = {};
#pragma unroll
    for (int kq2 = 0; kq2 < 4; ++kq2) {
        bhalf8_t ap = *reinterpret_cast<const bhalf8_t*>(&Ps[l16 * 136 + kq2 * 32 + quad * 8]);
#pragma unroll
        for (int j2 = 0; j2 < 4; ++j2) {
            bhalf8_t bv = *reinterpret_cast<const bhalf8_t*>(
                &Vh[(long)(j2 * 16 + l16) * 1024 + k0 + kq2 * 32 + quad * 8]);
            oacc[j2] = __builtin_amdgcn_mfma_f32_16x16x32_f16(
                __builtin_bit_cast(half8_t, ap), __builtin_bit_cast(half8_t, bv),
                oacc[j2], 0, 0, 0);
        }
    }

    float* pob = po + sbase * 64;
#pragma unroll
    for (int j2 = 0; j2 < 4; ++j2)
#pragma unroll
        for (int r = 0; r < 4; ++r)
            pob[(quad * 4 + r) * 64 + j2 * 16 + l16] = oacc[j2][r];
}

// ---------------- flash merge: combine 8 key-slice partials, write aob 3-split ---
__global__ __launch_bounds__(256)
void flash_merge_k(const float* __restrict__ po, const float* __restrict__ pm,
                   const float* __restrict__ pl, unsigned short* __restrict__ aob)
{
    int t = blockIdx.x * 256 + threadIdx.x;   // 65536 = 8h * 64qb * 16row * 8chunks
    int c8  = t & 7;
    int row = (t >> 3) & 15;
    int qb  = (t >> 7) & 63;
    int h   = t >> 13;
    long sidx = (((long)h * 64) + qb) * 16 + row;   // per-z stride 8192

    float m[8];
    float M = -3.0e38f;
#pragma unroll
    for (int z = 0; z < 8; ++z) { m[z] = pm[z * 8192 + sidx]; M = fmaxf(M, m[z]); }
    float w[8], lt = 0.f;
#pragma unroll
    for (int z = 0; z < 8; ++z) {
        w[z] = __expf(m[z] - M);
        lt = fmaf(pl[z * 8192 + sidx], w[z], lt);
    }
    float acc[8] = {};
#pragma unroll
    for (int z = 0; z < 8; ++z) {
        const float* p = po + (z * 8192 + sidx) * 64 + c8 * 8;
        float4 a = *reinterpret_cast<const float4*>(p);
        float4 b = *reinterpret_cast<const float4*>(p + 4);
        acc[0] = fmaf(a.x, w[z], acc[0]); acc[1] = fmaf(a.y, w[z], acc[1]);
        acc[2] = fmaf(a.z, w[z], acc[2]); acc[3] = fmaf(a.w, w[z], acc[3]);
        acc[4] = fmaf(b.x, w[z], acc[4]); acc[5] = fmaf(b.y, w[z], acc[5]);
        acc[6] = fmaf(b.z, w[z], acc[6]); acc[7] = fmaf(b.w, w[z], acc[7]);
    }
    float inv = 1.f / (16777216.f * lt);
    unsigned short hi[8], lo[8];
#pragma unroll
    for (int j = 0; j < 8; ++j) {
        float val = acc[j] * inv;
        hi[j] = f2bf(val);
        lo[j] = f2bf(val - bf2f(hi[j]));
    }
    long base = ((long)qb * 16 + row) * 1536 + h * 64 + c8 * 8;
    *reinterpret_cast<ushort4*>(&aob[base])        = make_ushort4(hi[0], hi[1], hi[2], hi[3]);
    *reinterpret_cast<ushort4*>(&aob[base + 4])    = make_ushort4(hi[4], hi[5], hi[6], hi[7]);
    *reinterpret_cast<ushort4*>(&aob[base + 512])  = make_ushort4(lo[0], lo[1], lo[2], lo[3]);
    *reinterpret_cast<ushort4*>(&aob[base + 516])  = make_ushort4(lo[4], lo[5], lo[6], lo[7]);
    *reinterpret_cast<ushort4*>(&aob[base + 1024]) = make_ushort4(hi[0], hi[1], hi[2], hi[3]);
    *reinterpret_cast<ushort4*>(&aob[base + 1028]) = make_ushort4(hi[4], hi[5], hi[6], hi[7]);
}

// ---------------- QKV split-K reduce: bias + direct 3-split to qb3/kb3, v f32 ----
__global__ __launch_bounds__(256)
void reduce_qkv_k(const float* __restrict__ part,
                  unsigned short* __restrict__ qb3, unsigned short* __restrict__ kb3,
                  float* __restrict__ v,
                  const float* __restrict__ qbias, const float* __restrict__ kbias,
                  const float* __restrict__ vbias)
{
    int z = blockIdx.y;
    const long MN = (long)kS * kD;
    long idx = ((long)blockIdx.x * 256 + threadIdx.x) * 4;
    const float* pz = part + (long)z * 4 * MN + idx;
    float4 s = *reinterpret_cast<const float4*>(pz);
#pragma unroll
    for (int t = 1; t < 4; ++t) {
        float4 vv = *reinterpret_cast<const float4*>(pz + (long)t * MN);
        s.x += vv.x; s.y += vv.y; s.z += vv.z; s.w += vv.w;
    }
    int m = (int)(idx >> 9), n = (int)(idx & 511);
    const float* bzp = (z == 1) ? kbias : (z == 2) ? vbias : qbias;
    s.x += bzp[n]; s.y += bzp[n + 1]; s.z += bzp[n + 2]; s.w += bzp[n + 3];
    if (z == 2) {
        *reinterpret_cast<float4*>(v + idx) = s;
        return;
    }
    float fv[4] = {s.x, s.y, s.z, s.w};
    unsigned short h[4], lo[4];
#pragma unroll
    for (int j = 0; j < 4; ++j) {
        h[j] = f2bf(fv[j]);
        lo[j] = f2bf(fv[j] - bf2f(h[j]));
    }
    int head = n >> 6, hc = n & 63;
    unsigned short* dst = ((z == 1) ? kb3 : qb3) + (long)head * 196608 + (long)m * 192 + hc;
    ushort4 hv = make_ushort4(h[0], h[1], h[2], h[3]);
    ushort4 lv = make_ushort4(lo[0], lo[1], lo[2], lo[3]);
    *reinterpret_cast<ushort4*>(dst) = hv;
    if (z == 0) {  // A-side [hi|lo|hi]
        *reinterpret_cast<ushort4*>(dst + 64)  = lv;
        *reinterpret_cast<ushort4*>(dst + 128) = hv;
    } else {       // B-side [hi|hi|lo]
        *reinterpret_cast<ushort4*>(dst + 64)  = hv;
        *reinterpret_cast<ushort4*>(dst + 128) = lv;
    }
}

// ---------------- generic split-K reduce -> f32 (+bias) ----------------
__global__ __launch_bounds__(256)
void reduce_k(const float* __restrict__ part, float* __restrict__ C,
              const float* __restrict__ bias, int N, int splitk)
{
    const long MN = (long)kS * N;
    long idx = ((long)blockIdx.x * 256 + threadIdx.x) * 4;
    const float* pz = part + idx;
    float4 s = *reinterpret_cast<const float4*>(pz);
    for (int t = 1; t < splitk; ++t) {
        float4 v = *reinterpret_cast<const float4*>(pz + (long)t * MN);
        s.x += v.x; s.y += v.y; s.z += v.z; s.w += v.w;
    }
    int n = (int)(idx % N);
    s.x += bias[n]; s.y += bias[n + 1]; s.z += bias[n + 2]; s.w += bias[n + 3];
    *reinterpret_cast<float4*>(C + idx) = s;
}

// ---------------- FFN1 reduce: bias + relu + direct 3-split to hb ----------------
__global__ __launch_bounds__(256)
void reduce3_k(const float* __restrict__ part, unsigned short* __restrict__ hb,
               const float* __restrict__ bias, int splitk)
{
    const long MN = (long)kS * kDFF;
    long idx = ((long)blockIdx.x * 256 + threadIdx.x) * 4;
    const float* pz = part + idx;
    float4 s = *reinterpret_cast<const float4*>(pz);
    for (int t = 1; t < splitk; ++t) {
        float4 v = *reinterpret_cast<const float4*>(pz + (long)t * MN);
        s.x += v.x; s.y += v.y; s.z += v.z; s.w += v.w;
    }
    int m = (int)(idx >> 11), n = (int)(idx & 2047);
    float fv[4] = {fmaxf(s.x + bias[n], 0.f), fmaxf(s.y + bias[n + 1], 0.f),
                   fmaxf(s.z + bias[n + 2], 0.f), fmaxf(s.w + bias[n + 3], 0.f)};
    unsigned short h[4], lo[4];
#pragma unroll
    for (int j = 0; j < 4; ++j) {
        h[j] = f2bf(fv[j]);
        lo[j] = f2bf(fv[j] - bf2f(h[j]));
    }
    unsigned short* dst = hb + (long)m * 6144 + n;
    ushort4 hv = make_ushort4(h[0], h[1], h[2], h[3]);
    *reinterpret_cast<ushort4*>(dst)        = hv;
    *reinterpret_cast<ushort4*>(dst + 2048) = make_ushort4(lo[0], lo[1], lo[2], lo[3]);
    *reinterpret_cast<ushort4*>(dst + 4096) = hv;
}

// ---------------- residual add + layernorm (in place on x, + 3-split xb) --------
__global__ __launch_bounds__(256)
void add_ln_k(float* __restrict__ x, const float* __restrict__ y,
              const float* __restrict__ g, const float* __restrict__ b,
              unsigned short* __restrict__ xb)
{
    __shared__ float sm[4];
    int row = blockIdx.x, t = threadIdx.x;
    float* xr = x + (long)row * kD;
    const float* yr = y + (long)row * kD;
    float s0 = xr[t] + yr[t];
    float s1 = xr[t + 256] + yr[t + 256];
    float sum = wave_sum(s0 + s1);
    if ((t & 63) == 0) sm[t >> 6] = sum;
    __syncthreads();
    sum = sm[0] + sm[1] + sm[2] + sm[3];
    float mu = sum * (1.f / kD);
    float d0 = s0 - mu, d1 = s1 - mu;
    __syncthreads();
    float vs = wave_sum(d0 * d0 + d1 * d1);
    if ((t & 63) == 0) sm[t >> 6] = vs;
    __syncthreads();
    vs = sm[0] + sm[1] + sm[2] + sm[3];
    float rs = rsqrtf(vs * (1.f / kD) + 1e-5f);
    float o0 = fmaf(d0 * rs, g[t], b[t]);
    float o1 = fmaf(d1 * rs, g[t + 256], b[t + 256]);
    xr[t]       = o0;
    xr[t + 256] = o1;
    unsigned short h0 = f2bf(o0), l0 = f2bf(o0 - bf2f(h0));
    unsigned short h1 = f2bf(o1), l1 = f2bf(o1 - bf2f(h1));
    unsigned short* xrow = xb + (long)row * 1536;
    xrow[t]            = h0;  xrow[t + 256]        = h1;
    xrow[t + 512]      = l0;  xrow[t + 768]        = l1;
    xrow[t + 1024]     = h0;  xrow[t + 1280]       = h1;
}

// ---------------- mean-pool partials ----------------
__global__ __launch_bounds__(256)
void pool_k(const float* __restrict__ x, float* __restrict__ partial)
{
    int col = blockIdx.x * 256 + threadIdx.x;
    int rb = blockIdx.y;
    float s = 0.f;
    for (int r = rb * 128; r < rb * 128 + 128; ++r) s += x[(long)r * kD + col];
    partial[rb * kD + col] = s;
}

// ---------------- classifier head ----------------
__global__ __launch_bounds__(256)
void head_k(const float* __restrict__ partial,
            const float* __restrict__ c1w, const float* __restrict__ c1b,
            const float* __restrict__ c2w, const float* __restrict__ c2b,
            float* __restrict__ out)
{
    __shared__ float pooled[kD];
    __shared__ float h1[256];
    int t = threadIdx.x;
    for (int d = t; d < kD; d += 256) {
        float s = 0.f;
        for (int r = 0; r < 8; ++r) s += partial[r * kD + d];
        pooled[d] = s * (1.0f / kS);
    }
    __syncthreads();
    float acc = c1b[t];
    for (int f = 0; f < kD; ++f) acc = fmaf(pooled[f], c1w[f * 256 + t], acc);
    h1[t] = fmaxf(acc, 0.f);
    __syncthreads();
    if (t < 10) {
        float o = c2b[t];
        for (int f = 0; f < 256; ++f) o = fmaf(h1[f], c2w[f * 10 + t], o);
        out[t] = o;
    }
}

// ---------------- launch ----------------
extern "C" void kernel_launch(void* const* d_in, const int* in_sizes, int n_in,
                              void* d_out, int out_size, void* d_ws, size_t ws_size,
                              hipStream_t stream)
{
    (void)in_sizes; (void)n_in; (void)out_size; (void)ws_size;
    const float* features = (const float*)d_in[0];
    const float* positions= (const float*)d_in[1];
    const float* fb       = (const float*)d_in[2];
    const float* in_w     = (const float*)d_in[3];
    const float* in_b     = (const float*)d_in[4];
    const float* qw  = (const float*)d_in[5];
    const float* qb  = (const float*)d_in[6];
    const float* kw  = (const float*)d_in[7];
    const float* kb  = (const float*)d_in[8];
    const float* vw  = (const float*)d_in[9];
    const float* vb  = (const float*)d_in[10];
    const float* ow  = (const float*)d_in[11];
    const float* ob  = (const float*)d_in[12];
    const float* db1w= (const float*)d_in[13];
    const float* db1b= (const float*)d_in[14];
    const float* db2w= (const float*)d_in[15];
    const float* db2b= (const float*)d_in[16];
    const float* n1g = (const float*)d_in[17];
    const float* n1b = (const float*)d_in[18];
    const float* n2g = (const float*)d_in[19];
    const float* n2b = (const float*)d_in[20];
    const float* f1w = (const float*)d_in[21];
    const float* f1b = (const float*)d_in[22];
    const float* f2w = (const float*)d_in[23];
    const float* f2b = (const float*)d_in[24];
    const float* c1w = (const float*)d_in[25];
    const float* c1b = (const float*)d_in[26];
    const float* c2w = (const float*)d_in[27];
    const float* c2b = (const float*)d_in[28];

    float* ws = (float*)d_ws;
    const long SD = (long)kS * kD;            // 524288
    float* x      = ws;
    float* v      = ws + 1 * SD;
    float* y      = ws + 2 * SD;
    float* dist   = ws + 3 * SD;              // 2*SD
    float* part   = ws + 5 * SD;              // 12*SD scratch (QKV partials / flash partials)
    float* bpw    = ws + 17 * SD;
    float* Atab   = bpw + 256;
    float* Btab   = Atab + 2080;
    float* partial= Btab + 2080;

    // flash partial overlays inside `part` (dead between QKV-reduce and O-proj)
    float* po = part;                          // 8*8*64*16*64 = 4,194,304 floats
    float* pmv = part + 4194304;               // 65536
    float* plv = pmv + 65536;                  // 65536

    unsigned short* ub = (unsigned short*)(ws + 17 * SD + 8512);
    unsigned short* xb   = ub;                       // 1024*1536
    unsigned short* aob  = xb   + 1572864;           // 1024*1536
    unsigned short* qb3  = aob  + 1572864;           // 8*1024*192
    unsigned short* kb3  = qb3  + 1572864;
    unsigned short* vtb  = kb3  + 1572864;           // 512*1024 (f16)
    unsigned short* hb   = vtb  + 524288;            // 1024*6144
    unsigned short* qwb  = hb   + 6291456;           // 2 x 512*1536
    unsigned short* kwb  = qwb  + 1572864;
    unsigned short* vwb  = kwb  + 1572864;
    unsigned short* owb  = vwb  + 1572864;
    unsigned short* f1wb = owb  + 1572864;           // 2 x 2048*1536
    unsigned short* f2wb = f1wb + 6291456;           // 2 x 512*6144
    unsigned short* bmap = f2wb + 6291456;           // 8*1024*1024 f16 bias map

    input_pe_k<<<kS, 256, 0, stream>>>(features, positions, fb, in_w, in_b, x);
    dist_k<<<kS, 256, 0, stream>>>(positions, dist);
    pwl_sort_k<<<2, 128, 0, stream>>>(db1w, db1b, bpw);
    pwl_tab_k<<<dim3(129, 2), 256, 0, stream>>>(db1w, db1b, db2w, db2b, bpw, Atab, Btab);
    split3_rm_k<<<512, 256, 0, stream>>>(x, xb, 524288, 9, 512);

    split3_tr_k<<<dim3(16, 16, 2), 256, 0, stream>>>(qw, qwb, 512, 512, 262144, 786432);
    split3_tr_k<<<dim3(16, 16, 2), 256, 0, stream>>>(kw, kwb, 512, 512, 262144, 786432);
    split3_tr_k<<<dim3(16, 16, 2), 256, 0, stream>>>(vw, vwb, 512, 512, 262144, 786432);
    split3_tr_k<<<dim3(16, 16, 2), 256, 0, stream>>>(ow, owb, 512, 512, 262144, 786432);
    split3_tr_k<<<dim3(16, 64, 2), 256, 0, stream>>>(f1w, f1wb, 512, 2048, 1048576, 3145728);
    split3_tr_k<<<dim3(64, 16, 2), 256, 0, stream>>>(f2w, f2wb, 2048, 512, 1048576, 3145728);

    for (int l = 0; l < 2; ++l) {
        // per-layer bias map (f16, all heads per thread)
        biasmap_k<<<1024, 256, 0, stream>>>(
            dist, bpw + l * 128, Atab + l * 1040, Btab + l * 1040, bmap);

        // QKV: A=xb (1024x1536), split-K x4 -> partials; reduce fuses bias + q/k 3-split
        bgemm_k<<<dim3(8, 4, 12), 256, 0, stream>>>(
            xb, qwb + l * 786432, kwb + l * 786432, vwb + l * 786432,
            1024, 512, 384, 1536, 1536, 0, 4, part);
        reduce_qkv_k<<<dim3(512, 3), 256, 0, stream>>>(
            part, qb3, kb3, v, qb + l * kD, kb + l * kD, vb + l * kD);
        tr_f16_k<<<dim3(32, 16), 256, 0, stream>>>(v, vtb, 1024, 512, 1024.f);

        // fused attention: K-split partials + merge -> aob (3-split)
        flash_part_k<<<dim3(64, 8, 8), 64, 0, stream>>>(
            qb3, kb3, vtb, bmap, po, pmv, plv);
        flash_merge_k<<<256, 256, 0, stream>>>(po, pmv, plv, aob);

        // O-proj: split-K x8
        bgemm_k<<<dim3(8, 4, 8), 256, 0, stream>>>(
            aob, owb + l * 786432, owb + l * 786432, owb + l * 786432,
            1024, 512, 192, 1536, 1536, 0, 8, part);
        reduce_k<<<512, 256, 0, stream>>>(part, y, ob + l * kD, 512, 8);
        add_ln_k<<<kS, 256, 0, stream>>>(x, y, n1g + l * kD, n1b + l * kD, xb);

        // FFN1: split-K x2, reduce fuses bias+relu+3-split -> hb
        bgemm_k<<<dim3(8, 16, 2), 256, 0, stream>>>(
            xb, f1wb + l * 3145728, f1wb + l * 3145728, f1wb + l * 3145728,
            1024, 2048, 768, 1536, 1536, 0, 2, part);
        reduce3_k<<<2048, 256, 0, stream>>>(part, hb, f1b + l * kDFF, 2);

        // FFN2: split-K x8
        bgemm_k<<<dim3(8, 4, 8), 256, 0, stream>>>(
            hb, f2wb + l * 3145728, f2wb + l * 3145728, f2wb + l * 3145728,
            1024, 512, 768, 6144, 6144, 0, 8, part);
        reduce_k<<<512, 256, 0, stream>>>(part, y, f2b + l * kD, 512, 8);
        add_ln_k<<<kS, 256, 0, stream>>>(x, y, n2g + l * kD, n2b + l * kD, xb);
    }

    pool_k<<<dim3(2, 8), 256, 0, stream>>>(x, partial);
    head_k<<<1, 256, 0, stream>>>(partial, c1w, c1b, c2w, c2b, (float*)d_out);
}

// Round 11
// 476.874 us; speedup vs baseline: 1.3069x; 1.0326x over previous
//
#include <hip/hip_runtime.h>

namespace {
constexpr int kS   = 1024;
constexpr int kD   = 512;
constexpr int kH   = 8;
constexpr int kDFF = 2048;
constexpr int kNF  = 85;   // D//6
}

typedef __attribute__((ext_vector_type(8))) short bhalf8_t;    // 8x16-bit in 4 VGPRs
typedef _Float16 half8_t __attribute__((ext_vector_type(8)));
typedef __attribute__((ext_vector_type(4))) float f32x4_t;

// ---------------- helpers ----------------
__device__ __forceinline__ float wave_sum(float v) {
#pragma unroll
    for (int o = 1; o < 64; o <<= 1) v += __shfl_xor(v, o, 64);
    return v;
}
__device__ __forceinline__ unsigned short f2bf(float f) {   // RNE fp32->bf16
    unsigned u = __float_as_uint(f);
    u = (u + 0x7FFF + ((u >> 16) & 1)) >> 16;
    return (unsigned short)u;
}
__device__ __forceinline__ float bf2f(unsigned short h) {
    return __uint_as_float(((unsigned)h) << 16);
}
__device__ __forceinline__ unsigned short f2h(float f) {    // RNE fp32->fp16
    _Float16 h = (_Float16)f;
    return __builtin_bit_cast(unsigned short, h);
}
__device__ __forceinline__ float h2f(unsigned short u) {
    return (float)__builtin_bit_cast(_Float16, u);
}

// ---------------- input projection + positional encoding ----------------
__global__ __launch_bounds__(256)
void input_pe_k(const float* __restrict__ feat, const float* __restrict__ pos,
                const float* __restrict__ fb, const float* __restrict__ in_w,
                const float* __restrict__ in_b, float* __restrict__ x)
{
    int s = blockIdx.x;
    int t = threadIdx.x;
    __shared__ float f[64];
    if (t < 64) f[t] = feat[s * 64 + t];
    __syncthreads();
    float acc0 = in_b[t], acc1 = in_b[t + 256];
#pragma unroll 8
    for (int c = 0; c < 64; ++c) {
        float fv = f[c];
        acc0 = fmaf(fv, in_w[c * kD + t], acc0);
        acc1 = fmaf(fv, in_w[c * kD + 256 + t], acc1);
    }
    float pe0 = 0.f, pe1 = 0.f;
    {
        int d = t;
        if (d < 6 * kNF) {
            int seg = d / kNF, idx = d - seg * kNF;
            float cs = pos[s * 3 + (seg >> 1)] * fb[idx];
            pe0 = (seg & 1) ? cosf(cs) : sinf(cs);
        }
        d = t + 256;
        if (d < 6 * kNF) {
            int seg = d / kNF, idx = d - seg * kNF;
            float cs = pos[s * 3 + (seg >> 1)] * fb[idx];
            pe1 = (seg & 1) ? cosf(cs) : sinf(cs);
        }
    }
    x[s * kD + t]       = acc0 + pe0;
    x[s * kD + 256 + t] = acc1 + pe1;
}

// ---------------- pairwise distance matrix ----------------
__global__ __launch_bounds__(256)
void dist_k(const float* __restrict__ pos, float* __restrict__ dist)
{
    int i = blockIdx.x;
    float px = pos[i * 3], py = pos[i * 3 + 1], pz = pos[i * 3 + 2];
    for (int j = threadIdx.x; j < kS; j += 256) {
        float dx = px - pos[j * 3], dy = py - pos[j * 3 + 1], dz = pz - pos[j * 3 + 2];
        float sq = dx * dx + dy * dy + dz * dz;
        dist[(long)i * kS + j] = sq > 0.f ? sqrtf(sq) : 0.f;
    }
}

// ---------------- PWL: sort breakpoints only (tiny) ----------------
__global__ __launch_bounds__(128)
void pwl_sort_k(const float* __restrict__ a_, const float* __restrict__ b_,
                float* __restrict__ bp_out)
{
    int l = blockIdx.x;
    a_ += l * 128; b_ += l * 128; bp_out += l * 128;
    __shared__ float key[128];
    int t = threadIdx.x;
    float a = a_[t], b = b_[t];
    key[t] = (a != 0.f) ? (-b / a) : 3.0e38f;
    __syncthreads();
    for (int ksz = 2; ksz <= 128; ksz <<= 1) {
        for (int j = ksz >> 1; j > 0; j >>= 1) {
            int ixj = t ^ j;
            if (ixj > t) {
                bool up = ((t & ksz) == 0);
                float x0 = key[t], x1 = key[ixj];
                if ((x0 > x1) == up) { key[t] = x1; key[ixj] = x0; }
            }
            __syncthreads();
        }
    }
    bp_out[t] = key[t];
}

// ---------------- PWL: per-segment table build ----------------
__global__ __launch_bounds__(256)
void pwl_tab_k(const float* __restrict__ a_, const float* __restrict__ b_,
               const float* __restrict__ w2, const float* __restrict__ b2,
               const float* __restrict__ bp, float* __restrict__ Atab,
               float* __restrict__ Btab)
{
    int l = blockIdx.y;
    int seg = blockIdx.x;   // 0..128
    a_ += l * 128; b_ += l * 128; w2 += l * 1024; b2 += l * 8;
    bp += l * 128; Atab += l * 1040; Btab += l * 1040;

    float m;
    if (seg == 0)        m = bp[0] - 1.0f;
    else if (seg == 128) m = bp[127] + 1.0f;
    else                 m = 0.5f * (bp[seg - 1] + bp[seg]);

    int t = threadIdx.x;
    int h = t & 7, cg = t >> 3;   // cg 0..31
    float A = 0.f, B = 0.f;
#pragma unroll
    for (int j = 0; j < 4; ++j) {
        int c = cg * 4 + j;
        float a = a_[c], b = b_[c];
        if (fmaf(a, m, b) > 0.f) {
            float w = w2[c * 8 + h];
            A = fmaf(a, w, A);
            B = fmaf(b, w, B);
        }
    }
#pragma unroll
    for (int off = 8; off < 64; off <<= 1) {
        A += __shfl_xor(A, off, 64);
        B += __shfl_xor(B, off, 64);
    }
    __shared__ float sA[4][8], sB[4][8];
    int w = t >> 6, lane = t & 63;
    if (lane < 8) { sA[w][lane] = A; sB[w][lane] = B; }
    __syncthreads();
    if (t < 8) {
        float At = sA[0][t] + sA[1][t] + sA[2][t] + sA[3][t];
        float Bt = sB[0][t] + sB[1][t] + sB[2][t] + sB[3][t];
        Atab[seg * 8 + t] = At;
        Btab[seg * 8 + t] = Bt + b2[t];
    }
}

// ---------------- per-layer bias map: one search -> all 8 heads ----------------
__global__ __launch_bounds__(256)
void biasmap_k(const float* __restrict__ dist, const float* __restrict__ bp,
               const float* __restrict__ Atab, const float* __restrict__ Btab,
               unsigned short* __restrict__ bmap)
{
    __shared__ float bps[128], Ah[1032], Bh[1032];
    int t = threadIdx.x;
    if (t < 128) bps[t] = bp[t];
    for (int i = t; i < 1032; i += 256) { Ah[i] = Atab[i]; Bh[i] = Btab[i]; }
    __syncthreads();
    long i = ((long)blockIdx.x * 256 + t) * 4;
    float4 d4 = *reinterpret_cast<const float4*>(dist + i);
    float dv[4] = {d4.x, d4.y, d4.z, d4.w};
    int seg[4];
#pragma unroll
    for (int j = 0; j < 4; ++j) {
        float tv = dv[j];
        int lo = 0, hi = 128;
        while (lo < hi) { int mid = (lo + hi) >> 1; if (bps[mid] < tv) lo = mid + 1; else hi = mid; }
        seg[j] = lo;
    }
#pragma unroll
    for (int h = 0; h < 8; ++h) {
        unsigned short o[4];
#pragma unroll
        for (int j = 0; j < 4; ++j)
            o[j] = f2h(fmaf(Ah[seg[j] * 8 + h], dv[j], Bh[seg[j] * 8 + h]));
        *reinterpret_cast<ushort4*>(bmap + (long)h * 1048576 + i) =
            make_ushort4(o[0], o[1], o[2], o[3]);
    }
}

// ---------------- fp32 -> bf16 3-term split, row-major (order0 [hi|lo|hi]) ------
__global__ __launch_bounds__(256)
void split3_rm_k(const float* __restrict__ in, unsigned short* __restrict__ out,
                 int total, int kshift, int ldin)
{
    long i = ((long)blockIdx.x * 256 + threadIdx.x) * 4;
    if (i >= total) return;
    int K = 1 << kshift;
    int m = (int)(i >> kshift), k = (int)(i & (K - 1));
    float4 v = *reinterpret_cast<const float4*>(in + (long)m * ldin + k);
    unsigned short h[4], lo[4];
    float fv[4] = {v.x, v.y, v.z, v.w};
#pragma unroll
    for (int j = 0; j < 4; ++j) {
        h[j] = f2bf(fv[j]);
        lo[j] = f2bf(fv[j] - bf2f(h[j]));
    }
    unsigned short* op = out + (long)m * (3 * K) + k;
    ushort4 hv = make_ushort4(h[0], h[1], h[2], h[3]);
    *reinterpret_cast<ushort4*>(op)         = hv;
    *reinterpret_cast<ushort4*>(op + K)     = make_ushort4(lo[0], lo[1], lo[2], lo[3]);
    *reinterpret_cast<ushort4*>(op + 2 * K) = hv;
}

// ---------------- fp32 K x N -> bf16 N x 3K transpose-split (weights, [hi|hi|lo]) --
__global__ __launch_bounds__(256)
void split3_tr_k(const float* __restrict__ in, unsigned short* __restrict__ out,
                 int K, int N, long szIn, long szOut)
{
    __shared__ float tile[32][33];
    int z = blockIdx.z;
    in  += (long)z * szIn;
    out += (long)z * szOut;
    int k0 = blockIdx.x * 32, n0 = blockIdx.y * 32;
    int t = threadIdx.x;
    int r = t >> 3, c4 = (t & 7) * 4;
    float4 v = *reinterpret_cast<const float4*>(&in[(long)(k0 + r) * N + n0 + c4]);
    tile[r][c4] = v.x; tile[r][c4 + 1] = v.y; tile[r][c4 + 2] = v.z; tile[r][c4 + 3] = v.w;
    __syncthreads();
    int nr = t >> 3, kq = (t & 7) * 4;
    unsigned short h[4], lo[4];
#pragma unroll
    for (int j = 0; j < 4; ++j) {
        float f = tile[kq + j][nr];
        h[j] = f2bf(f);
        lo[j] = f2bf(f - bf2f(h[j]));
    }
    unsigned short* op = out + (long)(n0 + nr) * (3 * K) + k0 + kq;
    ushort4 hv = make_ushort4(h[0], h[1], h[2], h[3]);
    *reinterpret_cast<ushort4*>(op)         = hv;
    *reinterpret_cast<ushort4*>(op + K)     = hv;
    *reinterpret_cast<ushort4*>(op + 2 * K) = make_ushort4(lo[0], lo[1], lo[2], lo[3]);
}

// ---------------- fp32 K x N -> f16 N x K transpose with scale (V matrix) -------
__global__ __launch_bounds__(256)
void tr_f16_k(const float* __restrict__ in, unsigned short* __restrict__ out,
              int K, int N, float scl)
{
    __shared__ float tile[32][33];
    int k0 = blockIdx.x * 32, n0 = blockIdx.y * 32;
    int t = threadIdx.x;
    int r = t >> 3, c4 = (t & 7) * 4;
    float4 v = *reinterpret_cast<const float4*>(&in[(long)(k0 + r) * N + n0 + c4]);
    tile[r][c4] = v.x; tile[r][c4 + 1] = v.y; tile[r][c4 + 2] = v.z; tile[r][c4 + 3] = v.w;
    __syncthreads();
    int nr = t >> 3, kq = (t & 7) * 4;
    unsigned short h[4];
#pragma unroll
    for (int j = 0; j < 4; ++j) h[j] = f2h(tile[kq + j][nr] * scl);
    *reinterpret_cast<ushort4*>(&out[(long)(n0 + nr) * K + k0 + kq]) =
        make_ushort4(h[0], h[1], h[2], h[3]);
}

// ---------------- 16-bit MFMA GEMM (bf16), split-K partial writer ----------------
// 64x128 tile, 4 waves of 32x64 each -> 2x the blocks of the old 128x128 version
// (grids were 1-1.5 blocks/CU = the round-5 occupancy ceiling).
__global__ __launch_bounds__(256, 4)
void bgemm_k(const unsigned short* __restrict__ A,
             const unsigned short* __restrict__ B0, const unsigned short* __restrict__ B1,
             const unsigned short* __restrict__ B2,
             int M, int N, int K, int lda, int ldb,
             long sA, int splitk,
             float* __restrict__ Cpart)
{
    constexpr int BKp = 40;
    int tid = threadIdx.x;
    int bz = blockIdx.z;
    int z  = bz / splitk;
    int ks = bz - z * splitk;

    const unsigned short* Ap = A + (long)z * sA + (long)ks * K;
    const unsigned short* Bp = ((z == 1) ? B1 : (z == 2) ? B2 : B0) + (long)ks * K;

    __shared__ unsigned short As[64 * BKp];
    __shared__ unsigned short Bs[128 * BKp];

    int bm = blockIdx.x * 64;
    int bn = blockIdx.y * 128;
    int w = tid >> 6, lane = tid & 63, quad = lane >> 4, l16 = lane & 15;
    int wm = (w >> 1) * 32;
    int wn = (w & 1) * 64;

    int ar = tid >> 2, ac = (tid & 3) * 8;      // A: 64 rows, 4 thr/row, 1 bhalf8 each
    int br = tid >> 1, bc = (tid & 1) * 16;     // B: 128 rows, 2 thr/row, 2 bhalf8 each

    f32x4_t acc[2][4] = {};
    bhalf8_t aS0, bS0, bS1;

    auto ldgA = [&](int k0) {
        aS0 = *reinterpret_cast<const bhalf8_t*>(Ap + (long)(bm + ar) * lda + k0 + ac);
    };
    auto ldgB = [&](int k0) {
        const unsigned short* p = Bp + (long)(bn + br) * ldb + k0 + bc;
        bS0 = *reinterpret_cast<const bhalf8_t*>(p);
        bS1 = *reinterpret_cast<const bhalf8_t*>(p + 8);
    };

    ldgA(0); ldgB(0);

    for (int k0 = 0; k0 < K; k0 += 32) {
        *reinterpret_cast<bhalf8_t*>(&As[ar * BKp + ac])     = aS0;
        *reinterpret_cast<bhalf8_t*>(&Bs[br * BKp + bc])     = bS0;
        *reinterpret_cast<bhalf8_t*>(&Bs[br * BKp + bc + 8]) = bS1;
        __syncthreads();
        if (k0 + 32 < K) { ldgA(k0 + 32); ldgB(k0 + 32); }
        bhalf8_t af[2], bf[4];
#pragma unroll
        for (int i = 0; i < 2; ++i)
            af[i] = *reinterpret_cast<const bhalf8_t*>(&As[(wm + i * 16 + l16) * BKp + quad * 8]);
#pragma unroll
        for (int j = 0; j < 4; ++j)
            bf[j] = *reinterpret_cast<const bhalf8_t*>(&Bs[(wn + j * 16 + l16) * BKp + quad * 8]);
#pragma unroll
        for (int i = 0; i < 2; ++i)
#pragma unroll
            for (int j = 0; j < 4; ++j)
                acc[i][j] = __builtin_amdgcn_mfma_f32_16x16x32_bf16(af[i], bf[j], acc[i][j], 0, 0, 0);
        __syncthreads();
    }

    float* Cp = Cpart + (long)bz * M * N;
#pragma unroll
    for (int i = 0; i < 2; ++i)
#pragma unroll
        for (int j = 0; j < 4; ++j)
#pragma unroll
            for (int r = 0; r < 4; ++r) {
                int m = bm + wm + i * 16 + quad * 4 + r;
                int n = bn + wn + j * 16 + l16;
                Cp[(long)m * N + n] = acc[i][j][r];
            }
}

// ---------------- flash partial: one wave = (16 Q-rows, 128 keys, 1 head) --------
__global__ __launch_bounds__(64)
void flash_part_k(const unsigned short* __restrict__ qb3, const unsigned short* __restrict__ kb3,
                  const unsigned short* __restrict__ vtb, const unsigned short* __restrict__ bmap,
                  float* __restrict__ po, float* __restrict__ pm, float* __restrict__ pl)
{
    __shared__ unsigned short Ps[16 * 136];

    int tid = threadIdx.x;          // 0..63
    int qb = blockIdx.x;            // 64 Q-blocks of 16 rows
    int h  = blockIdx.y;            // 8 heads
    int z  = blockIdx.z;            // 8 key-slices of 128
    int bm = qb * 16;
    int k0 = z * 128;

    const unsigned short* Qh = qb3 + (long)h * 196608;
    const unsigned short* Kh = kb3 + (long)h * 196608;
    const unsigned short* Vh = vtb + (long)h * 65536;
    const unsigned short* Bm = bmap + (long)h * 1048576;

    int quad = tid >> 4, l16 = tid & 15;

    // Q fragments (rows bm..bm+15, K=192 3-split)
    bhalf8_t aq[6];
#pragma unroll
    for (int kq = 0; kq < 6; ++kq)
        aq[kq] = *reinterpret_cast<const bhalf8_t*>(
            &Qh[(long)(bm + l16) * 192 + kq * 32 + quad * 8]);

    // QK^T: scores 16x128, K fragments straight from global (L2-hot)
    f32x4_t sacc[8] = {};
#pragma unroll
    for (int kq = 0; kq < 6; ++kq) {
        bhalf8_t bk[8];
#pragma unroll
        for (int nb = 0; nb < 8; ++nb)
            bk[nb] = *reinterpret_cast<const bhalf8_t*>(
                &Kh[(long)(k0 + nb * 16 + l16) * 192 + kq * 32 + quad * 8]);
#pragma unroll
        for (int nb = 0; nb < 8; ++nb)
            sacc[nb] = __builtin_amdgcn_mfma_f32_16x16x32_bf16(aq[kq], bk[nb], sacc[nb], 0, 0, 0);
    }

    // scale + bias (from f16 map), row max over 128 cols
    float m_r[4] = {-3.0e38f, -3.0e38f, -3.0e38f, -3.0e38f};
#pragma unroll
    for (int nb = 0; nb < 8; ++nb)
#pragma unroll
        for (int r = 0; r < 4; ++r) {
            int gm = bm + quad * 4 + r;
            int gn = k0 + nb * 16 + l16;
            float bias = h2f(Bm[(long)gm * kS + gn]);
            float s = fmaf(sacc[nb][r], 0.125f, bias);
            sacc[nb][r] = s;
            m_r[r] = fmaxf(m_r[r], s);
        }
#pragma unroll
    for (int r = 0; r < 4; ++r) {
        float m_ = m_r[r];
#pragma unroll
        for (int off = 1; off < 16; off <<= 1) m_ = fmaxf(m_, __shfl_xor(m_, off, 64));
        m_r[r] = m_;
    }

    // P = exp(s-m) -> LDS (x2^14 f16), row sums
    float l_r[4];
#pragma unroll
    for (int r = 0; r < 4; ++r) {
        int row = quad * 4 + r;
        float mN = m_r[r];
        float s_ = 0.f;
#pragma unroll
        for (int nb = 0; nb < 8; ++nb) {
            float p = __expf(sacc[nb][r] - mN);
            Ps[row * 136 + nb * 16 + l16] = f2h(p * 16384.f);
            s_ += p;
        }
#pragma unroll
        for (int off = 1; off < 16; off <<= 1) s_ += __shfl_xor(s_, off, 64);
        l_r[r] = s_;
    }

    long sbase = (((long)z * 8 + h) * 64 + qb) * 16;   // per-z stride 8192
    if (l16 == 0) {
#pragma unroll
        for (int r = 0; r < 4; ++r) {
            pm[sbase + quad * 4 + r] = m_r[r];
            pl[sbase + quad * 4 + r] = l_r[r];
        }
    }
    __syncthreads();

    // PV: O(16x64) = P(16x128) @ V-slice, f16 MFMA, V from global
    f32x4_t oacc[4] = {};
#pragma unroll
    for (int kq2 = 0; kq2 < 4; ++kq2) {
        bhalf8_t ap = *reinterpret_cast<const bhalf8_t*>(&Ps[l16 * 136 + kq2 * 32 + quad * 8]);
#pragma unroll
        for (int j2 = 0; j2 < 4; ++j2) {
            bhalf8_t bv = *reinterpret_cast<const bhalf8_t*>(
                &Vh[(long)(j2 * 16 + l16) * 1024 + k0 + kq2 * 32 + quad * 8]);
            oacc[j2] = __builtin_amdgcn_mfma_f32_16x16x32_f16(
                __builtin_bit_cast(half8_t, ap), __builtin_bit_cast(half8_t, bv),
                oacc[j2], 0, 0, 0);
        }
    }

    float* pob = po + sbase * 64;
#pragma unroll
    for (int j2 = 0; j2 < 4; ++j2)
#pragma unroll
        for (int r = 0; r < 4; ++r)
            pob[(quad * 4 + r) * 64 + j2 * 16 + l16] = oacc[j2][r];
}

// ---------------- flash merge: combine 8 key-slice partials, write aob 3-split ---
__global__ __launch_bounds__(256)
void flash_merge_k(const float* __restrict__ po, const float* __restrict__ pm,
                   const float* __restrict__ pl, unsigned short* __restrict__ aob)
{
    int t = blockIdx.x * 256 + threadIdx.x;   // 65536 = 8h * 64qb * 16row * 8chunks
    int c8  = t & 7;
    int row = (t >> 3) & 15;
    int qb  = (t >> 7) & 63;
    int h   = t >> 13;
    long sidx = (((long)h * 64) + qb) * 16 + row;   // per-z stride 8192

    float m[8];
    float M = -3.0e38f;
#pragma unroll
    for (int z = 0; z < 8; ++z) { m[z] = pm[z * 8192 + sidx]; M = fmaxf(M, m[z]); }
    float w[8], lt = 0.f;
#pragma unroll
    for (int z = 0; z < 8; ++z) {
        w[z] = __expf(m[z] - M);
        lt = fmaf(pl[z * 8192 + sidx], w[z], lt);
    }
    float acc[8] = {};
#pragma unroll
    for (int z = 0; z < 8; ++z) {
        const float* p = po + (z * 8192 + sidx) * 64 + c8 * 8;
        float4 a = *reinterpret_cast<const float4*>(p);
        float4 b = *reinterpret_cast<const float4*>(p + 4);
        acc[0] = fmaf(a.x, w[z], acc[0]); acc[1] = fmaf(a.y, w[z], acc[1]);
        acc[2] = fmaf(a.z, w[z], acc[2]); acc[3] = fmaf(a.w, w[z], acc[3]);
        acc[4] = fmaf(b.x, w[z], acc[4]); acc[5] = fmaf(b.y, w[z], acc[5]);
        acc[6] = fmaf(b.z, w[z], acc[6]); acc[7] = fmaf(b.w, w[z], acc[7]);
    }
    float inv = 1.f / (16777216.f * lt);
    unsigned short hi[8], lo[8];
#pragma unroll
    for (int j = 0; j < 8; ++j) {
        float val = acc[j] * inv;
        hi[j] = f2bf(val);
        lo[j] = f2bf(val - bf2f(hi[j]));
    }
    long base = ((long)qb * 16 + row) * 1536 + h * 64 + c8 * 8;
    *reinterpret_cast<ushort4*>(&aob[base])        = make_ushort4(hi[0], hi[1], hi[2], hi[3]);
    *reinterpret_cast<ushort4*>(&aob[base + 4])    = make_ushort4(hi[4], hi[5], hi[6], hi[7]);
    *reinterpret_cast<ushort4*>(&aob[base + 512])  = make_ushort4(lo[0], lo[1], lo[2], lo[3]);
    *reinterpret_cast<ushort4*>(&aob[base + 516])  = make_ushort4(lo[4], lo[5], lo[6], lo[7]);
    *reinterpret_cast<ushort4*>(&aob[base + 1024]) = make_ushort4(hi[0], hi[1], hi[2], hi[3]);
    *reinterpret_cast<ushort4*>(&aob[base + 1028]) = make_ushort4(hi[4], hi[5], hi[6], hi[7]);
}

// ---------------- QKV split-K reduce: bias + direct 3-split to qb3/kb3, v f32 ----
__global__ __launch_bounds__(256)
void reduce_qkv_k(const float* __restrict__ part,
                  unsigned short* __restrict__ qb3, unsigned short* __restrict__ kb3,
                  float* __restrict__ v,
                  const float* __restrict__ qbias, const float* __restrict__ kbias,
                  const float* __restrict__ vbias)
{
    int z = blockIdx.y;
    const long MN = (long)kS * kD;
    long idx = ((long)blockIdx.x * 256 + threadIdx.x) * 4;
    const float* pz = part + (long)z * 4 * MN + idx;
    float4 s = *reinterpret_cast<const float4*>(pz);
#pragma unroll
    for (int t = 1; t < 4; ++t) {
        float4 vv = *reinterpret_cast<const float4*>(pz + (long)t * MN);
        s.x += vv.x; s.y += vv.y; s.z += vv.z; s.w += vv.w;
    }
    int m = (int)(idx >> 9), n = (int)(idx & 511);
    const float* bzp = (z == 1) ? kbias : (z == 2) ? vbias : qbias;
    s.x += bzp[n]; s.y += bzp[n + 1]; s.z += bzp[n + 2]; s.w += bzp[n + 3];
    if (z == 2) {
        *reinterpret_cast<float4*>(v + idx) = s;
        return;
    }
    float fv[4] = {s.x, s.y, s.z, s.w};
    unsigned short h[4], lo[4];
#pragma unroll
    for (int j = 0; j < 4; ++j) {
        h[j] = f2bf(fv[j]);
        lo[j] = f2bf(fv[j] - bf2f(h[j]));
    }
    int head = n >> 6, hc = n & 63;
    unsigned short* dst = ((z == 1) ? kb3 : qb3) + (long)head * 196608 + (long)m * 192 + hc;
    ushort4 hv = make_ushort4(h[0], h[1], h[2], h[3]);
    ushort4 lv = make_ushort4(lo[0], lo[1], lo[2], lo[3]);
    *reinterpret_cast<ushort4*>(dst) = hv;
    if (z == 0) {  // A-side [hi|lo|hi]
        *reinterpret_cast<ushort4*>(dst + 64)  = lv;
        *reinterpret_cast<ushort4*>(dst + 128) = hv;
    } else {       // B-side [hi|hi|lo]
        *reinterpret_cast<ushort4*>(dst + 64)  = hv;
        *reinterpret_cast<ushort4*>(dst + 128) = lv;
    }
}

// ---------------- generic split-K reduce -> f32 (+bias) ----------------
__global__ __launch_bounds__(256)
void reduce_k(const float* __restrict__ part, float* __restrict__ C,
              const float* __restrict__ bias, int N, int splitk)
{
    const long MN = (long)kS * N;
    long idx = ((long)blockIdx.x * 256 + threadIdx.x) * 4;
    const float* pz = part + idx;
    float4 s = *reinterpret_cast<const float4*>(pz);
    for (int t = 1; t < splitk; ++t) {
        float4 v = *reinterpret_cast<const float4*>(pz + (long)t * MN);
        s.x += v.x; s.y += v.y; s.z += v.z; s.w += v.w;
    }
    int n = (int)(idx % N);
    s.x += bias[n]; s.y += bias[n + 1]; s.z += bias[n + 2]; s.w += bias[n + 3];
    *reinterpret_cast<float4*>(C + idx) = s;
}

// ---------------- FFN1 reduce: bias + relu + direct 3-split to hb ----------------
__global__ __launch_bounds__(256)
void reduce3_k(const float* __restrict__ part, unsigned short* __restrict__ hb,
               const float* __restrict__ bias, int splitk)
{
    const long MN = (long)kS * kDFF;
    long idx = ((long)blockIdx.x * 256 + threadIdx.x) * 4;
    const float* pz = part + idx;
    float4 s = *reinterpret_cast<const float4*>(pz);
    for (int t = 1; t < splitk; ++t) {
        float4 v = *reinterpret_cast<const float4*>(pz + (long)t * MN);
        s.x += v.x; s.y += v.y; s.z += v.z; s.w += v.w;
    }
    int m = (int)(idx >> 11), n = (int)(idx & 2047);
    float fv[4] = {fmaxf(s.x + bias[n], 0.f), fmaxf(s.y + bias[n + 1], 0.f),
                   fmaxf(s.z + bias[n + 2], 0.f), fmaxf(s.w + bias[n + 3], 0.f)};
    unsigned short h[4], lo[4];
#pragma unroll
    for (int j = 0; j < 4; ++j) {
        h[j] = f2bf(fv[j]);
        lo[j] = f2bf(fv[j] - bf2f(h[j]));
    }
    unsigned short* dst = hb + (long)m * 6144 + n;
    ushort4 hv = make_ushort4(h[0], h[1], h[2], h[3]);
    *reinterpret_cast<ushort4*>(dst)        = hv;
    *reinterpret_cast<ushort4*>(dst + 2048) = make_ushort4(lo[0], lo[1], lo[2], lo[3]);
    *reinterpret_cast<ushort4*>(dst + 4096) = hv;
}

// ---------------- residual add + layernorm (in place on x, + 3-split xb) --------
__global__ __launch_bounds__(256)
void add_ln_k(float* __restrict__ x, const float* __restrict__ y,
              const float* __restrict__ g, const float* __restrict__ b,
              unsigned short* __restrict__ xb)
{
    __shared__ float sm[4];
    int row = blockIdx.x, t = threadIdx.x;
    float* xr = x + (long)row * kD;
    const float* yr = y + (long)row * kD;
    float s0 = xr[t] + yr[t];
    float s1 = xr[t + 256] + yr[t + 256];
    float sum = wave_sum(s0 + s1);
    if ((t & 63) == 0) sm[t >> 6] = sum;
    __syncthreads();
    sum = sm[0] + sm[1] + sm[2] + sm[3];
    float mu = sum * (1.f / kD);
    float d0 = s0 - mu, d1 = s1 - mu;
    __syncthreads();
    float vs = wave_sum(d0 * d0 + d1 * d1);
    if ((t & 63) == 0) sm[t >> 6] = vs;
    __syncthreads();
    vs = sm[0] + sm[1] + sm[2] + sm[3];
    float rs = rsqrtf(vs * (1.f / kD) + 1e-5f);
    float o0 = fmaf(d0 * rs, g[t], b[t]);
    float o1 = fmaf(d1 * rs, g[t + 256], b[t + 256]);
    xr[t]       = o0;
    xr[t + 256] = o1;
    unsigned short h0 = f2bf(o0), l0 = f2bf(o0 - bf2f(h0));
    unsigned short h1 = f2bf(o1), l1 = f2bf(o1 - bf2f(h1));
    unsigned short* xrow = xb + (long)row * 1536;
    xrow[t]            = h0;  xrow[t + 256]        = h1;
    xrow[t + 512]      = l0;  xrow[t + 768]        = l1;
    xrow[t + 1024]     = h0;  xrow[t + 1280]       = h1;
}

// ---------------- mean-pool partials ----------------
__global__ __launch_bounds__(256)
void pool_k(const float* __restrict__ x, float* __restrict__ partial)
{
    int col = blockIdx.x * 256 + threadIdx.x;
    int rb = blockIdx.y;
    float s = 0.f;
    for (int r = rb * 128; r < rb * 128 + 128; ++r) s += x[(long)r * kD + col];
    partial[rb * kD + col] = s;
}

// ---------------- classifier head ----------------
__global__ __launch_bounds__(256)
void head_k(const float* __restrict__ partial,
            const float* __restrict__ c1w, const float* __restrict__ c1b,
            const float* __restrict__ c2w, const float* __restrict__ c2b,
            float* __restrict__ out)
{
    __shared__ float pooled[kD];
    __shared__ float h1[256];
    int t = threadIdx.x;
    for (int d = t; d < kD; d += 256) {
        float s = 0.f;
        for (int r = 0; r < 8; ++r) s += partial[r * kD + d];
        pooled[d] = s * (1.0f / kS);
    }
    __syncthreads();
    float acc = c1b[t];
    for (int f = 0; f < kD; ++f) acc = fmaf(pooled[f], c1w[f * 256 + t], acc);
    h1[t] = fmaxf(acc, 0.f);
    __syncthreads();
    if (t < 10) {
        float o = c2b[t];
        for (int f = 0; f < 256; ++f) o = fmaf(h1[f], c2w[f * 10 + t], o);
        out[t] = o;
    }
}

// ---------------- launch ----------------
extern "C" void kernel_launch(void* const* d_in, const int* in_sizes, int n_in,
                              void* d_out, int out_size, void* d_ws, size_t ws_size,
                              hipStream_t stream)
{
    (void)in_sizes; (void)n_in; (void)out_size; (void)ws_size;
    const float* features = (const float*)d_in[0];
    const float* positions= (const float*)d_in[1];
    const float* fb       = (const float*)d_in[2];
    const float* in_w     = (const float*)d_in[3];
    const float* in_b     = (const float*)d_in[4];
    const float* qw  = (const float*)d_in[5];
    const float* qb  = (const float*)d_in[6];
    const float* kw  = (const float*)d_in[7];
    const float* kb  = (const float*)d_in[8];
    const float* vw  = (const float*)d_in[9];
    const float* vb  = (const float*)d_in[10];
    const float* ow  = (const float*)d_in[11];
    const float* ob  = (const float*)d_in[12];
    const float* db1w= (const float*)d_in[13];
    const float* db1b= (const float*)d_in[14];
    const float* db2w= (const float*)d_in[15];
    const float* db2b= (const float*)d_in[16];
    const float* n1g = (const float*)d_in[17];
    const float* n1b = (const float*)d_in[18];
    const float* n2g = (const float*)d_in[19];
    const float* n2b = (const float*)d_in[20];
    const float* f1w = (const float*)d_in[21];
    const float* f1b = (const float*)d_in[22];
    const float* f2w = (const float*)d_in[23];
    const float* f2b = (const float*)d_in[24];
    const float* c1w = (const float*)d_in[25];
    const float* c1b = (const float*)d_in[26];
    const float* c2w = (const float*)d_in[27];
    const float* c2b = (const float*)d_in[28];

    float* ws = (float*)d_ws;
    const long SD = (long)kS * kD;            // 524288
    float* x      = ws;
    float* v      = ws + 1 * SD;
    float* y      = ws + 2 * SD;
    float* dist   = ws + 3 * SD;              // 2*SD
    float* part   = ws + 5 * SD;              // 12*SD scratch (QKV partials / flash partials)
    float* bpw    = ws + 17 * SD;
    float* Atab   = bpw + 256;
    float* Btab   = Atab + 2080;
    float* partial= Btab + 2080;

    // flash partial overlays inside `part` (dead between QKV-reduce and O-proj)
    float* po = part;                          // 8*8*64*16*64 = 4,194,304 floats
    float* pmv = part + 4194304;               // 65536
    float* plv = pmv + 65536;                  // 65536

    unsigned short* ub = (unsigned short*)(ws + 17 * SD + 8512);
    unsigned short* xb   = ub;                       // 1024*1536
    unsigned short* aob  = xb   + 1572864;           // 1024*1536
    unsigned short* qb3  = aob  + 1572864;           // 8*1024*192
    unsigned short* kb3  = qb3  + 1572864;
    unsigned short* vtb  = kb3  + 1572864;           // 512*1024 (f16)
    unsigned short* hb   = vtb  + 524288;            // 1024*6144
    unsigned short* qwb  = hb   + 6291456;           // 2 x 512*1536
    unsigned short* kwb  = qwb  + 1572864;
    unsigned short* vwb  = kwb  + 1572864;
    unsigned short* owb  = vwb  + 1572864;
    unsigned short* f1wb = owb  + 1572864;           // 2 x 2048*1536
    unsigned short* f2wb = f1wb + 6291456;           // 2 x 512*6144
    unsigned short* bmap = f2wb + 6291456;           // 8*1024*1024 f16 bias map

    input_pe_k<<<kS, 256, 0, stream>>>(features, positions, fb, in_w, in_b, x);
    dist_k<<<kS, 256, 0, stream>>>(positions, dist);
    pwl_sort_k<<<2, 128, 0, stream>>>(db1w, db1b, bpw);
    pwl_tab_k<<<dim3(129, 2), 256, 0, stream>>>(db1w, db1b, db2w, db2b, bpw, Atab, Btab);
    split3_rm_k<<<512, 256, 0, stream>>>(x, xb, 524288, 9, 512);

    split3_tr_k<<<dim3(16, 16, 2), 256, 0, stream>>>(qw, qwb, 512, 512, 262144, 786432);
    split3_tr_k<<<dim3(16, 16, 2), 256, 0, stream>>>(kw, kwb, 512, 512, 262144, 786432);
    split3_tr_k<<<dim3(16, 16, 2), 256, 0, stream>>>(vw, vwb, 512, 512, 262144, 786432);
    split3_tr_k<<<dim3(16, 16, 2), 256, 0, stream>>>(ow, owb, 512, 512, 262144, 786432);
    split3_tr_k<<<dim3(16, 64, 2), 256, 0, stream>>>(f1w, f1wb, 512, 2048, 1048576, 3145728);
    split3_tr_k<<<dim3(64, 16, 2), 256, 0, stream>>>(f2w, f2wb, 2048, 512, 1048576, 3145728);

    for (int l = 0; l < 2; ++l) {
        // per-layer bias map (f16, all heads per thread)
        biasmap_k<<<1024, 256, 0, stream>>>(
            dist, bpw + l * 128, Atab + l * 1040, Btab + l * 1040, bmap);

        // QKV: A=xb (1024x1536), split-K x4 -> partials; reduce fuses bias + q/k 3-split
        bgemm_k<<<dim3(16, 4, 12), 256, 0, stream>>>(
            xb, qwb + l * 786432, kwb + l * 786432, vwb + l * 786432,
            1024, 512, 384, 1536, 1536, 0, 4, part);
        reduce_qkv_k<<<dim3(512, 3), 256, 0, stream>>>(
            part, qb3, kb3, v, qb + l * kD, kb + l * kD, vb + l * kD);
        tr_f16_k<<<dim3(32, 16), 256, 0, stream>>>(v, vtb, 1024, 512, 1024.f);

        // fused attention: K-split partials + merge -> aob (3-split)
        flash_part_k<<<dim3(64, 8, 8), 64, 0, stream>>>(
            qb3, kb3, vtb, bmap, po, pmv, plv);
        flash_merge_k<<<256, 256, 0, stream>>>(po, pmv, plv, aob);

        // O-proj: split-K x8
        bgemm_k<<<dim3(16, 4, 8), 256, 0, stream>>>(
            aob, owb + l * 786432, owb + l * 786432, owb + l * 786432,
            1024, 512, 192, 1536, 1536, 0, 8, part);
        reduce_k<<<512, 256, 0, stream>>>(part, y, ob + l * kD, 512, 8);
        add_ln_k<<<kS, 256, 0, stream>>>(x, y, n1g + l * kD, n1b + l * kD, xb);

        // FFN1: split-K x2, reduce fuses bias+relu+3-split -> hb
        bgemm_k<<<dim3(16, 16, 2), 256, 0, stream>>>(
            xb, f1wb + l * 3145728, f1wb + l * 3145728, f1wb + l * 3145728,
            1024, 2048, 768, 1536, 1536, 0, 2, part);
        reduce3_k<<<2048, 256, 0, stream>>>(part, hb, f1b + l * kDFF, 2);

        // FFN2: split-K x8
        bgemm_k<<<dim3(16, 4, 8), 256, 0, stream>>>(
            hb, f2wb + l * 3145728, f2wb + l * 3145728, f2wb + l * 3145728,
            1024, 512, 768, 6144, 6144, 0, 8, part);
        reduce_k<<<512, 256, 0, stream>>>(part, y, f2b + l * kD, 512, 8);
        add_ln_k<<<kS, 256, 0, stream>>>(x, y, n2g + l * kD, n2b + l * kD, xb);
    }

    pool_k<<<dim3(2, 8), 256, 0, stream>>>(x, partial);
    head_k<<<1, 256, 0, stream>>>(partial, c1w, c1b, c2w, c2b, (float*)d_out);
}

// Round 12
// 470.759 us; speedup vs baseline: 1.3239x; 1.0130x over previous
//
#include <hip/hip_runtime.h>

namespace {
constexpr int kS   = 1024;
constexpr int kD   = 512;
constexpr int kH   = 8;
constexpr int kDFF = 2048;
constexpr int kNF  = 85;   // D//6
}

typedef __attribute__((ext_vector_type(8))) short bhalf8_t;    // 8x16-bit in 4 VGPRs
typedef _Float16 half8_t __attribute__((ext_vector_type(8)));
typedef __attribute__((ext_vector_type(4))) float f32x4_t;

// ---------------- helpers ----------------
__device__ __forceinline__ float wave_sum(float v) {
#pragma unroll
    for (int o = 1; o < 64; o <<= 1) v += __shfl_xor(v, o, 64);
    return v;
}
__device__ __forceinline__ unsigned short f2bf(float f) {   // RNE fp32->bf16
    unsigned u = __float_as_uint(f);
    u = (u + 0x7FFF + ((u >> 16) & 1)) >> 16;
    return (unsigned short)u;
}
__device__ __forceinline__ float bf2f(unsigned short h) {
    return __uint_as_float(((unsigned)h) << 16);
}
__device__ __forceinline__ unsigned short f2h(float f) {    // RNE fp32->fp16
    _Float16 h = (_Float16)f;
    return __builtin_bit_cast(unsigned short, h);
}
__device__ __forceinline__ float h2f(unsigned short u) {
    return (float)__builtin_bit_cast(_Float16, u);
}

// ---------------- input projection + positional encoding ----------------
__global__ __launch_bounds__(256)
void input_pe_k(const float* __restrict__ feat, const float* __restrict__ pos,
                const float* __restrict__ fb, const float* __restrict__ in_w,
                const float* __restrict__ in_b, float* __restrict__ x)
{
    int s = blockIdx.x;
    int t = threadIdx.x;
    __shared__ float f[64];
    if (t < 64) f[t] = feat[s * 64 + t];
    __syncthreads();
    float acc0 = in_b[t], acc1 = in_b[t + 256];
#pragma unroll 8
    for (int c = 0; c < 64; ++c) {
        float fv = f[c];
        acc0 = fmaf(fv, in_w[c * kD + t], acc0);
        acc1 = fmaf(fv, in_w[c * kD + 256 + t], acc1);
    }
    float pe0 = 0.f, pe1 = 0.f;
    {
        int d = t;
        if (d < 6 * kNF) {
            int seg = d / kNF, idx = d - seg * kNF;
            float cs = pos[s * 3 + (seg >> 1)] * fb[idx];
            pe0 = (seg & 1) ? cosf(cs) : sinf(cs);
        }
        d = t + 256;
        if (d < 6 * kNF) {
            int seg = d / kNF, idx = d - seg * kNF;
            float cs = pos[s * 3 + (seg >> 1)] * fb[idx];
            pe1 = (seg & 1) ? cosf(cs) : sinf(cs);
        }
    }
    x[s * kD + t]       = acc0 + pe0;
    x[s * kD + 256 + t] = acc1 + pe1;
}

// ---------------- pairwise distance matrix ----------------
__global__ __launch_bounds__(256)
void dist_k(const float* __restrict__ pos, float* __restrict__ dist)
{
    int i = blockIdx.x;
    float px = pos[i * 3], py = pos[i * 3 + 1], pz = pos[i * 3 + 2];
    for (int j = threadIdx.x; j < kS; j += 256) {
        float dx = px - pos[j * 3], dy = py - pos[j * 3 + 1], dz = pz - pos[j * 3 + 2];
        float sq = dx * dx + dy * dy + dz * dz;
        dist[(long)i * kS + j] = sq > 0.f ? sqrtf(sq) : 0.f;
    }
}

// ---------------- PWL: sort breakpoints only (tiny) ----------------
__global__ __launch_bounds__(128)
void pwl_sort_k(const float* __restrict__ a_, const float* __restrict__ b_,
                float* __restrict__ bp_out)
{
    int l = blockIdx.x;
    a_ += l * 128; b_ += l * 128; bp_out += l * 128;
    __shared__ float key[128];
    int t = threadIdx.x;
    float a = a_[t], b = b_[t];
    key[t] = (a != 0.f) ? (-b / a) : 3.0e38f;
    __syncthreads();
    for (int ksz = 2; ksz <= 128; ksz <<= 1) {
        for (int j = ksz >> 1; j > 0; j >>= 1) {
            int ixj = t ^ j;
            if (ixj > t) {
                bool up = ((t & ksz) == 0);
                float x0 = key[t], x1 = key[ixj];
                if ((x0 > x1) == up) { key[t] = x1; key[ixj] = x0; }
            }
            __syncthreads();
        }
    }
    bp_out[t] = key[t];
}

// ---------------- PWL: per-segment table build ----------------
__global__ __launch_bounds__(256)
void pwl_tab_k(const float* __restrict__ a_, const float* __restrict__ b_,
               const float* __restrict__ w2, const float* __restrict__ b2,
               const float* __restrict__ bp, float* __restrict__ Atab,
               float* __restrict__ Btab)
{
    int l = blockIdx.y;
    int seg = blockIdx.x;   // 0..128
    a_ += l * 128; b_ += l * 128; w2 += l * 1024; b2 += l * 8;
    bp += l * 128; Atab += l * 1040; Btab += l * 1040;

    float m;
    if (seg == 0)        m = bp[0] - 1.0f;
    else if (seg == 128) m = bp[127] + 1.0f;
    else                 m = 0.5f * (bp[seg - 1] + bp[seg]);

    int t = threadIdx.x;
    int h = t & 7, cg = t >> 3;   // cg 0..31
    float A = 0.f, B = 0.f;
#pragma unroll
    for (int j = 0; j < 4; ++j) {
        int c = cg * 4 + j;
        float a = a_[c], b = b_[c];
        if (fmaf(a, m, b) > 0.f) {
            float w = w2[c * 8 + h];
            A = fmaf(a, w, A);
            B = fmaf(b, w, B);
        }
    }
#pragma unroll
    for (int off = 8; off < 64; off <<= 1) {
        A += __shfl_xor(A, off, 64);
        B += __shfl_xor(B, off, 64);
    }
    __shared__ float sA[4][8], sB[4][8];
    int w = t >> 6, lane = t & 63;
    if (lane < 8) { sA[w][lane] = A; sB[w][lane] = B; }
    __syncthreads();
    if (t < 8) {
        float At = sA[0][t] + sA[1][t] + sA[2][t] + sA[3][t];
        float Bt = sB[0][t] + sB[1][t] + sB[2][t] + sB[3][t];
        Atab[seg * 8 + t] = At;
        Btab[seg * 8 + t] = Bt + b2[t];
    }
}

// ---------------- per-layer bias map: one search -> all 8 heads ----------------
__global__ __launch_bounds__(256)
void biasmap_k(const float* __restrict__ dist, const float* __restrict__ bp,
               const float* __restrict__ Atab, const float* __restrict__ Btab,
               unsigned short* __restrict__ bmap)
{
    __shared__ float bps[128], Ah[1032], Bh[1032];
    int t = threadIdx.x;
    if (t < 128) bps[t] = bp[t];
    for (int i = t; i < 1032; i += 256) { Ah[i] = Atab[i]; Bh[i] = Btab[i]; }
    __syncthreads();
    long i = ((long)blockIdx.x * 256 + t) * 4;
    float4 d4 = *reinterpret_cast<const float4*>(dist + i);
    float dv[4] = {d4.x, d4.y, d4.z, d4.w};
    int seg[4];
#pragma unroll
    for (int j = 0; j < 4; ++j) {
        float tv = dv[j];
        int lo = 0, hi = 128;
        while (lo < hi) { int mid = (lo + hi) >> 1; if (bps[mid] < tv) lo = mid + 1; else hi = mid; }
        seg[j] = lo;
    }
#pragma unroll
    for (int h = 0; h < 8; ++h) {
        unsigned short o[4];
#pragma unroll
        for (int j = 0; j < 4; ++j)
            o[j] = f2h(fmaf(Ah[seg[j] * 8 + h], dv[j], Bh[seg[j] * 8 + h]));
        *reinterpret_cast<ushort4*>(bmap + (long)h * 1048576 + i) =
            make_ushort4(o[0], o[1], o[2], o[3]);
    }
}

// ---------------- fp32 -> bf16 3-term split, row-major (order0 [hi|lo|hi]) ------
__global__ __launch_bounds__(256)
void split3_rm_k(const float* __restrict__ in, unsigned short* __restrict__ out,
                 int total, int kshift, int ldin)
{
    long i = ((long)blockIdx.x * 256 + threadIdx.x) * 4;
    if (i >= total) return;
    int K = 1 << kshift;
    int m = (int)(i >> kshift), k = (int)(i & (K - 1));
    float4 v = *reinterpret_cast<const float4*>(in + (long)m * ldin + k);
    unsigned short h[4], lo[4];
    float fv[4] = {v.x, v.y, v.z, v.w};
#pragma unroll
    for (int j = 0; j < 4; ++j) {
        h[j] = f2bf(fv[j]);
        lo[j] = f2bf(fv[j] - bf2f(h[j]));
    }
    unsigned short* op = out + (long)m * (3 * K) + k;
    ushort4 hv = make_ushort4(h[0], h[1], h[2], h[3]);
    *reinterpret_cast<ushort4*>(op)         = hv;
    *reinterpret_cast<ushort4*>(op + K)     = make_ushort4(lo[0], lo[1], lo[2], lo[3]);
    *reinterpret_cast<ushort4*>(op + 2 * K) = hv;
}

// ---------------- fp32 K x N -> bf16 N x 3K transpose-split (weights, [hi|hi|lo]) --
__global__ __launch_bounds__(256)
void split3_tr_k(const float* __restrict__ in, unsigned short* __restrict__ out,
                 int K, int N, long szIn, long szOut)
{
    __shared__ float tile[32][33];
    int z = blockIdx.z;
    in  += (long)z * szIn;
    out += (long)z * szOut;
    int k0 = blockIdx.x * 32, n0 = blockIdx.y * 32;
    int t = threadIdx.x;
    int r = t >> 3, c4 = (t & 7) * 4;
    float4 v = *reinterpret_cast<const float4*>(&in[(long)(k0 + r) * N + n0 + c4]);
    tile[r][c4] = v.x; tile[r][c4 + 1] = v.y; tile[r][c4 + 2] = v.z; tile[r][c4 + 3] = v.w;
    __syncthreads();
    int nr = t >> 3, kq = (t & 7) * 4;
    unsigned short h[4], lo[4];
#pragma unroll
    for (int j = 0; j < 4; ++j) {
        float f = tile[kq + j][nr];
        h[j] = f2bf(f);
        lo[j] = f2bf(f - bf2f(h[j]));
    }
    unsigned short* op = out + (long)(n0 + nr) * (3 * K) + k0 + kq;
    ushort4 hv = make_ushort4(h[0], h[1], h[2], h[3]);
    *reinterpret_cast<ushort4*>(op)         = hv;
    *reinterpret_cast<ushort4*>(op + K)     = hv;
    *reinterpret_cast<ushort4*>(op + 2 * K) = make_ushort4(lo[0], lo[1], lo[2], lo[3]);
}

// ---------------- fp32 K x N -> f16 N x K transpose with scale (V matrix) -------
__global__ __launch_bounds__(256)
void tr_f16_k(const float* __restrict__ in, unsigned short* __restrict__ out,
              int K, int N, float scl)
{
    __shared__ float tile[32][33];
    int k0 = blockIdx.x * 32, n0 = blockIdx.y * 32;
    int t = threadIdx.x;
    int r = t >> 3, c4 = (t & 7) * 4;
    float4 v = *reinterpret_cast<const float4*>(&in[(long)(k0 + r) * N + n0 + c4]);
    tile[r][c4] = v.x; tile[r][c4 + 1] = v.y; tile[r][c4 + 2] = v.z; tile[r][c4 + 3] = v.w;
    __syncthreads();
    int nr = t >> 3, kq = (t & 7) * 4;
    unsigned short h[4];
#pragma unroll
    for (int j = 0; j < 4; ++j) h[j] = f2h(tile[kq + j][nr] * scl);
    *reinterpret_cast<ushort4*>(&out[(long)(n0 + nr) * K + k0 + kq]) =
        make_ushort4(h[0], h[1], h[2], h[3]);
}

// ---------------- 16-bit MFMA GEMM (bf16), split-K partial writer ----------------
// 64x128 tile, 4 waves of 32x64 each.
__global__ __launch_bounds__(256, 4)
void bgemm_k(const unsigned short* __restrict__ A,
             const unsigned short* __restrict__ B0, const unsigned short* __restrict__ B1,
             const unsigned short* __restrict__ B2,
             int M, int N, int K, int lda, int ldb,
             long sA, int splitk,
             float* __restrict__ Cpart)
{
    constexpr int BKp = 40;
    int tid = threadIdx.x;
    int bz = blockIdx.z;
    int z  = bz / splitk;
    int ks = bz - z * splitk;

    const unsigned short* Ap = A + (long)z * sA + (long)ks * K;
    const unsigned short* Bp = ((z == 1) ? B1 : (z == 2) ? B2 : B0) + (long)ks * K;

    __shared__ unsigned short As[64 * BKp];
    __shared__ unsigned short Bs[128 * BKp];

    int bm = blockIdx.x * 64;
    int bn = blockIdx.y * 128;
    int w = tid >> 6, lane = tid & 63, quad = lane >> 4, l16 = lane & 15;
    int wm = (w >> 1) * 32;
    int wn = (w & 1) * 64;

    int ar = tid >> 2, ac = (tid & 3) * 8;      // A: 64 rows, 4 thr/row
    int br = tid >> 1, bc = (tid & 1) * 16;     // B: 128 rows, 2 thr/row

    f32x4_t acc[2][4] = {};
    bhalf8_t aS0, bS0, bS1;

    auto ldgA = [&](int k0) {
        aS0 = *reinterpret_cast<const bhalf8_t*>(Ap + (long)(bm + ar) * lda + k0 + ac);
    };
    auto ldgB = [&](int k0) {
        const unsigned short* p = Bp + (long)(bn + br) * ldb + k0 + bc;
        bS0 = *reinterpret_cast<const bhalf8_t*>(p);
        bS1 = *reinterpret_cast<const bhalf8_t*>(p + 8);
    };

    ldgA(0); ldgB(0);

    for (int k0 = 0; k0 < K; k0 += 32) {
        *reinterpret_cast<bhalf8_t*>(&As[ar * BKp + ac])     = aS0;
        *reinterpret_cast<bhalf8_t*>(&Bs[br * BKp + bc])     = bS0;
        *reinterpret_cast<bhalf8_t*>(&Bs[br * BKp + bc + 8]) = bS1;
        __syncthreads();
        if (k0 + 32 < K) { ldgA(k0 + 32); ldgB(k0 + 32); }
        bhalf8_t af[2], bf[4];
#pragma unroll
        for (int i = 0; i < 2; ++i)
            af[i] = *reinterpret_cast<const bhalf8_t*>(&As[(wm + i * 16 + l16) * BKp + quad * 8]);
#pragma unroll
        for (int j = 0; j < 4; ++j)
            bf[j] = *reinterpret_cast<const bhalf8_t*>(&Bs[(wn + j * 16 + l16) * BKp + quad * 8]);
#pragma unroll
        for (int i = 0; i < 2; ++i)
#pragma unroll
            for (int j = 0; j < 4; ++j)
                acc[i][j] = __builtin_amdgcn_mfma_f32_16x16x32_bf16(af[i], bf[j], acc[i][j], 0, 0, 0);
        __syncthreads();
    }

    float* Cp = Cpart + (long)bz * M * N;
#pragma unroll
    for (int i = 0; i < 2; ++i)
#pragma unroll
        for (int j = 0; j < 4; ++j)
#pragma unroll
            for (int r = 0; r < 4; ++r) {
                int m = bm + wm + i * 16 + quad * 4 + r;
                int n = bn + wn + j * 16 + l16;
                Cp[(long)m * N + n] = acc[i][j][r];
            }
}

// ---------------- flash partial: one wave = (16 Q-rows, 128 keys, 1 head) --------
__global__ __launch_bounds__(64)
void flash_part_k(const unsigned short* __restrict__ qb3, const unsigned short* __restrict__ kb3,
                  const unsigned short* __restrict__ vtb, const unsigned short* __restrict__ bmap,
                  float* __restrict__ po, float* __restrict__ pm, float* __restrict__ pl)
{
    __shared__ unsigned short Ps[16 * 136];

    int tid = threadIdx.x;          // 0..63
    int qb = blockIdx.x;            // 64 Q-blocks of 16 rows
    int h  = blockIdx.y;            // 8 heads
    int z  = blockIdx.z;            // 8 key-slices of 128
    int bm = qb * 16;
    int k0 = z * 128;

    const unsigned short* Qh = qb3 + (long)h * 196608;
    const unsigned short* Kh = kb3 + (long)h * 196608;
    const unsigned short* Vh = vtb + (long)h * 65536;
    const unsigned short* Bm = bmap + (long)h * 1048576;

    int quad = tid >> 4, l16 = tid & 15;

    bhalf8_t aq[6];
#pragma unroll
    for (int kq = 0; kq < 6; ++kq)
        aq[kq] = *reinterpret_cast<const bhalf8_t*>(
            &Qh[(long)(bm + l16) * 192 + kq * 32 + quad * 8]);

    f32x4_t sacc[8] = {};
#pragma unroll
    for (int kq = 0; kq < 6; ++kq) {
        bhalf8_t bk[8];
#pragma unroll
        for (int nb = 0; nb < 8; ++nb)
            bk[nb] = *reinterpret_cast<const bhalf8_t*>(
                &Kh[(long)(k0 + nb * 16 + l16) * 192 + kq * 32 + quad * 8]);
#pragma unroll
        for (int nb = 0; nb < 8; ++nb)
            sacc[nb] = __builtin_amdgcn_mfma_f32_16x16x32_bf16(aq[kq], bk[nb], sacc[nb], 0, 0, 0);
    }

    float m_r[4] = {-3.0e38f, -3.0e38f, -3.0e38f, -3.0e38f};
#pragma unroll
    for (int nb = 0; nb < 8; ++nb)
#pragma unroll
        for (int r = 0; r < 4; ++r) {
            int gm = bm + quad * 4 + r;
            int gn = k0 + nb * 16 + l16;
            float bias = h2f(Bm[(long)gm * kS + gn]);
            float s = fmaf(sacc[nb][r], 0.125f, bias);
            sacc[nb][r] = s;
            m_r[r] = fmaxf(m_r[r], s);
        }
#pragma unroll
    for (int r = 0; r < 4; ++r) {
        float m_ = m_r[r];
#pragma unroll
        for (int off = 1; off < 16; off <<= 1) m_ = fmaxf(m_, __shfl_xor(m_, off, 64));
        m_r[r] = m_;
    }

    float l_r[4];
#pragma unroll
    for (int r = 0; r < 4; ++r) {
        int row = quad * 4 + r;
        float mN = m_r[r];
        float s_ = 0.f;
#pragma unroll
        for (int nb = 0; nb < 8; ++nb) {
            float p = __expf(sacc[nb][r] - mN);
            Ps[row * 136 + nb * 16 + l16] = f2h(p * 16384.f);
            s_ += p;
        }
#pragma unroll
        for (int off = 1; off < 16; off <<= 1) s_ += __shfl_xor(s_, off, 64);
        l_r[r] = s_;
    }

    long sbase = (((long)z * 8 + h) * 64 + qb) * 16;   // per-z stride 8192
    if (l16 == 0) {
#pragma unroll
        for (int r = 0; r < 4; ++r) {
            pm[sbase + quad * 4 + r] = m_r[r];
            pl[sbase + quad * 4 + r] = l_r[r];
        }
    }
    __syncthreads();

    f32x4_t oacc[4] = {};
#pragma unroll
    for (int kq2 = 0; kq2 < 4; ++kq2) {
        bhalf8_t ap = *reinterpret_cast<const bhalf8_t*>(&Ps[l16 * 136 + kq2 * 32 + quad * 8]);
#pragma unroll
        for (int j2 = 0; j2 < 4; ++j2) {
            bhalf8_t bv = *reinterpret_cast<const bhalf8_t*>(
                &Vh[(long)(j2 * 16 + l16) * 1024 + k0 + kq2 * 32 + quad * 8]);
            oacc[j2] = __builtin_amdgcn_mfma_f32_16x16x32_f16(
                __builtin_bit_cast(half8_t, ap), __builtin_bit_cast(half8_t, bv),
                oacc[j2], 0, 0, 0);
        }
    }

    float* pob = po + sbase * 64;
#pragma unroll
    for (int j2 = 0; j2 < 4; ++j2)
#pragma unroll
        for (int r = 0; r < 4; ++r)
            pob[(quad * 4 + r) * 64 + j2 * 16 + l16] = oacc[j2][r];
}

// ---------------- flash merge: combine 8 key-slice partials, write aob 3-split ---
__global__ __launch_bounds__(256)
void flash_merge_k(const float* __restrict__ po, const float* __restrict__ pm,
                   const float* __restrict__ pl, unsigned short* __restrict__ aob)
{
    int t = blockIdx.x * 256 + threadIdx.x;   // 65536 = 8h * 64qb * 16row * 8chunks
    int c8  = t & 7;
    int row = (t >> 3) & 15;
    int qb  = (t >> 7) & 63;
    int h   = t >> 13;
    long sidx = (((long)h * 64) + qb) * 16 + row;   // per-z stride 8192

    float m[8];
    float M = -3.0e38f;
#pragma unroll
    for (int z = 0; z < 8; ++z) { m[z] = pm[z * 8192 + sidx]; M = fmaxf(M, m[z]); }
    float w[8], lt = 0.f;
#pragma unroll
    for (int z = 0; z < 8; ++z) {
        w[z] = __expf(m[z] - M);
        lt = fmaf(pl[z * 8192 + sidx], w[z], lt);
    }
    float acc[8] = {};
#pragma unroll
    for (int z = 0; z < 8; ++z) {
        const float* p = po + (z * 8192 + sidx) * 64 + c8 * 8;
        float4 a = *reinterpret_cast<const float4*>(p);
        float4 b = *reinterpret_cast<const float4*>(p + 4);
        acc[0] = fmaf(a.x, w[z], acc[0]); acc[1] = fmaf(a.y, w[z], acc[1]);
        acc[2] = fmaf(a.z, w[z], acc[2]); acc[3] = fmaf(a.w, w[z], acc[3]);
        acc[4] = fmaf(b.x, w[z], acc[4]); acc[5] = fmaf(b.y, w[z], acc[5]);
        acc[6] = fmaf(b.z, w[z], acc[6]); acc[7] = fmaf(b.w, w[z], acc[7]);
    }
    float inv = 1.f / (16777216.f * lt);
    unsigned short hi[8], lo[8];
#pragma unroll
    for (int j = 0; j < 8; ++j) {
        float val = acc[j] * inv;
        hi[j] = f2bf(val);
        lo[j] = f2bf(val - bf2f(hi[j]));
    }
    long base = ((long)qb * 16 + row) * 1536 + h * 64 + c8 * 8;
    *reinterpret_cast<ushort4*>(&aob[base])        = make_ushort4(hi[0], hi[1], hi[2], hi[3]);
    *reinterpret_cast<ushort4*>(&aob[base + 4])    = make_ushort4(hi[4], hi[5], hi[6], hi[7]);
    *reinterpret_cast<ushort4*>(&aob[base + 512])  = make_ushort4(lo[0], lo[1], lo[2], lo[3]);
    *reinterpret_cast<ushort4*>(&aob[base + 516])  = make_ushort4(lo[4], lo[5], lo[6], lo[7]);
    *reinterpret_cast<ushort4*>(&aob[base + 1024]) = make_ushort4(hi[0], hi[1], hi[2], hi[3]);
    *reinterpret_cast<ushort4*>(&aob[base + 1028]) = make_ushort4(hi[4], hi[5], hi[6], hi[7]);
}

// ---------------- QKV split-K reduce: bias + direct 3-split to qb3/kb3, v f32 ----
__global__ __launch_bounds__(256)
void reduce_qkv_k(const float* __restrict__ part,
                  unsigned short* __restrict__ qb3, unsigned short* __restrict__ kb3,
                  float* __restrict__ v,
                  const float* __restrict__ qbias, const float* __restrict__ kbias,
                  const float* __restrict__ vbias, int splitk)
{
    int z = blockIdx.y;
    const long MN = (long)kS * kD;
    long idx = ((long)blockIdx.x * 256 + threadIdx.x) * 4;
    const float* pz = part + (long)z * splitk * MN + idx;
    float4 s = *reinterpret_cast<const float4*>(pz);
    for (int t = 1; t < splitk; ++t) {
        float4 vv = *reinterpret_cast<const float4*>(pz + (long)t * MN);
        s.x += vv.x; s.y += vv.y; s.z += vv.z; s.w += vv.w;
    }
    int m = (int)(idx >> 9), n = (int)(idx & 511);
    const float* bzp = (z == 1) ? kbias : (z == 2) ? vbias : qbias;
    s.x += bzp[n]; s.y += bzp[n + 1]; s.z += bzp[n + 2]; s.w += bzp[n + 3];
    if (z == 2) {
        *reinterpret_cast<float4*>(v + idx) = s;
        return;
    }
    float fv[4] = {s.x, s.y, s.z, s.w};
    unsigned short h[4], lo[4];
#pragma unroll
    for (int j = 0; j < 4; ++j) {
        h[j] = f2bf(fv[j]);
        lo[j] = f2bf(fv[j] - bf2f(h[j]));
    }
    int head = n >> 6, hc = n & 63;
    unsigned short* dst = ((z == 1) ? kb3 : qb3) + (long)head * 196608 + (long)m * 192 + hc;
    ushort4 hv = make_ushort4(h[0], h[1], h[2], h[3]);
    ushort4 lv = make_ushort4(lo[0], lo[1], lo[2], lo[3]);
    *reinterpret_cast<ushort4*>(dst) = hv;
    if (z == 0) {  // A-side [hi|lo|hi]
        *reinterpret_cast<ushort4*>(dst + 64)  = lv;
        *reinterpret_cast<ushort4*>(dst + 128) = hv;
    } else {       // B-side [hi|hi|lo]
        *reinterpret_cast<ushort4*>(dst + 64)  = hv;
        *reinterpret_cast<ushort4*>(dst + 128) = lv;
    }
}

// ---------------- FFN1 reduce: bias + relu + direct 3-split to hb ----------------
__global__ __launch_bounds__(256)
void reduce3_k(const float* __restrict__ part, unsigned short* __restrict__ hb,
               const float* __restrict__ bias, int splitk)
{
    const long MN = (long)kS * kDFF;
    long idx = ((long)blockIdx.x * 256 + threadIdx.x) * 4;
    const float* pz = part + idx;
    float4 s = *reinterpret_cast<const float4*>(pz);
    for (int t = 1; t < splitk; ++t) {
        float4 v = *reinterpret_cast<const float4*>(pz + (long)t * MN);
        s.x += v.x; s.y += v.y; s.z += v.z; s.w += v.w;
    }
    int m = (int)(idx >> 11), n = (int)(idx & 2047);
    float fv[4] = {fmaxf(s.x + bias[n], 0.f), fmaxf(s.y + bias[n + 1], 0.f),
                   fmaxf(s.z + bias[n + 2], 0.f), fmaxf(s.w + bias[n + 3], 0.f)};
    unsigned short h[4], lo[4];
#pragma unroll
    for (int j = 0; j < 4; ++j) {
        h[j] = f2bf(fv[j]);
        lo[j] = f2bf(fv[j] - bf2f(h[j]));
    }
    unsigned short* dst = hb + (long)m * 6144 + n;
    ushort4 hv = make_ushort4(h[0], h[1], h[2], h[3]);
    *reinterpret_cast<ushort4*>(dst)        = hv;
    *reinterpret_cast<ushort4*>(dst + 2048) = make_ushort4(lo[0], lo[1], lo[2], lo[3]);
    *reinterpret_cast<ushort4*>(dst + 4096) = hv;
}

// ---------------- fused: split-K reduce + bias + residual + LN + 3-split xb ------
__global__ __launch_bounds__(256)
void add_ln_fused_k(const float* __restrict__ part, float* __restrict__ x,
                    const float* __restrict__ bias,
                    const float* __restrict__ g, const float* __restrict__ b,
                    unsigned short* __restrict__ xb, int splitk)
{
    __shared__ float sm[4];
    int row = blockIdx.x, t = threadIdx.x;
    const long MN = (long)kS * kD;
    float* xr = x + (long)row * kD;
    float s0 = 0.f, s1 = 0.f;
    const float* pr = part + (long)row * kD;
    for (int sl = 0; sl < splitk; ++sl) {
        s0 += pr[(long)sl * MN + t];
        s1 += pr[(long)sl * MN + t + 256];
    }
    s0 += bias[t] + xr[t];
    s1 += bias[t + 256] + xr[t + 256];
    float sum = wave_sum(s0 + s1);
    if ((t & 63) == 0) sm[t >> 6] = sum;
    __syncthreads();
    sum = sm[0] + sm[1] + sm[2] + sm[3];
    float mu = sum * (1.f / kD);
    float d0 = s0 - mu, d1 = s1 - mu;
    __syncthreads();
    float vs = wave_sum(d0 * d0 + d1 * d1);
    if ((t & 63) == 0) sm[t >> 6] = vs;
    __syncthreads();
    vs = sm[0] + sm[1] + sm[2] + sm[3];
    float rs = rsqrtf(vs * (1.f / kD) + 1e-5f);
    float o0 = fmaf(d0 * rs, g[t], b[t]);
    float o1 = fmaf(d1 * rs, g[t + 256], b[t + 256]);
    xr[t]       = o0;
    xr[t + 256] = o1;
    unsigned short h0 = f2bf(o0), l0 = f2bf(o0 - bf2f(h0));
    unsigned short h1 = f2bf(o1), l1 = f2bf(o1 - bf2f(h1));
    unsigned short* xrow = xb + (long)row * 1536;
    xrow[t]            = h0;  xrow[t + 256]        = h1;
    xrow[t + 512]      = l0;  xrow[t + 768]        = l1;
    xrow[t + 1024]     = h0;  xrow[t + 1280]       = h1;
}

// ---------------- mean-pool partials ----------------
__global__ __launch_bounds__(256)
void pool_k(const float* __restrict__ x, float* __restrict__ partial)
{
    int col = blockIdx.x * 256 + threadIdx.x;
    int rb = blockIdx.y;
    float s = 0.f;
    for (int r = rb * 128; r < rb * 128 + 128; ++r) s += x[(long)r * kD + col];
    partial[rb * kD + col] = s;
}

// ---------------- classifier head ----------------
__global__ __launch_bounds__(256)
void head_k(const float* __restrict__ partial,
            const float* __restrict__ c1w, const float* __restrict__ c1b,
            const float* __restrict__ c2w, const float* __restrict__ c2b,
            float* __restrict__ out)
{
    __shared__ float pooled[kD];
    __shared__ float h1[256];
    int t = threadIdx.x;
    for (int d = t; d < kD; d += 256) {
        float s = 0.f;
        for (int r = 0; r < 8; ++r) s += partial[r * kD + d];
        pooled[d] = s * (1.0f / kS);
    }
    __syncthreads();
    float acc = c1b[t];
    for (int f = 0; f < kD; ++f) acc = fmaf(pooled[f], c1w[f * 256 + t], acc);
    h1[t] = fmaxf(acc, 0.f);
    __syncthreads();
    if (t < 10) {
        float o = c2b[t];
        for (int f = 0; f < 256; ++f) o = fmaf(h1[f], c2w[f * 10 + t], o);
        out[t] = o;
    }
}

// ---------------- launch ----------------
extern "C" void kernel_launch(void* const* d_in, const int* in_sizes, int n_in,
                              void* d_out, int out_size, void* d_ws, size_t ws_size,
                              hipStream_t stream)
{
    (void)in_sizes; (void)n_in; (void)out_size; (void)ws_size;
    const float* features = (const float*)d_in[0];
    const float* positions= (const float*)d_in[1];
    const float* fb       = (const float*)d_in[2];
    const float* in_w     = (const float*)d_in[3];
    const float* in_b     = (const float*)d_in[4];
    const float* qw  = (const float*)d_in[5];
    const float* qb  = (const float*)d_in[6];
    const float* kw  = (const float*)d_in[7];
    const float* kb  = (const float*)d_in[8];
    const float* vw  = (const float*)d_in[9];
    const float* vb  = (const float*)d_in[10];
    const float* ow  = (const float*)d_in[11];
    const float* ob  = (const float*)d_in[12];
    const float* db1w= (const float*)d_in[13];
    const float* db1b= (const float*)d_in[14];
    const float* db2w= (const float*)d_in[15];
    const float* db2b= (const float*)d_in[16];
    const float* n1g = (const float*)d_in[17];
    const float* n1b = (const float*)d_in[18];
    const float* n2g = (const float*)d_in[19];
    const float* n2b = (const float*)d_in[20];
    const float* f1w = (const float*)d_in[21];
    const float* f1b = (const float*)d_in[22];
    const float* f2w = (const float*)d_in[23];
    const float* f2b = (const float*)d_in[24];
    const float* c1w = (const float*)d_in[25];
    const float* c1b = (const float*)d_in[26];
    const float* c2w = (const float*)d_in[27];
    const float* c2b = (const float*)d_in[28];

    float* ws = (float*)d_ws;
    const long SD = (long)kS * kD;            // 524288
    float* x      = ws;
    float* v      = ws + 1 * SD;
    float* dist   = ws + 3 * SD;              // 2*SD
    float* part   = ws + 5 * SD;              // 12*SD scratch
    float* bpw    = ws + 17 * SD;
    float* Atab   = bpw + 256;
    float* Btab   = Atab + 2080;
    float* partial= Btab + 2080;

    // flash partial overlays inside `part`
    float* po = part;                          // 4,194,304 floats
    float* pmv = part + 4194304;               // 65536
    float* plv = pmv + 65536;                  // 65536

    unsigned short* ub = (unsigned short*)(ws + 17 * SD + 8512);
    unsigned short* xb   = ub;                       // 1024*1536
    unsigned short* aob  = xb   + 1572864;
    unsigned short* qb3  = aob  + 1572864;           // 8*1024*192
    unsigned short* kb3  = qb3  + 1572864;
    unsigned short* vtb  = kb3  + 1572864;           // 512*1024 (f16)
    unsigned short* hb   = vtb  + 524288;            // 1024*6144
    unsigned short* qwb  = hb   + 6291456;
    unsigned short* kwb  = qwb  + 1572864;
    unsigned short* vwb  = kwb  + 1572864;
    unsigned short* owb  = vwb  + 1572864;
    unsigned short* f1wb = owb  + 1572864;
    unsigned short* f2wb = f1wb + 6291456;
    unsigned short* bmap = f2wb + 6291456;           // 8*1024*1024 f16

    input_pe_k<<<kS, 256, 0, stream>>>(features, positions, fb, in_w, in_b, x);
    dist_k<<<kS, 256, 0, stream>>>(positions, dist);
    pwl_sort_k<<<2, 128, 0, stream>>>(db1w, db1b, bpw);
    pwl_tab_k<<<dim3(129, 2), 256, 0, stream>>>(db1w, db1b, db2w, db2b, bpw, Atab, Btab);
    split3_rm_k<<<512, 256, 0, stream>>>(x, xb, 524288, 9, 512);

    split3_tr_k<<<dim3(16, 16, 2), 256, 0, stream>>>(qw, qwb, 512, 512, 262144, 786432);
    split3_tr_k<<<dim3(16, 16, 2), 256, 0, stream>>>(kw, kwb, 512, 512, 262144, 786432);
    split3_tr_k<<<dim3(16, 16, 2), 256, 0, stream>>>(vw, vwb, 512, 512, 262144, 786432);
    split3_tr_k<<<dim3(16, 16, 2), 256, 0, stream>>>(ow, owb, 512, 512, 262144, 786432);
    split3_tr_k<<<dim3(16, 64, 2), 256, 0, stream>>>(f1w, f1wb, 512, 2048, 1048576, 3145728);
    split3_tr_k<<<dim3(64, 16, 2), 256, 0, stream>>>(f2w, f2wb, 2048, 512, 1048576, 3145728);

    for (int l = 0; l < 2; ++l) {
        biasmap_k<<<1024, 256, 0, stream>>>(
            dist, bpw + l * 128, Atab + l * 1040, Btab + l * 1040, bmap);

        // QKV: split-K x2 (384 blocks)
        bgemm_k<<<dim3(16, 4, 6), 256, 0, stream>>>(
            xb, qwb + l * 786432, kwb + l * 786432, vwb + l * 786432,
            1024, 512, 768, 1536, 1536, 0, 2, part);
        reduce_qkv_k<<<dim3(512, 3), 256, 0, stream>>>(
            part, qb3, kb3, v, qb + l * kD, kb + l * kD, vb + l * kD, 2);
        tr_f16_k<<<dim3(32, 16), 256, 0, stream>>>(v, vtb, 1024, 512, 1024.f);

        // fused attention
        flash_part_k<<<dim3(64, 8, 8), 64, 0, stream>>>(
            qb3, kb3, vtb, bmap, po, pmv, plv);
        flash_merge_k<<<256, 256, 0, stream>>>(po, pmv, plv, aob);

        // O-proj: split-K x4 (256 blocks); reduce fused into add_ln
        bgemm_k<<<dim3(16, 4, 4), 256, 0, stream>>>(
            aob, owb + l * 786432, owb + l * 786432, owb + l * 786432,
            1024, 512, 384, 1536, 1536, 0, 4, part);
        add_ln_fused_k<<<kS, 256, 0, stream>>>(
            part, x, ob + l * kD, n1g + l * kD, n1b + l * kD, xb, 4);

        // FFN1: split-K x2 (512 blocks), reduce fuses bias+relu+3-split -> hb
        bgemm_k<<<dim3(16, 16, 2), 256, 0, stream>>>(
            xb, f1wb + l * 3145728, f1wb + l * 3145728, f1wb + l * 3145728,
            1024, 2048, 768, 1536, 1536, 0, 2, part);
        reduce3_k<<<2048, 256, 0, stream>>>(part, hb, f1b + l * kDFF, 2);

        // FFN2: split-K x4 (256 blocks); reduce fused into add_ln
        bgemm_k<<<dim3(16, 4, 4), 256, 0, stream>>>(
            hb, f2wb + l * 3145728, f2wb + l * 3145728, f2wb + l * 3145728,
            1024, 512, 1536, 6144, 6144, 0, 4, part);
        add_ln_fused_k<<<kS, 256, 0, stream>>>(
            part, x, f2b + l * kD, n2g + l * kD, n2b + l * kD, xb, 4);
    }

    pool_k<<<dim3(2, 8), 256, 0, stream>>>(x, partial);
    head_k<<<1, 256, 0, stream>>>(partial, c1w, c1b, c2w, c2b, (float*)d_out);
}

// Round 13
// 412.479 us; speedup vs baseline: 1.5109x; 1.1413x over previous
//
#include <hip/hip_runtime.h>

namespace {
constexpr int kS   = 1024;
constexpr int kD   = 512;
constexpr int kH   = 8;
constexpr int kDFF = 2048;
constexpr int kNF  = 85;   // D//6
}

typedef __attribute__((ext_vector_type(8))) short bhalf8_t;    // 8x16-bit in 4 VGPRs
typedef _Float16 half8_t __attribute__((ext_vector_type(8)));
typedef __attribute__((ext_vector_type(4))) float f32x4_t;

// ---------------- helpers ----------------
__device__ __forceinline__ float wave_sum(float v) {
#pragma unroll
    for (int o = 1; o < 64; o <<= 1) v += __shfl_xor(v, o, 64);
    return v;
}
__device__ __forceinline__ unsigned short f2h(float f) {    // RNE fp32->fp16
    _Float16 h = (_Float16)f;
    return __builtin_bit_cast(unsigned short, h);
}
__device__ __forceinline__ float h2f(unsigned short u) {
    return (float)__builtin_bit_cast(_Float16, u);
}

// ---------------- input projection + positional encoding ----------------
__global__ __launch_bounds__(256)
void input_pe_k(const float* __restrict__ feat, const float* __restrict__ pos,
                const float* __restrict__ fb, const float* __restrict__ in_w,
                const float* __restrict__ in_b, float* __restrict__ x)
{
    int s = blockIdx.x;
    int t = threadIdx.x;
    __shared__ float f[64];
    if (t < 64) f[t] = feat[s * 64 + t];
    __syncthreads();
    float acc0 = in_b[t], acc1 = in_b[t + 256];
#pragma unroll 8
    for (int c = 0; c < 64; ++c) {
        float fv = f[c];
        acc0 = fmaf(fv, in_w[c * kD + t], acc0);
        acc1 = fmaf(fv, in_w[c * kD + 256 + t], acc1);
    }
    float pe0 = 0.f, pe1 = 0.f;
    {
        int d = t;
        if (d < 6 * kNF) {
            int seg = d / kNF, idx = d - seg * kNF;
            float cs = pos[s * 3 + (seg >> 1)] * fb[idx];
            pe0 = (seg & 1) ? cosf(cs) : sinf(cs);
        }
        d = t + 256;
        if (d < 6 * kNF) {
            int seg = d / kNF, idx = d - seg * kNF;
            float cs = pos[s * 3 + (seg >> 1)] * fb[idx];
            pe1 = (seg & 1) ? cosf(cs) : sinf(cs);
        }
    }
    x[s * kD + t]       = acc0 + pe0;
    x[s * kD + 256 + t] = acc1 + pe1;
}

// ---------------- pairwise distance matrix ----------------
__global__ __launch_bounds__(256)
void dist_k(const float* __restrict__ pos, float* __restrict__ dist)
{
    int i = blockIdx.x;
    float px = pos[i * 3], py = pos[i * 3 + 1], pz = pos[i * 3 + 2];
    for (int j = threadIdx.x; j < kS; j += 256) {
        float dx = px - pos[j * 3], dy = py - pos[j * 3 + 1], dz = pz - pos[j * 3 + 2];
        float sq = dx * dx + dy * dy + dz * dz;
        dist[(long)i * kS + j] = sq > 0.f ? sqrtf(sq) : 0.f;
    }
}

// ---------------- PWL: sort breakpoints only (tiny) ----------------
__global__ __launch_bounds__(128)
void pwl_sort_k(const float* __restrict__ a_, const float* __restrict__ b_,
                float* __restrict__ bp_out)
{
    int l = blockIdx.x;
    a_ += l * 128; b_ += l * 128; bp_out += l * 128;
    __shared__ float key[128];
    int t = threadIdx.x;
    float a = a_[t], b = b_[t];
    key[t] = (a != 0.f) ? (-b / a) : 3.0e38f;
    __syncthreads();
    for (int ksz = 2; ksz <= 128; ksz <<= 1) {
        for (int j = ksz >> 1; j > 0; j >>= 1) {
            int ixj = t ^ j;
            if (ixj > t) {
                bool up = ((t & ksz) == 0);
                float x0 = key[t], x1 = key[ixj];
                if ((x0 > x1) == up) { key[t] = x1; key[ixj] = x0; }
            }
            __syncthreads();
        }
    }
    bp_out[t] = key[t];
}

// ---------------- PWL: per-segment table build ----------------
__global__ __launch_bounds__(256)
void pwl_tab_k(const float* __restrict__ a_, const float* __restrict__ b_,
               const float* __restrict__ w2, const float* __restrict__ b2,
               const float* __restrict__ bp, float* __restrict__ Atab,
               float* __restrict__ Btab)
{
    int l = blockIdx.y;
    int seg = blockIdx.x;   // 0..128
    a_ += l * 128; b_ += l * 128; w2 += l * 1024; b2 += l * 8;
    bp += l * 128; Atab += l * 1040; Btab += l * 1040;

    float m;
    if (seg == 0)        m = bp[0] - 1.0f;
    else if (seg == 128) m = bp[127] + 1.0f;
    else                 m = 0.5f * (bp[seg - 1] + bp[seg]);

    int t = threadIdx.x;
    int h = t & 7, cg = t >> 3;   // cg 0..31
    float A = 0.f, B = 0.f;
#pragma unroll
    for (int j = 0; j < 4; ++j) {
        int c = cg * 4 + j;
        float a = a_[c], b = b_[c];
        if (fmaf(a, m, b) > 0.f) {
            float w = w2[c * 8 + h];
            A = fmaf(a, w, A);
            B = fmaf(b, w, B);
        }
    }
#pragma unroll
    for (int off = 8; off < 64; off <<= 1) {
        A += __shfl_xor(A, off, 64);
        B += __shfl_xor(B, off, 64);
    }
    __shared__ float sA[4][8], sB[4][8];
    int w = t >> 6, lane = t & 63;
    if (lane < 8) { sA[w][lane] = A; sB[w][lane] = B; }
    __syncthreads();
    if (t < 8) {
        float At = sA[0][t] + sA[1][t] + sA[2][t] + sA[3][t];
        float Bt = sB[0][t] + sB[1][t] + sB[2][t] + sB[3][t];
        Atab[seg * 8 + t] = At;
        Btab[seg * 8 + t] = Bt + b2[t];
    }
}

// ---------------- per-layer bias map: one search -> all 8 heads ----------------
__global__ __launch_bounds__(256)
void biasmap_k(const float* __restrict__ dist, const float* __restrict__ bp,
               const float* __restrict__ Atab, const float* __restrict__ Btab,
               unsigned short* __restrict__ bmap)
{
    __shared__ float bps[128], Ah[1032], Bh[1032];
    int t = threadIdx.x;
    if (t < 128) bps[t] = bp[t];
    for (int i = t; i < 1032; i += 256) { Ah[i] = Atab[i]; Bh[i] = Btab[i]; }
    __syncthreads();
    long i = ((long)blockIdx.x * 256 + t) * 4;
    float4 d4 = *reinterpret_cast<const float4*>(dist + i);
    float dv[4] = {d4.x, d4.y, d4.z, d4.w};
    int seg[4];
#pragma unroll
    for (int j = 0; j < 4; ++j) {
        float tv = dv[j];
        int lo = 0, hi = 128;
        while (lo < hi) { int mid = (lo + hi) >> 1; if (bps[mid] < tv) lo = mid + 1; else hi = mid; }
        seg[j] = lo;
    }
#pragma unroll
    for (int h = 0; h < 8; ++h) {
        unsigned short o[4];
#pragma unroll
        for (int j = 0; j < 4; ++j)
            o[j] = f2h(fmaf(Ah[seg[j] * 8 + h], dv[j], Bh[seg[j] * 8 + h]));
        *reinterpret_cast<ushort4*>(bmap + (long)h * 1048576 + i) =
            make_ushort4(o[0], o[1], o[2], o[3]);
    }
}

// ---------------- fp32 -> f16 2-seg split, row-major (A-side [hi|lo]) ------
__global__ __launch_bounds__(256)
void split2_rm_k(const float* __restrict__ in, unsigned short* __restrict__ out,
                 int total, int kshift, int ldin)
{
    long i = ((long)blockIdx.x * 256 + threadIdx.x) * 4;
    if (i >= total) return;
    int K = 1 << kshift;
    int m = (int)(i >> kshift), k = (int)(i & (K - 1));
    float4 v = *reinterpret_cast<const float4*>(in + (long)m * ldin + k);
    unsigned short h[4], lo[4];
    float fv[4] = {v.x, v.y, v.z, v.w};
#pragma unroll
    for (int j = 0; j < 4; ++j) {
        h[j] = f2h(fv[j]);
        lo[j] = f2h(fv[j] - h2f(h[j]));
    }
    unsigned short* op = out + (long)m * (2 * K) + k;
    *reinterpret_cast<ushort4*>(op)     = make_ushort4(h[0], h[1], h[2], h[3]);
    *reinterpret_cast<ushort4*>(op + K) = make_ushort4(lo[0], lo[1], lo[2], lo[3]);
}

// ---------------- fp32 K x N -> f16 N x 2K transpose (weights, B-side [hi|hi]) --
__global__ __launch_bounds__(256)
void split2_tr_k(const float* __restrict__ in, unsigned short* __restrict__ out,
                 int K, int N, long szIn, long szOut)
{
    __shared__ float tile[32][33];
    int z = blockIdx.z;
    in  += (long)z * szIn;
    out += (long)z * szOut;
    int k0 = blockIdx.x * 32, n0 = blockIdx.y * 32;
    int t = threadIdx.x;
    int r = t >> 3, c4 = (t & 7) * 4;
    float4 v = *reinterpret_cast<const float4*>(&in[(long)(k0 + r) * N + n0 + c4]);
    tile[r][c4] = v.x; tile[r][c4 + 1] = v.y; tile[r][c4 + 2] = v.z; tile[r][c4 + 3] = v.w;
    __syncthreads();
    int nr = t >> 3, kq = (t & 7) * 4;
    unsigned short h[4];
#pragma unroll
    for (int j = 0; j < 4; ++j) h[j] = f2h(tile[kq + j][nr]);
    unsigned short* op = out + (long)(n0 + nr) * (2 * K) + k0 + kq;
    ushort4 hv = make_ushort4(h[0], h[1], h[2], h[3]);
    *reinterpret_cast<ushort4*>(op)     = hv;
    *reinterpret_cast<ushort4*>(op + K) = hv;
}

// ---------------- fp32 K x N -> f16 N x K transpose with scale (V matrix) -------
__global__ __launch_bounds__(256)
void tr_f16_k(const float* __restrict__ in, unsigned short* __restrict__ out,
              int K, int N, float scl)
{
    __shared__ float tile[32][33];
    int k0 = blockIdx.x * 32, n0 = blockIdx.y * 32;
    int t = threadIdx.x;
    int r = t >> 3, c4 = (t & 7) * 4;
    float4 v = *reinterpret_cast<const float4*>(&in[(long)(k0 + r) * N + n0 + c4]);
    tile[r][c4] = v.x; tile[r][c4 + 1] = v.y; tile[r][c4 + 2] = v.z; tile[r][c4 + 3] = v.w;
    __syncthreads();
    int nr = t >> 3, kq = (t & 7) * 4;
    unsigned short h[4];
#pragma unroll
    for (int j = 0; j < 4; ++j) h[j] = f2h(tile[kq + j][nr] * scl);
    *reinterpret_cast<ushort4*>(&out[(long)(n0 + nr) * K + k0 + kq]) =
        make_ushort4(h[0], h[1], h[2], h[3]);
}

// ---------------- f16 MFMA GEMM, split-K partial writer ----------------
// A: M x K row-major (2-seg f16 [hi|lo]), B: N x K row-major ([hi|hi]).
// 64x128 tile, 4 waves of 32x64 each.
__global__ __launch_bounds__(256, 4)
void bgemm_k(const unsigned short* __restrict__ A,
             const unsigned short* __restrict__ B0, const unsigned short* __restrict__ B1,
             const unsigned short* __restrict__ B2,
             int M, int N, int K, int lda, int ldb,
             long sA, int splitk,
             float* __restrict__ Cpart)
{
    constexpr int BKp = 40;
    int tid = threadIdx.x;
    int bz = blockIdx.z;
    int z  = bz / splitk;
    int ks = bz - z * splitk;

    const unsigned short* Ap = A + (long)z * sA + (long)ks * K;
    const unsigned short* Bp = ((z == 1) ? B1 : (z == 2) ? B2 : B0) + (long)ks * K;

    __shared__ unsigned short As[64 * BKp];
    __shared__ unsigned short Bs[128 * BKp];

    int bm = blockIdx.x * 64;
    int bn = blockIdx.y * 128;
    int w = tid >> 6, lane = tid & 63, quad = lane >> 4, l16 = lane & 15;
    int wm = (w >> 1) * 32;
    int wn = (w & 1) * 64;

    int ar = tid >> 2, ac = (tid & 3) * 8;      // A: 64 rows, 4 thr/row
    int br = tid >> 1, bc = (tid & 1) * 16;     // B: 128 rows, 2 thr/row

    f32x4_t acc[2][4] = {};
    bhalf8_t aS0, bS0, bS1;

    auto ldgA = [&](int k0) {
        aS0 = *reinterpret_cast<const bhalf8_t*>(Ap + (long)(bm + ar) * lda + k0 + ac);
    };
    auto ldgB = [&](int k0) {
        const unsigned short* p = Bp + (long)(bn + br) * ldb + k0 + bc;
        bS0 = *reinterpret_cast<const bhalf8_t*>(p);
        bS1 = *reinterpret_cast<const bhalf8_t*>(p + 8);
    };

    ldgA(0); ldgB(0);

    for (int k0 = 0; k0 < K; k0 += 32) {
        *reinterpret_cast<bhalf8_t*>(&As[ar * BKp + ac])     = aS0;
        *reinterpret_cast<bhalf8_t*>(&Bs[br * BKp + bc])     = bS0;
        *reinterpret_cast<bhalf8_t*>(&Bs[br * BKp + bc + 8]) = bS1;
        __syncthreads();
        if (k0 + 32 < K) { ldgA(k0 + 32); ldgB(k0 + 32); }
        bhalf8_t af[2], bf[4];
#pragma unroll
        for (int i = 0; i < 2; ++i)
            af[i] = *reinterpret_cast<const bhalf8_t*>(&As[(wm + i * 16 + l16) * BKp + quad * 8]);
#pragma unroll
        for (int j = 0; j < 4; ++j)
            bf[j] = *reinterpret_cast<const bhalf8_t*>(&Bs[(wn + j * 16 + l16) * BKp + quad * 8]);
#pragma unroll
        for (int i = 0; i < 2; ++i)
#pragma unroll
            for (int j = 0; j < 4; ++j)
                acc[i][j] = __builtin_amdgcn_mfma_f32_16x16x32_f16(
                    __builtin_bit_cast(half8_t, af[i]), __builtin_bit_cast(half8_t, bf[j]),
                    acc[i][j], 0, 0, 0);
        __syncthreads();
    }

    float* Cp = Cpart + (long)bz * M * N;
#pragma unroll
    for (int i = 0; i < 2; ++i)
#pragma unroll
        for (int j = 0; j < 4; ++j)
#pragma unroll
            for (int r = 0; r < 4; ++r) {
                int m = bm + wm + i * 16 + quad * 4 + r;
                int n = bn + wn + j * 16 + l16;
                Cp[(long)m * N + n] = acc[i][j][r];
            }
}

// ---------------- flash partial: one wave = (16 Q-rows, 128 keys, 1 head) --------
// Q/K: per-head 1024 x 128 f16 2-seg (Q [hi|lo], K [hi|hi]).
__global__ __launch_bounds__(64)
void flash_part_k(const unsigned short* __restrict__ qb2, const unsigned short* __restrict__ kb2,
                  const unsigned short* __restrict__ vtb, const unsigned short* __restrict__ bmap,
                  float* __restrict__ po, float* __restrict__ pm, float* __restrict__ pl)
{
    __shared__ unsigned short Ps[16 * 136];

    int tid = threadIdx.x;          // 0..63
    int qb = blockIdx.x;            // 64 Q-blocks of 16 rows
    int h  = blockIdx.y;            // 8 heads
    int z  = blockIdx.z;            // 8 key-slices of 128
    int bm = qb * 16;
    int k0 = z * 128;

    const unsigned short* Qh = qb2 + (long)h * 131072;
    const unsigned short* Kh = kb2 + (long)h * 131072;
    const unsigned short* Vh = vtb + (long)h * 65536;
    const unsigned short* Bm = bmap + (long)h * 1048576;

    int quad = tid >> 4, l16 = tid & 15;

    bhalf8_t aq[4];
#pragma unroll
    for (int kq = 0; kq < 4; ++kq)
        aq[kq] = *reinterpret_cast<const bhalf8_t*>(
            &Qh[(long)(bm + l16) * 128 + kq * 32 + quad * 8]);

    f32x4_t sacc[8] = {};
#pragma unroll
    for (int kq = 0; kq < 4; ++kq) {
        bhalf8_t bk[8];
#pragma unroll
        for (int nb = 0; nb < 8; ++nb)
            bk[nb] = *reinterpret_cast<const bhalf8_t*>(
                &Kh[(long)(k0 + nb * 16 + l16) * 128 + kq * 32 + quad * 8]);
#pragma unroll
        for (int nb = 0; nb < 8; ++nb)
            sacc[nb] = __builtin_amdgcn_mfma_f32_16x16x32_f16(
                __builtin_bit_cast(half8_t, aq[kq]), __builtin_bit_cast(half8_t, bk[nb]),
                sacc[nb], 0, 0, 0);
    }

    float m_r[4] = {-3.0e38f, -3.0e38f, -3.0e38f, -3.0e38f};
#pragma unroll
    for (int nb = 0; nb < 8; ++nb)
#pragma unroll
        for (int r = 0; r < 4; ++r) {
            int gm = bm + quad * 4 + r;
            int gn = k0 + nb * 16 + l16;
            float bias = h2f(Bm[(long)gm * kS + gn]);
            float s = fmaf(sacc[nb][r], 0.125f, bias);
            sacc[nb][r] = s;
            m_r[r] = fmaxf(m_r[r], s);
        }
#pragma unroll
    for (int r = 0; r < 4; ++r) {
        float m_ = m_r[r];
#pragma unroll
        for (int off = 1; off < 16; off <<= 1) m_ = fmaxf(m_, __shfl_xor(m_, off, 64));
        m_r[r] = m_;
    }

    float l_r[4];
#pragma unroll
    for (int r = 0; r < 4; ++r) {
        int row = quad * 4 + r;
        float mN = m_r[r];
        float s_ = 0.f;
#pragma unroll
        for (int nb = 0; nb < 8; ++nb) {
            float p = __expf(sacc[nb][r] - mN);
            Ps[row * 136 + nb * 16 + l16] = f2h(p * 16384.f);
            s_ += p;
        }
#pragma unroll
        for (int off = 1; off < 16; off <<= 1) s_ += __shfl_xor(s_, off, 64);
        l_r[r] = s_;
    }

    long sbase = (((long)z * 8 + h) * 64 + qb) * 16;   // per-z stride 8192
    if (l16 == 0) {
#pragma unroll
        for (int r = 0; r < 4; ++r) {
            pm[sbase + quad * 4 + r] = m_r[r];
            pl[sbase + quad * 4 + r] = l_r[r];
        }
    }
    __syncthreads();

    f32x4_t oacc[4] = {};
#pragma unroll
    for (int kq2 = 0; kq2 < 4; ++kq2) {
        bhalf8_t ap = *reinterpret_cast<const bhalf8_t*>(&Ps[l16 * 136 + kq2 * 32 + quad * 8]);
#pragma unroll
        for (int j2 = 0; j2 < 4; ++j2) {
            bhalf8_t bv = *reinterpret_cast<const bhalf8_t*>(
                &Vh[(long)(j2 * 16 + l16) * 1024 + k0 + kq2 * 32 + quad * 8]);
            oacc[j2] = __builtin_amdgcn_mfma_f32_16x16x32_f16(
                __builtin_bit_cast(half8_t, ap), __builtin_bit_cast(half8_t, bv),
                oacc[j2], 0, 0, 0);
        }
    }

    float* pob = po + sbase * 64;
#pragma unroll
    for (int j2 = 0; j2 < 4; ++j2)
#pragma unroll
        for (int r = 0; r < 4; ++r)
            pob[(quad * 4 + r) * 64 + j2 * 16 + l16] = oacc[j2][r];
}

// ---------------- flash merge: combine 8 key-slice partials, write aob 2-seg ----
__global__ __launch_bounds__(256)
void flash_merge_k(const float* __restrict__ po, const float* __restrict__ pm,
                   const float* __restrict__ pl, unsigned short* __restrict__ aob)
{
    int t = blockIdx.x * 256 + threadIdx.x;   // 65536 = 8h * 64qb * 16row * 8chunks
    int c8  = t & 7;
    int row = (t >> 3) & 15;
    int qb  = (t >> 7) & 63;
    int h   = t >> 13;
    long sidx = (((long)h * 64) + qb) * 16 + row;   // per-z stride 8192

    float m[8];
    float M = -3.0e38f;
#pragma unroll
    for (int z = 0; z < 8; ++z) { m[z] = pm[z * 8192 + sidx]; M = fmaxf(M, m[z]); }
    float w[8], lt = 0.f;
#pragma unroll
    for (int z = 0; z < 8; ++z) {
        w[z] = __expf(m[z] - M);
        lt = fmaf(pl[z * 8192 + sidx], w[z], lt);
    }
    float acc[8] = {};
#pragma unroll
    for (int z = 0; z < 8; ++z) {
        const float* p = po + (z * 8192 + sidx) * 64 + c8 * 8;
        float4 a = *reinterpret_cast<const float4*>(p);
        float4 b = *reinterpret_cast<const float4*>(p + 4);
        acc[0] = fmaf(a.x, w[z], acc[0]); acc[1] = fmaf(a.y, w[z], acc[1]);
        acc[2] = fmaf(a.z, w[z], acc[2]); acc[3] = fmaf(a.w, w[z], acc[3]);
        acc[4] = fmaf(b.x, w[z], acc[4]); acc[5] = fmaf(b.y, w[z], acc[5]);
        acc[6] = fmaf(b.z, w[z], acc[6]); acc[7] = fmaf(b.w, w[z], acc[7]);
    }
    float inv = 1.f / (16777216.f * lt);
    unsigned short hi[8], lo[8];
#pragma unroll
    for (int j = 0; j < 8; ++j) {
        float val = acc[j] * inv;
        hi[j] = f2h(val);
        lo[j] = f2h(val - h2f(hi[j]));
    }
    long base = ((long)qb * 16 + row) * 1024 + h * 64 + c8 * 8;
    *reinterpret_cast<ushort4*>(&aob[base])       = make_ushort4(hi[0], hi[1], hi[2], hi[3]);
    *reinterpret_cast<ushort4*>(&aob[base + 4])   = make_ushort4(hi[4], hi[5], hi[6], hi[7]);
    *reinterpret_cast<ushort4*>(&aob[base + 512]) = make_ushort4(lo[0], lo[1], lo[2], lo[3]);
    *reinterpret_cast<ushort4*>(&aob[base + 516]) = make_ushort4(lo[4], lo[5], lo[6], lo[7]);
}

// ---------------- QKV split-K reduce: bias + 2-seg f16 to qb2/kb2, v f32 --------
__global__ __launch_bounds__(256)
void reduce_qkv_k(const float* __restrict__ part,
                  unsigned short* __restrict__ qb2, unsigned short* __restrict__ kb2,
                  float* __restrict__ v,
                  const float* __restrict__ qbias, const float* __restrict__ kbias,
                  const float* __restrict__ vbias, int splitk)
{
    int z = blockIdx.y;
    const long MN = (long)kS * kD;
    long idx = ((long)blockIdx.x * 256 + threadIdx.x) * 4;
    const float* pz = part + (long)z * splitk * MN + idx;
    float4 s = *reinterpret_cast<const float4*>(pz);
    for (int t = 1; t < splitk; ++t) {
        float4 vv = *reinterpret_cast<const float4*>(pz + (long)t * MN);
        s.x += vv.x; s.y += vv.y; s.z += vv.z; s.w += vv.w;
    }
    int m = (int)(idx >> 9), n = (int)(idx & 511);
    const float* bzp = (z == 1) ? kbias : (z == 2) ? vbias : qbias;
    s.x += bzp[n]; s.y += bzp[n + 1]; s.z += bzp[n + 2]; s.w += bzp[n + 3];
    if (z == 2) {
        *reinterpret_cast<float4*>(v + idx) = s;
        return;
    }
    float fv[4] = {s.x, s.y, s.z, s.w};
    unsigned short h[4], lo[4];
#pragma unroll
    for (int j = 0; j < 4; ++j) {
        h[j] = f2h(fv[j]);
        lo[j] = f2h(fv[j] - h2f(h[j]));
    }
    int head = n >> 6, hc = n & 63;
    unsigned short* dst = ((z == 1) ? kb2 : qb2) + (long)head * 131072 + (long)m * 128 + hc;
    ushort4 hv = make_ushort4(h[0], h[1], h[2], h[3]);
    *reinterpret_cast<ushort4*>(dst) = hv;
    if (z == 0) {  // Q: A-side [hi|lo]
        *reinterpret_cast<ushort4*>(dst + 64) = make_ushort4(lo[0], lo[1], lo[2], lo[3]);
    } else {       // K: B-side [hi|hi]
        *reinterpret_cast<ushort4*>(dst + 64) = hv;
    }
}

// ---------------- FFN1 reduce: bias + relu + 2-seg f16 to hb ----------------
__global__ __launch_bounds__(256)
void reduce3_k(const float* __restrict__ part, unsigned short* __restrict__ hb,
               const float* __restrict__ bias, int splitk)
{
    const long MN = (long)kS * kDFF;
    long idx = ((long)blockIdx.x * 256 + threadIdx.x) * 4;
    const float* pz = part + idx;
    float4 s = *reinterpret_cast<const float4*>(pz);
    for (int t = 1; t < splitk; ++t) {
        float4 v = *reinterpret_cast<const float4*>(pz + (long)t * MN);
        s.x += v.x; s.y += v.y; s.z += v.z; s.w += v.w;
    }
    int m = (int)(idx >> 11), n = (int)(idx & 2047);
    float fv[4] = {fmaxf(s.x + bias[n], 0.f), fmaxf(s.y + bias[n + 1], 0.f),
                   fmaxf(s.z + bias[n + 2], 0.f), fmaxf(s.w + bias[n + 3], 0.f)};
    unsigned short h[4], lo[4];
#pragma unroll
    for (int j = 0; j < 4; ++j) {
        h[j] = f2h(fv[j]);
        lo[j] = f2h(fv[j] - h2f(h[j]));
    }
    unsigned short* dst = hb + (long)m * 4096 + n;
    *reinterpret_cast<ushort4*>(dst)        = make_ushort4(h[0], h[1], h[2], h[3]);
    *reinterpret_cast<ushort4*>(dst + 2048) = make_ushort4(lo[0], lo[1], lo[2], lo[3]);
}

// ---------------- fused: split-K reduce + bias + residual + LN + 2-seg xb --------
__global__ __launch_bounds__(256)
void add_ln_fused_k(const float* __restrict__ part, float* __restrict__ x,
                    const float* __restrict__ bias,
                    const float* __restrict__ g, const float* __restrict__ b,
                    unsigned short* __restrict__ xb, int splitk)
{
    __shared__ float sm[4];
    int row = blockIdx.x, t = threadIdx.x;
    const long MN = (long)kS * kD;
    float* xr = x + (long)row * kD;
    float s0 = 0.f, s1 = 0.f;
    const float* pr = part + (long)row * kD;
    for (int sl = 0; sl < splitk; ++sl) {
        s0 += pr[(long)sl * MN + t];
        s1 += pr[(long)sl * MN + t + 256];
    }
    s0 += bias[t] + xr[t];
    s1 += bias[t + 256] + xr[t + 256];
    float sum = wave_sum(s0 + s1);
    if ((t & 63) == 0) sm[t >> 6] = sum;
    __syncthreads();
    sum = sm[0] + sm[1] + sm[2] + sm[3];
    float mu = sum * (1.f / kD);
    float d0 = s0 - mu, d1 = s1 - mu;
    __syncthreads();
    float vs = wave_sum(d0 * d0 + d1 * d1);
    if ((t & 63) == 0) sm[t >> 6] = vs;
    __syncthreads();
    vs = sm[0] + sm[1] + sm[2] + sm[3];
    float rs = rsqrtf(vs * (1.f / kD) + 1e-5f);
    float o0 = fmaf(d0 * rs, g[t], b[t]);
    float o1 = fmaf(d1 * rs, g[t + 256], b[t + 256]);
    xr[t]       = o0;
    xr[t + 256] = o1;
    unsigned short h0 = f2h(o0), l0 = f2h(o0 - h2f(h0));
    unsigned short h1 = f2h(o1), l1 = f2h(o1 - h2f(h1));
    unsigned short* xrow = xb + (long)row * 1024;
    xrow[t]       = h0;  xrow[t + 256] = h1;
    xrow[t + 512] = l0;  xrow[t + 768] = l1;
}

// ---------------- mean-pool partials ----------------
__global__ __launch_bounds__(256)
void pool_k(const float* __restrict__ x, float* __restrict__ partial)
{
    int col = blockIdx.x * 256 + threadIdx.x;
    int rb = blockIdx.y;
    float s = 0.f;
    for (int r = rb * 128; r < rb * 128 + 128; ++r) s += x[(long)r * kD + col];
    partial[rb * kD + col] = s;
}

// ---------------- classifier head ----------------
__global__ __launch_bounds__(256)
void head_k(const float* __restrict__ partial,
            const float* __restrict__ c1w, const float* __restrict__ c1b,
            const float* __restrict__ c2w, const float* __restrict__ c2b,
            float* __restrict__ out)
{
    __shared__ float pooled[kD];
    __shared__ float h1[256];
    int t = threadIdx.x;
    for (int d = t; d < kD; d += 256) {
        float s = 0.f;
        for (int r = 0; r < 8; ++r) s += partial[r * kD + d];
        pooled[d] = s * (1.0f / kS);
    }
    __syncthreads();
    float acc = c1b[t];
    for (int f = 0; f < kD; ++f) acc = fmaf(pooled[f], c1w[f * 256 + t], acc);
    h1[t] = fmaxf(acc, 0.f);
    __syncthreads();
    if (t < 10) {
        float o = c2b[t];
        for (int f = 0; f < 256; ++f) o = fmaf(h1[f], c2w[f * 10 + t], o);
        out[t] = o;
    }
}

// ---------------- launch ----------------
extern "C" void kernel_launch(void* const* d_in, const int* in_sizes, int n_in,
                              void* d_out, int out_size, void* d_ws, size_t ws_size,
                              hipStream_t stream)
{
    (void)in_sizes; (void)n_in; (void)out_size; (void)ws_size;
    const float* features = (const float*)d_in[0];
    const float* positions= (const float*)d_in[1];
    const float* fb       = (const float*)d_in[2];
    const float* in_w     = (const float*)d_in[3];
    const float* in_b     = (const float*)d_in[4];
    const float* qw  = (const float*)d_in[5];
    const float* qb  = (const float*)d_in[6];
    const float* kw  = (const float*)d_in[7];
    const float* kb  = (const float*)d_in[8];
    const float* vw  = (const float*)d_in[9];
    const float* vb  = (const float*)d_in[10];
    const float* ow  = (const float*)d_in[11];
    const float* ob  = (const float*)d_in[12];
    const float* db1w= (const float*)d_in[13];
    const float* db1b= (const float*)d_in[14];
    const float* db2w= (const float*)d_in[15];
    const float* db2b= (const float*)d_in[16];
    const float* n1g = (const float*)d_in[17];
    const float* n1b = (const float*)d_in[18];
    const float* n2g = (const float*)d_in[19];
    const float* n2b = (const float*)d_in[20];
    const float* f1w = (const float*)d_in[21];
    const float* f1b = (const float*)d_in[22];
    const float* f2w = (const float*)d_in[23];
    const float* f2b = (const float*)d_in[24];
    const float* c1w = (const float*)d_in[25];
    const float* c1b = (const float*)d_in[26];
    const float* c2w = (const float*)d_in[27];
    const float* c2b = (const float*)d_in[28];

    float* ws = (float*)d_ws;
    const long SD = (long)kS * kD;            // 524288
    float* x      = ws;
    float* v      = ws + 1 * SD;
    float* dist   = ws + 3 * SD;              // 2*SD
    float* part   = ws + 5 * SD;              // 12*SD scratch
    float* bpw    = ws + 17 * SD;
    float* Atab   = bpw + 256;
    float* Btab   = Atab + 2080;
    float* partial= Btab + 2080;

    // flash partial overlays inside `part`
    float* po = part;                          // 4,194,304 floats
    float* pmv = part + 4194304;               // 65536
    float* plv = pmv + 65536;                  // 65536

    unsigned short* ub = (unsigned short*)(ws + 17 * SD + 8512);
    unsigned short* xb   = ub;                       // 1024*1024
    unsigned short* aob  = xb   + 1048576;           // 1024*1024
    unsigned short* qb2  = aob  + 1048576;           // 8*1024*128
    unsigned short* kb2  = qb2  + 1048576;
    unsigned short* vtb  = kb2  + 1048576;           // 512*1024 (f16)
    unsigned short* hb   = vtb  + 524288;            // 1024*4096
    unsigned short* qwb  = hb   + 4194304;           // 2 x 512*1024
    unsigned short* kwb  = qwb  + 1048576;
    unsigned short* vwb  = kwb  + 1048576;
    unsigned short* owb  = vwb  + 1048576;
    unsigned short* f1wb = owb  + 1048576;           // 2 x 2048*1024
    unsigned short* f2wb = f1wb + 4194304;           // 2 x 512*4096
    unsigned short* bmap = f2wb + 4194304;           // 8*1024*1024 f16

    input_pe_k<<<kS, 256, 0, stream>>>(features, positions, fb, in_w, in_b, x);
    dist_k<<<kS, 256, 0, stream>>>(positions, dist);
    pwl_sort_k<<<2, 128, 0, stream>>>(db1w, db1b, bpw);
    pwl_tab_k<<<dim3(129, 2), 256, 0, stream>>>(db1w, db1b, db2w, db2b, bpw, Atab, Btab);
    split2_rm_k<<<512, 256, 0, stream>>>(x, xb, 524288, 9, 512);

    split2_tr_k<<<dim3(16, 16, 2), 256, 0, stream>>>(qw, qwb, 512, 512, 262144, 524288);
    split2_tr_k<<<dim3(16, 16, 2), 256, 0, stream>>>(kw, kwb, 512, 512, 262144, 524288);
    split2_tr_k<<<dim3(16, 16, 2), 256, 0, stream>>>(vw, vwb, 512, 512, 262144, 524288);
    split2_tr_k<<<dim3(16, 16, 2), 256, 0, stream>>>(ow, owb, 512, 512, 262144, 524288);
    split2_tr_k<<<dim3(16, 64, 2), 256, 0, stream>>>(f1w, f1wb, 512, 2048, 1048576, 2097152);
    split2_tr_k<<<dim3(64, 16, 2), 256, 0, stream>>>(f2w, f2wb, 2048, 512, 1048576, 2097152);

    for (int l = 0; l < 2; ++l) {
        biasmap_k<<<1024, 256, 0, stream>>>(
            dist, bpw + l * 128, Atab + l * 1040, Btab + l * 1040, bmap);

        // QKV: A=xb (1024x1024), split-K x2 (384 blocks)
        bgemm_k<<<dim3(16, 4, 6), 256, 0, stream>>>(
            xb, qwb + l * 524288, kwb + l * 524288, vwb + l * 524288,
            1024, 512, 512, 1024, 1024, 0, 2, part);
        reduce_qkv_k<<<dim3(512, 3), 256, 0, stream>>>(
            part, qb2, kb2, v, qb + l * kD, kb + l * kD, vb + l * kD, 2);
        tr_f16_k<<<dim3(32, 16), 256, 0, stream>>>(v, vtb, 1024, 512, 1024.f);

        // fused attention
        flash_part_k<<<dim3(64, 8, 8), 64, 0, stream>>>(
            qb2, kb2, vtb, bmap, po, pmv, plv);
        flash_merge_k<<<256, 256, 0, stream>>>(po, pmv, plv, aob);

        // O-proj: split-K x4 (256 blocks); reduce fused into add_ln
        bgemm_k<<<dim3(16, 4, 4), 256, 0, stream>>>(
            aob, owb + l * 524288, owb + l * 524288, owb + l * 524288,
            1024, 512, 256, 1024, 1024, 0, 4, part);
        add_ln_fused_k<<<kS, 256, 0, stream>>>(
            part, x, ob + l * kD, n1g + l * kD, n1b + l * kD, xb, 4);

        // FFN1: split-K x2 (512 blocks), reduce fuses bias+relu+2-seg -> hb
        bgemm_k<<<dim3(16, 16, 2), 256, 0, stream>>>(
            xb, f1wb + l * 2097152, f1wb + l * 2097152, f1wb + l * 2097152,
            1024, 2048, 512, 1024, 1024, 0, 2, part);
        reduce3_k<<<2048, 256, 0, stream>>>(part, hb, f1b + l * kDFF, 2);

        // FFN2: split-K x4 (256 blocks); reduce fused into add_ln
        bgemm_k<<<dim3(16, 4, 4), 256, 0, stream>>>(
            hb, f2wb + l * 2097152, f2wb + l * 2097152, f2wb + l * 2097152,
            1024, 512, 1024, 4096, 4096, 0, 4, part);
        add_ln_fused_k<<<kS, 256, 0, stream>>>(
            part, x, f2b + l * kD, n2g + l * kD, n2b + l * kD, xb, 4);
    }

    pool_k<<<dim3(2, 8), 256, 0, stream>>>(x, partial);
    head_k<<<1, 256, 0, stream>>>(partial, c1w, c1b, c2w, c2b, (float*)d_out);
}

// Round 14
// 388.141 us; speedup vs baseline: 1.6057x; 1.0627x over previous
//
#include <hip/hip_runtime.h>

namespace {
constexpr int kS   = 1024;
constexpr int kD   = 512;
constexpr int kH   = 8;
constexpr int kDFF = 2048;
constexpr int kNF  = 85;   // D//6
}

typedef __attribute__((ext_vector_type(8))) short bhalf8_t;    // 8x16-bit in 4 VGPRs
typedef _Float16 half8_t __attribute__((ext_vector_type(8)));
typedef __attribute__((ext_vector_type(4))) float f32x4_t;

// ---------------- helpers ----------------
__device__ __forceinline__ float wave_sum(float v) {
#pragma unroll
    for (int o = 1; o < 64; o <<= 1) v += __shfl_xor(v, o, 64);
    return v;
}
__device__ __forceinline__ unsigned short f2h(float f) {    // RNE fp32->fp16
    _Float16 h = (_Float16)f;
    return __builtin_bit_cast(unsigned short, h);
}
__device__ __forceinline__ float h2f(unsigned short u) {
    return (float)__builtin_bit_cast(_Float16, u);
}

// ---------------- input projection + positional encoding ----------------
__global__ __launch_bounds__(256)
void input_pe_k(const float* __restrict__ feat, const float* __restrict__ pos,
                const float* __restrict__ fb, const float* __restrict__ in_w,
                const float* __restrict__ in_b, float* __restrict__ x)
{
    int s = blockIdx.x;
    int t = threadIdx.x;
    __shared__ float f[64];
    if (t < 64) f[t] = feat[s * 64 + t];
    __syncthreads();
    float acc0 = in_b[t], acc1 = in_b[t + 256];
#pragma unroll 8
    for (int c = 0; c < 64; ++c) {
        float fv = f[c];
        acc0 = fmaf(fv, in_w[c * kD + t], acc0);
        acc1 = fmaf(fv, in_w[c * kD + 256 + t], acc1);
    }
    float pe0 = 0.f, pe1 = 0.f;
    {
        int d = t;
        if (d < 6 * kNF) {
            int seg = d / kNF, idx = d - seg * kNF;
            float cs = pos[s * 3 + (seg >> 1)] * fb[idx];
            pe0 = (seg & 1) ? cosf(cs) : sinf(cs);
        }
        d = t + 256;
        if (d < 6 * kNF) {
            int seg = d / kNF, idx = d - seg * kNF;
            float cs = pos[s * 3 + (seg >> 1)] * fb[idx];
            pe1 = (seg & 1) ? cosf(cs) : sinf(cs);
        }
    }
    x[s * kD + t]       = acc0 + pe0;
    x[s * kD + 256 + t] = acc1 + pe1;
}

// ---------------- pairwise distance matrix ----------------
__global__ __launch_bounds__(256)
void dist_k(const float* __restrict__ pos, float* __restrict__ dist)
{
    int i = blockIdx.x;
    float px = pos[i * 3], py = pos[i * 3 + 1], pz = pos[i * 3 + 2];
    for (int j = threadIdx.x; j < kS; j += 256) {
        float dx = px - pos[j * 3], dy = py - pos[j * 3 + 1], dz = pz - pos[j * 3 + 2];
        float sq = dx * dx + dy * dy + dz * dz;
        dist[(long)i * kS + j] = sq > 0.f ? sqrtf(sq) : 0.f;
    }
}

// ---------------- PWL: sort breakpoints only (tiny) ----------------
__global__ __launch_bounds__(128)
void pwl_sort_k(const float* __restrict__ a_, const float* __restrict__ b_,
                float* __restrict__ bp_out)
{
    int l = blockIdx.x;
    a_ += l * 128; b_ += l * 128; bp_out += l * 128;
    __shared__ float key[128];
    int t = threadIdx.x;
    float a = a_[t], b = b_[t];
    key[t] = (a != 0.f) ? (-b / a) : 3.0e38f;
    __syncthreads();
    for (int ksz = 2; ksz <= 128; ksz <<= 1) {
        for (int j = ksz >> 1; j > 0; j >>= 1) {
            int ixj = t ^ j;
            if (ixj > t) {
                bool up = ((t & ksz) == 0);
                float x0 = key[t], x1 = key[ixj];
                if ((x0 > x1) == up) { key[t] = x1; key[ixj] = x0; }
            }
            __syncthreads();
        }
    }
    bp_out[t] = key[t];
}

// ---------------- PWL: per-segment table build ----------------
__global__ __launch_bounds__(256)
void pwl_tab_k(const float* __restrict__ a_, const float* __restrict__ b_,
               const float* __restrict__ w2, const float* __restrict__ b2,
               const float* __restrict__ bp, float* __restrict__ Atab,
               float* __restrict__ Btab)
{
    int l = blockIdx.y;
    int seg = blockIdx.x;   // 0..128
    a_ += l * 128; b_ += l * 128; w2 += l * 1024; b2 += l * 8;
    bp += l * 128; Atab += l * 1040; Btab += l * 1040;

    float m;
    if (seg == 0)        m = bp[0] - 1.0f;
    else if (seg == 128) m = bp[127] + 1.0f;
    else                 m = 0.5f * (bp[seg - 1] + bp[seg]);

    int t = threadIdx.x;
    int h = t & 7, cg = t >> 3;   // cg 0..31
    float A = 0.f, B = 0.f;
#pragma unroll
    for (int j = 0; j < 4; ++j) {
        int c = cg * 4 + j;
        float a = a_[c], b = b_[c];
        if (fmaf(a, m, b) > 0.f) {
            float w = w2[c * 8 + h];
            A = fmaf(a, w, A);
            B = fmaf(b, w, B);
        }
    }
#pragma unroll
    for (int off = 8; off < 64; off <<= 1) {
        A += __shfl_xor(A, off, 64);
        B += __shfl_xor(B, off, 64);
    }
    __shared__ float sA[4][8], sB[4][8];
    int w = t >> 6, lane = t & 63;
    if (lane < 8) { sA[w][lane] = A; sB[w][lane] = B; }
    __syncthreads();
    if (t < 8) {
        float At = sA[0][t] + sA[1][t] + sA[2][t] + sA[3][t];
        float Bt = sB[0][t] + sB[1][t] + sB[2][t] + sB[3][t];
        Atab[seg * 8 + t] = At;
        Btab[seg * 8 + t] = Bt + b2[t];
    }
}

// ---------------- per-layer bias map: one search -> all 8 heads ----------------
__global__ __launch_bounds__(256)
void biasmap_k(const float* __restrict__ dist, const float* __restrict__ bp,
               const float* __restrict__ Atab, const float* __restrict__ Btab,
               unsigned short* __restrict__ bmap)
{
    __shared__ float bps[128], Ah[1032], Bh[1032];
    int t = threadIdx.x;
    if (t < 128) bps[t] = bp[t];
    for (int i = t; i < 1032; i += 256) { Ah[i] = Atab[i]; Bh[i] = Btab[i]; }
    __syncthreads();
    long i = ((long)blockIdx.x * 256 + t) * 4;
    float4 d4 = *reinterpret_cast<const float4*>(dist + i);
    float dv[4] = {d4.x, d4.y, d4.z, d4.w};
    int seg[4];
#pragma unroll
    for (int j = 0; j < 4; ++j) {
        float tv = dv[j];
        int lo = 0, hi = 128;
        while (lo < hi) { int mid = (lo + hi) >> 1; if (bps[mid] < tv) lo = mid + 1; else hi = mid; }
        seg[j] = lo;
    }
#pragma unroll
    for (int h = 0; h < 8; ++h) {
        unsigned short o[4];
#pragma unroll
        for (int j = 0; j < 4; ++j)
            o[j] = f2h(fmaf(Ah[seg[j] * 8 + h], dv[j], Bh[seg[j] * 8 + h]));
        *reinterpret_cast<ushort4*>(bmap + (long)h * 1048576 + i) =
            make_ushort4(o[0], o[1], o[2], o[3]);
    }
}

// ---------------- fp32 -> f16 plain, contiguous ----------------
__global__ __launch_bounds__(256)
void tof16_k(const float* __restrict__ in, unsigned short* __restrict__ out, long total)
{
    long i = ((long)blockIdx.x * 256 + threadIdx.x) * 4;
    if (i >= total) return;
    float4 v = *reinterpret_cast<const float4*>(in + i);
    *reinterpret_cast<ushort4*>(out + i) =
        make_ushort4(f2h(v.x), f2h(v.y), f2h(v.z), f2h(v.w));
}

// ---------------- fp32 K x N -> f16 N x K transpose (weights, layer-batched) ----
__global__ __launch_bounds__(256)
void trw_f16_k(const float* __restrict__ in, unsigned short* __restrict__ out,
               int K, int N, long szIn, long szOut)
{
    __shared__ float tile[32][33];
    int z = blockIdx.z;
    in  += (long)z * szIn;
    out += (long)z * szOut;
    int k0 = blockIdx.x * 32, n0 = blockIdx.y * 32;
    int t = threadIdx.x;
    int r = t >> 3, c4 = (t & 7) * 4;
    float4 v = *reinterpret_cast<const float4*>(&in[(long)(k0 + r) * N + n0 + c4]);
    tile[r][c4] = v.x; tile[r][c4 + 1] = v.y; tile[r][c4 + 2] = v.z; tile[r][c4 + 3] = v.w;
    __syncthreads();
    int nr = t >> 3, kq = (t & 7) * 4;
    unsigned short h[4];
#pragma unroll
    for (int j = 0; j < 4; ++j) h[j] = f2h(tile[kq + j][nr]);
    *reinterpret_cast<ushort4*>(&out[(long)(n0 + nr) * K + k0 + kq]) =
        make_ushort4(h[0], h[1], h[2], h[3]);
}

// ---------------- fp32 K x N -> f16 N x K transpose with scale (V matrix) -------
__global__ __launch_bounds__(256)
void tr_f16_k(const float* __restrict__ in, unsigned short* __restrict__ out,
              int K, int N, float scl)
{
    __shared__ float tile[32][33];
    int k0 = blockIdx.x * 32, n0 = blockIdx.y * 32;
    int t = threadIdx.x;
    int r = t >> 3, c4 = (t & 7) * 4;
    float4 v = *reinterpret_cast<const float4*>(&in[(long)(k0 + r) * N + n0 + c4]);
    tile[r][c4] = v.x; tile[r][c4 + 1] = v.y; tile[r][c4 + 2] = v.z; tile[r][c4 + 3] = v.w;
    __syncthreads();
    int nr = t >> 3, kq = (t & 7) * 4;
    unsigned short h[4];
#pragma unroll
    for (int j = 0; j < 4; ++j) h[j] = f2h(tile[kq + j][nr] * scl);
    *reinterpret_cast<ushort4*>(&out[(long)(n0 + nr) * K + k0 + kq]) =
        make_ushort4(h[0], h[1], h[2], h[3]);
}

// ---------------- f16 MFMA GEMM (single precision pair), split-K partial writer --
// A: M x K f16 row-major, B: N x K f16 row-major. 64x128 tile, 4 waves of 32x64.
__global__ __launch_bounds__(256, 4)
void bgemm_k(const unsigned short* __restrict__ A,
             const unsigned short* __restrict__ B0, const unsigned short* __restrict__ B1,
             const unsigned short* __restrict__ B2,
             int M, int N, int K, int lda, int ldb,
             long sA, int splitk,
             float* __restrict__ Cpart)
{
    constexpr int BKp = 40;
    int tid = threadIdx.x;
    int bz = blockIdx.z;
    int z  = bz / splitk;
    int ks = bz - z * splitk;

    const unsigned short* Ap = A + (long)z * sA + (long)ks * K;
    const unsigned short* Bp = ((z == 1) ? B1 : (z == 2) ? B2 : B0) + (long)ks * K;

    __shared__ unsigned short As[64 * BKp];
    __shared__ unsigned short Bs[128 * BKp];

    int bm = blockIdx.x * 64;
    int bn = blockIdx.y * 128;
    int w = tid >> 6, lane = tid & 63, quad = lane >> 4, l16 = lane & 15;
    int wm = (w >> 1) * 32;
    int wn = (w & 1) * 64;

    int ar = tid >> 2, ac = (tid & 3) * 8;      // A: 64 rows, 4 thr/row
    int br = tid >> 1, bc = (tid & 1) * 16;     // B: 128 rows, 2 thr/row

    f32x4_t acc[2][4] = {};
    bhalf8_t aS0, bS0, bS1;

    auto ldgA = [&](int k0) {
        aS0 = *reinterpret_cast<const bhalf8_t*>(Ap + (long)(bm + ar) * lda + k0 + ac);
    };
    auto ldgB = [&](int k0) {
        const unsigned short* p = Bp + (long)(bn + br) * ldb + k0 + bc;
        bS0 = *reinterpret_cast<const bhalf8_t*>(p);
        bS1 = *reinterpret_cast<const bhalf8_t*>(p + 8);
    };

    ldgA(0); ldgB(0);

    for (int k0 = 0; k0 < K; k0 += 32) {
        *reinterpret_cast<bhalf8_t*>(&As[ar * BKp + ac])     = aS0;
        *reinterpret_cast<bhalf8_t*>(&Bs[br * BKp + bc])     = bS0;
        *reinterpret_cast<bhalf8_t*>(&Bs[br * BKp + bc + 8]) = bS1;
        __syncthreads();
        if (k0 + 32 < K) { ldgA(k0 + 32); ldgB(k0 + 32); }
        bhalf8_t af[2], bf[4];
#pragma unroll
        for (int i = 0; i < 2; ++i)
            af[i] = *reinterpret_cast<const bhalf8_t*>(&As[(wm + i * 16 + l16) * BKp + quad * 8]);
#pragma unroll
        for (int j = 0; j < 4; ++j)
            bf[j] = *reinterpret_cast<const bhalf8_t*>(&Bs[(wn + j * 16 + l16) * BKp + quad * 8]);
#pragma unroll
        for (int i = 0; i < 2; ++i)
#pragma unroll
            for (int j = 0; j < 4; ++j)
                acc[i][j] = __builtin_amdgcn_mfma_f32_16x16x32_f16(
                    __builtin_bit_cast(half8_t, af[i]), __builtin_bit_cast(half8_t, bf[j]),
                    acc[i][j], 0, 0, 0);
        __syncthreads();
    }

    float* Cp = Cpart + (long)bz * M * N;
#pragma unroll
    for (int i = 0; i < 2; ++i)
#pragma unroll
        for (int j = 0; j < 4; ++j)
#pragma unroll
            for (int r = 0; r < 4; ++r) {
                int m = bm + wm + i * 16 + quad * 4 + r;
                int n = bn + wn + j * 16 + l16;
                Cp[(long)m * N + n] = acc[i][j][r];
            }
}

// ---------------- flash partial: one wave = (16 Q-rows, 128 keys, 1 head) --------
// Q/K per-head 1024x128 f16 2-seg (Q [hi|lo], K [hi|hi]) — kept 2-seg for accuracy.
__global__ __launch_bounds__(64)
void flash_part_k(const unsigned short* __restrict__ qb2, const unsigned short* __restrict__ kb2,
                  const unsigned short* __restrict__ vtb, const unsigned short* __restrict__ bmap,
                  float* __restrict__ po, float* __restrict__ pm, float* __restrict__ pl)
{
    __shared__ unsigned short Ps[16 * 136];

    int tid = threadIdx.x;
    int qb = blockIdx.x;            // 64 Q-blocks of 16 rows
    int h  = blockIdx.y;            // 8 heads
    int z  = blockIdx.z;            // 8 key-slices of 128
    int bm = qb * 16;
    int k0 = z * 128;

    const unsigned short* Qh = qb2 + (long)h * 131072;
    const unsigned short* Kh = kb2 + (long)h * 131072;
    const unsigned short* Vh = vtb + (long)h * 65536;
    const unsigned short* Bm = bmap + (long)h * 1048576;

    int quad = tid >> 4, l16 = tid & 15;

    bhalf8_t aq[4];
#pragma unroll
    for (int kq = 0; kq < 4; ++kq)
        aq[kq] = *reinterpret_cast<const bhalf8_t*>(
            &Qh[(long)(bm + l16) * 128 + kq * 32 + quad * 8]);

    f32x4_t sacc[8] = {};
#pragma unroll
    for (int kq = 0; kq < 4; ++kq) {
        bhalf8_t bk[8];
#pragma unroll
        for (int nb = 0; nb < 8; ++nb)
            bk[nb] = *reinterpret_cast<const bhalf8_t*>(
                &Kh[(long)(k0 + nb * 16 + l16) * 128 + kq * 32 + quad * 8]);
#pragma unroll
        for (int nb = 0; nb < 8; ++nb)
            sacc[nb] = __builtin_amdgcn_mfma_f32_16x16x32_f16(
                __builtin_bit_cast(half8_t, aq[kq]), __builtin_bit_cast(half8_t, bk[nb]),
                sacc[nb], 0, 0, 0);
    }

    float m_r[4] = {-3.0e38f, -3.0e38f, -3.0e38f, -3.0e38f};
#pragma unroll
    for (int nb = 0; nb < 8; ++nb)
#pragma unroll
        for (int r = 0; r < 4; ++r) {
            int gm = bm + quad * 4 + r;
            int gn = k0 + nb * 16 + l16;
            float bias = h2f(Bm[(long)gm * kS + gn]);
            float s = fmaf(sacc[nb][r], 0.125f, bias);
            sacc[nb][r] = s;
            m_r[r] = fmaxf(m_r[r], s);
        }
#pragma unroll
    for (int r = 0; r < 4; ++r) {
        float m_ = m_r[r];
#pragma unroll
        for (int off = 1; off < 16; off <<= 1) m_ = fmaxf(m_, __shfl_xor(m_, off, 64));
        m_r[r] = m_;
    }

    float l_r[4];
#pragma unroll
    for (int r = 0; r < 4; ++r) {
        int row = quad * 4 + r;
        float mN = m_r[r];
        float s_ = 0.f;
#pragma unroll
        for (int nb = 0; nb < 8; ++nb) {
            float p = __expf(sacc[nb][r] - mN);
            Ps[row * 136 + nb * 16 + l16] = f2h(p * 16384.f);
            s_ += p;
        }
#pragma unroll
        for (int off = 1; off < 16; off <<= 1) s_ += __shfl_xor(s_, off, 64);
        l_r[r] = s_;
    }

    long sbase = (((long)z * 8 + h) * 64 + qb) * 16;
    if (l16 == 0) {
#pragma unroll
        for (int r = 0; r < 4; ++r) {
            pm[sbase + quad * 4 + r] = m_r[r];
            pl[sbase + quad * 4 + r] = l_r[r];
        }
    }
    __syncthreads();

    f32x4_t oacc[4] = {};
#pragma unroll
    for (int kq2 = 0; kq2 < 4; ++kq2) {
        bhalf8_t ap = *reinterpret_cast<const bhalf8_t*>(&Ps[l16 * 136 + kq2 * 32 + quad * 8]);
#pragma unroll
        for (int j2 = 0; j2 < 4; ++j2) {
            bhalf8_t bv = *reinterpret_cast<const bhalf8_t*>(
                &Vh[(long)(j2 * 16 + l16) * 1024 + k0 + kq2 * 32 + quad * 8]);
            oacc[j2] = __builtin_amdgcn_mfma_f32_16x16x32_f16(
                __builtin_bit_cast(half8_t, ap), __builtin_bit_cast(half8_t, bv),
                oacc[j2], 0, 0, 0);
        }
    }

    float* pob = po + sbase * 64;
#pragma unroll
    for (int j2 = 0; j2 < 4; ++j2)
#pragma unroll
        for (int r = 0; r < 4; ++r)
            pob[(quad * 4 + r) * 64 + j2 * 16 + l16] = oacc[j2][r];
}

// ---------------- flash merge: combine 8 key-slice partials -> aob (f16) ---------
__global__ __launch_bounds__(256)
void flash_merge_k(const float* __restrict__ po, const float* __restrict__ pm,
                   const float* __restrict__ pl, unsigned short* __restrict__ aob)
{
    int t = blockIdx.x * 256 + threadIdx.x;
    int c8  = t & 7;
    int row = (t >> 3) & 15;
    int qb  = (t >> 7) & 63;
    int h   = t >> 13;
    long sidx = (((long)h * 64) + qb) * 16 + row;

    float m[8];
    float M = -3.0e38f;
#pragma unroll
    for (int z = 0; z < 8; ++z) { m[z] = pm[z * 8192 + sidx]; M = fmaxf(M, m[z]); }
    float w[8], lt = 0.f;
#pragma unroll
    for (int z = 0; z < 8; ++z) {
        w[z] = __expf(m[z] - M);
        lt = fmaf(pl[z * 8192 + sidx], w[z], lt);
    }
    float acc[8] = {};
#pragma unroll
    for (int z = 0; z < 8; ++z) {
        const float* p = po + (z * 8192 + sidx) * 64 + c8 * 8;
        float4 a = *reinterpret_cast<const float4*>(p);
        float4 b = *reinterpret_cast<const float4*>(p + 4);
        acc[0] = fmaf(a.x, w[z], acc[0]); acc[1] = fmaf(a.y, w[z], acc[1]);
        acc[2] = fmaf(a.z, w[z], acc[2]); acc[3] = fmaf(a.w, w[z], acc[3]);
        acc[4] = fmaf(b.x, w[z], acc[4]); acc[5] = fmaf(b.y, w[z], acc[5]);
        acc[6] = fmaf(b.z, w[z], acc[6]); acc[7] = fmaf(b.w, w[z], acc[7]);
    }
    float inv = 1.f / (16777216.f * lt);
    unsigned short hi[8];
#pragma unroll
    for (int j = 0; j < 8; ++j) hi[j] = f2h(acc[j] * inv);
    long base = ((long)qb * 16 + row) * 512 + h * 64 + c8 * 8;
    *reinterpret_cast<ushort4*>(&aob[base])     = make_ushort4(hi[0], hi[1], hi[2], hi[3]);
    *reinterpret_cast<ushort4*>(&aob[base + 4]) = make_ushort4(hi[4], hi[5], hi[6], hi[7]);
}

// ---------------- QKV split-K reduce: bias + 2-seg f16 to qb2/kb2, v f32 --------
__global__ __launch_bounds__(256)
void reduce_qkv_k(const float* __restrict__ part,
                  unsigned short* __restrict__ qb2, unsigned short* __restrict__ kb2,
                  float* __restrict__ v,
                  const float* __restrict__ qbias, const float* __restrict__ kbias,
                  const float* __restrict__ vbias, int splitk)
{
    int z = blockIdx.y;
    const long MN = (long)kS * kD;
    long idx = ((long)blockIdx.x * 256 + threadIdx.x) * 4;
    const float* pz = part + (long)z * splitk * MN + idx;
    float4 s = *reinterpret_cast<const float4*>(pz);
    for (int t = 1; t < splitk; ++t) {
        float4 vv = *reinterpret_cast<const float4*>(pz + (long)t * MN);
        s.x += vv.x; s.y += vv.y; s.z += vv.z; s.w += vv.w;
    }
    int m = (int)(idx >> 9), n = (int)(idx & 511);
    const float* bzp = (z == 1) ? kbias : (z == 2) ? vbias : qbias;
    s.x += bzp[n]; s.y += bzp[n + 1]; s.z += bzp[n + 2]; s.w += bzp[n + 3];
    if (z == 2) {
        *reinterpret_cast<float4*>(v + idx) = s;
        return;
    }
    float fv[4] = {s.x, s.y, s.z, s.w};
    unsigned short h[4], lo[4];
#pragma unroll
    for (int j = 0; j < 4; ++j) {
        h[j] = f2h(fv[j]);
        lo[j] = f2h(fv[j] - h2f(h[j]));
    }
    int head = n >> 6, hc = n & 63;
    unsigned short* dst = ((z == 1) ? kb2 : qb2) + (long)head * 131072 + (long)m * 128 + hc;
    ushort4 hv = make_ushort4(h[0], h[1], h[2], h[3]);
    *reinterpret_cast<ushort4*>(dst) = hv;
    if (z == 0) {  // Q: A-side [hi|lo]
        *reinterpret_cast<ushort4*>(dst + 64) = make_ushort4(lo[0], lo[1], lo[2], lo[3]);
    } else {       // K: B-side [hi|hi]
        *reinterpret_cast<ushort4*>(dst + 64) = hv;
    }
}

// ---------------- FFN1 reduce: bias + relu + f16 to hb ----------------
__global__ __launch_bounds__(256)
void reduce3_k(const float* __restrict__ part, unsigned short* __restrict__ hb,
               const float* __restrict__ bias, int splitk)
{
    const long MN = (long)kS * kDFF;
    long idx = ((long)blockIdx.x * 256 + threadIdx.x) * 4;
    const float* pz = part + idx;
    float4 s = *reinterpret_cast<const float4*>(pz);
    for (int t = 1; t < splitk; ++t) {
        float4 v = *reinterpret_cast<const float4*>(pz + (long)t * MN);
        s.x += v.x; s.y += v.y; s.z += v.z; s.w += v.w;
    }
    int n = (int)(idx & 2047);
    unsigned short h[4];
    h[0] = f2h(fmaxf(s.x + bias[n], 0.f));
    h[1] = f2h(fmaxf(s.y + bias[n + 1], 0.f));
    h[2] = f2h(fmaxf(s.z + bias[n + 2], 0.f));
    h[3] = f2h(fmaxf(s.w + bias[n + 3], 0.f));
    *reinterpret_cast<ushort4*>(hb + idx) = make_ushort4(h[0], h[1], h[2], h[3]);
}

// ---------------- fused: split-K reduce + bias + residual + LN + f16 xb ---------
__global__ __launch_bounds__(256)
void add_ln_fused_k(const float* __restrict__ part, float* __restrict__ x,
                    const float* __restrict__ bias,
                    const float* __restrict__ g, const float* __restrict__ b,
                    unsigned short* __restrict__ xb, int splitk)
{
    __shared__ float sm[4];
    int row = blockIdx.x, t = threadIdx.x;
    const long MN = (long)kS * kD;
    float* xr = x + (long)row * kD;
    float s0 = 0.f, s1 = 0.f;
    const float* pr = part + (long)row * kD;
    for (int sl = 0; sl < splitk; ++sl) {
        s0 += pr[(long)sl * MN + t];
        s1 += pr[(long)sl * MN + t + 256];
    }
    s0 += bias[t] + xr[t];
    s1 += bias[t + 256] + xr[t + 256];
    float sum = wave_sum(s0 + s1);
    if ((t & 63) == 0) sm[t >> 6] = sum;
    __syncthreads();
    sum = sm[0] + sm[1] + sm[2] + sm[3];
    float mu = sum * (1.f / kD);
    float d0 = s0 - mu, d1 = s1 - mu;
    __syncthreads();
    float vs = wave_sum(d0 * d0 + d1 * d1);
    if ((t & 63) == 0) sm[t >> 6] = vs;
    __syncthreads();
    vs = sm[0] + sm[1] + sm[2] + sm[3];
    float rs = rsqrtf(vs * (1.f / kD) + 1e-5f);
    float o0 = fmaf(d0 * rs, g[t], b[t]);
    float o1 = fmaf(d1 * rs, g[t + 256], b[t + 256]);
    xr[t]       = o0;
    xr[t + 256] = o1;
    unsigned short* xrow = xb + (long)row * 512;
    xrow[t]       = f2h(o0);
    xrow[t + 256] = f2h(o1);
}

// ---------------- mean-pool partials ----------------
__global__ __launch_bounds__(256)
void pool_k(const float* __restrict__ x, float* __restrict__ partial)
{
    int col = blockIdx.x * 256 + threadIdx.x;
    int rb = blockIdx.y;
    float s = 0.f;
    for (int r = rb * 128; r < rb * 128 + 128; ++r) s += x[(long)r * kD + col];
    partial[rb * kD + col] = s;
}

// ---------------- classifier head ----------------
__global__ __launch_bounds__(256)
void head_k(const float* __restrict__ partial,
            const float* __restrict__ c1w, const float* __restrict__ c1b,
            const float* __restrict__ c2w, const float* __restrict__ c2b,
            float* __restrict__ out)
{
    __shared__ float pooled[kD];
    __shared__ float h1[256];
    int t = threadIdx.x;
    for (int d = t; d < kD; d += 256) {
        float s = 0.f;
        for (int r = 0; r < 8; ++r) s += partial[r * kD + d];
        pooled[d] = s * (1.0f / kS);
    }
    __syncthreads();
    float acc = c1b[t];
    for (int f = 0; f < kD; ++f) acc = fmaf(pooled[f], c1w[f * 256 + t], acc);
    h1[t] = fmaxf(acc, 0.f);
    __syncthreads();
    if (t < 10) {
        float o = c2b[t];
        for (int f = 0; f < 256; ++f) o = fmaf(h1[f], c2w[f * 10 + t], o);
        out[t] = o;
    }
}

// ---------------- launch ----------------
extern "C" void kernel_launch(void* const* d_in, const int* in_sizes, int n_in,
                              void* d_out, int out_size, void* d_ws, size_t ws_size,
                              hipStream_t stream)
{
    (void)in_sizes; (void)n_in; (void)out_size; (void)ws_size;
    const float* features = (const float*)d_in[0];
    const float* positions= (const float*)d_in[1];
    const float* fb       = (const float*)d_in[2];
    const float* in_w     = (const float*)d_in[3];
    const float* in_b     = (const float*)d_in[4];
    const float* qw  = (const float*)d_in[5];
    const float* qb  = (const float*)d_in[6];
    const float* kw  = (const float*)d_in[7];
    const float* kb  = (const float*)d_in[8];
    const float* vw  = (const float*)d_in[9];
    const float* vb  = (const float*)d_in[10];
    const float* ow  = (const float*)d_in[11];
    const float* ob  = (const float*)d_in[12];
    const float* db1w= (const float*)d_in[13];
    const float* db1b= (const float*)d_in[14];
    const float* db2w= (const float*)d_in[15];
    const float* db2b= (const float*)d_in[16];
    const float* n1g = (const float*)d_in[17];
    const float* n1b = (const float*)d_in[18];
    const float* n2g = (const float*)d_in[19];
    const float* n2b = (const float*)d_in[20];
    const float* f1w = (const float*)d_in[21];
    const float* f1b = (const float*)d_in[22];
    const float* f2w = (const float*)d_in[23];
    const float* f2b = (const float*)d_in[24];
    const float* c1w = (const float*)d_in[25];
    const float* c1b = (const float*)d_in[26];
    const float* c2w = (const float*)d_in[27];
    const float* c2b = (const float*)d_in[28];

    float* ws = (float*)d_ws;
    const long SD = (long)kS * kD;            // 524288
    float* x      = ws;
    float* v      = ws + 1 * SD;
    float* dist   = ws + 3 * SD;              // 2*SD
    float* part   = ws + 5 * SD;              // 12*SD scratch
    float* bpw    = ws + 17 * SD;
    float* Atab   = bpw + 256;
    float* Btab   = Atab + 2080;
    float* partial= Btab + 2080;

    // flash partial overlays inside `part`
    float* po = part;                          // 4,194,304 floats
    float* pmv = part + 4194304;               // 65536
    float* plv = pmv + 65536;                  // 65536

    unsigned short* ub = (unsigned short*)(ws + 17 * SD + 8512);
    unsigned short* xb   = ub;                       // 1024*512 (f16)
    unsigned short* aob  = xb   + 524288;            // 1024*512
    unsigned short* qb2  = aob  + 524288;            // 8*1024*128 (2-seg)
    unsigned short* kb2  = qb2  + 1048576;
    unsigned short* vtb  = kb2  + 1048576;           // 512*1024 (f16)
    unsigned short* hb   = vtb  + 524288;            // 1024*2048
    unsigned short* qwb  = hb   + 2097152;           // 2 x 512*512
    unsigned short* kwb  = qwb  + 524288;
    unsigned short* vwb  = kwb  + 524288;
    unsigned short* owb  = vwb  + 524288;
    unsigned short* f1wb = owb  + 524288;            // 2 x 2048*512
    unsigned short* f2wb = f1wb + 2097152;           // 2 x 512*2048
    unsigned short* bmap = f2wb + 2097152;           // 8*1024*1024 f16

    input_pe_k<<<kS, 256, 0, stream>>>(features, positions, fb, in_w, in_b, x);
    dist_k<<<kS, 256, 0, stream>>>(positions, dist);
    pwl_sort_k<<<2, 128, 0, stream>>>(db1w, db1b, bpw);
    pwl_tab_k<<<dim3(129, 2), 256, 0, stream>>>(db1w, db1b, db2w, db2b, bpw, Atab, Btab);
    tof16_k<<<512, 256, 0, stream>>>(x, xb, 524288);

    trw_f16_k<<<dim3(16, 16, 2), 256, 0, stream>>>(qw, qwb, 512, 512, 262144, 262144);
    trw_f16_k<<<dim3(16, 16, 2), 256, 0, stream>>>(kw, kwb, 512, 512, 262144, 262144);
    trw_f16_k<<<dim3(16, 16, 2), 256, 0, stream>>>(vw, vwb, 512, 512, 262144, 262144);
    trw_f16_k<<<dim3(16, 16, 2), 256, 0, stream>>>(ow, owb, 512, 512, 262144, 262144);
    trw_f16_k<<<dim3(16, 64, 2), 256, 0, stream>>>(f1w, f1wb, 512, 2048, 1048576, 1048576);
    trw_f16_k<<<dim3(64, 16, 2), 256, 0, stream>>>(f2w, f2wb, 2048, 512, 1048576, 1048576);

    for (int l = 0; l < 2; ++l) {
        biasmap_k<<<1024, 256, 0, stream>>>(
            dist, bpw + l * 128, Atab + l * 1040, Btab + l * 1040, bmap);

        // QKV: A=xb (1024x512 f16), split-K x2 (384 blocks)
        bgemm_k<<<dim3(16, 4, 6), 256, 0, stream>>>(
            xb, qwb + l * 262144, kwb + l * 262144, vwb + l * 262144,
            1024, 512, 256, 512, 512, 0, 2, part);
        reduce_qkv_k<<<dim3(512, 3), 256, 0, stream>>>(
            part, qb2, kb2, v, qb + l * kD, kb + l * kD, vb + l * kD, 2);
        tr_f16_k<<<dim3(32, 16), 256, 0, stream>>>(v, vtb, 1024, 512, 1024.f);

        // fused attention (Q 2-seg kept for accuracy)
        flash_part_k<<<dim3(64, 8, 8), 64, 0, stream>>>(
            qb2, kb2, vtb, bmap, po, pmv, plv);
        flash_merge_k<<<256, 256, 0, stream>>>(po, pmv, plv, aob);

        // O-proj: K=512, split-K x4 (256 blocks); reduce fused into add_ln
        bgemm_k<<<dim3(16, 4, 4), 256, 0, stream>>>(
            aob, owb + l * 262144, owb + l * 262144, owb + l * 262144,
            1024, 512, 128, 512, 512, 0, 4, part);
        add_ln_fused_k<<<kS, 256, 0, stream>>>(
            part, x, ob + l * kD, n1g + l * kD, n1b + l * kD, xb, 4);

        // FFN1: K=512, split-K x2 (512 blocks), reduce fuses bias+relu -> hb f16
        bgemm_k<<<dim3(16, 16, 2), 256, 0, stream>>>(
            xb, f1wb + l * 1048576, f1wb + l * 1048576, f1wb + l * 1048576,
            1024, 2048, 256, 512, 512, 0, 2, part);
        reduce3_k<<<2048, 256, 0, stream>>>(part, hb, f1b + l * kDFF, 2);

        // FFN2: K=2048, split-K x4 (256 blocks); reduce fused into add_ln
        bgemm_k<<<dim3(16, 4, 4), 256, 0, stream>>>(
            hb, f2wb + l * 1048576, f2wb + l * 1048576, f2wb + l * 1048576,
            1024, 512, 512, 2048, 2048, 0, 4, part);
        add_ln_fused_k<<<kS, 256, 0, stream>>>(
            part, x, f2b + l * kD, n2g + l * kD, n2b + l * kD, xb, 4);
    }

    pool_k<<<dim3(2, 8), 256, 0, stream>>>(x, partial);
    head_k<<<1, 256, 0, stream>>>(partial, c1w, c1b, c2w, c2b, (float*)d_out);
}

// Round 15
// 369.063 us; speedup vs baseline: 1.6887x; 1.0517x over previous
//
#include <hip/hip_runtime.h>

namespace {
constexpr int kS   = 1024;
constexpr int kD   = 512;
constexpr int kH   = 8;
constexpr int kDFF = 2048;
constexpr int kNF  = 85;   // D//6
}

typedef __attribute__((ext_vector_type(8))) short bhalf8_t;    // 8x16-bit in 4 VGPRs
typedef _Float16 half8_t __attribute__((ext_vector_type(8)));
typedef __attribute__((ext_vector_type(4))) float f32x4_t;

// ---------------- helpers ----------------
__device__ __forceinline__ float wave_sum(float v) {
#pragma unroll
    for (int o = 1; o < 64; o <<= 1) v += __shfl_xor(v, o, 64);
    return v;
}
__device__ __forceinline__ unsigned short f2h(float f) {    // RNE fp32->fp16
    _Float16 h = (_Float16)f;
    return __builtin_bit_cast(unsigned short, h);
}
__device__ __forceinline__ float h2f(unsigned short u) {
    return (float)__builtin_bit_cast(_Float16, u);
}

// ---------------- input projection + positional encoding ----------------
__global__ __launch_bounds__(256)
void input_pe_k(const float* __restrict__ feat, const float* __restrict__ pos,
                const float* __restrict__ fb, const float* __restrict__ in_w,
                const float* __restrict__ in_b, float* __restrict__ x)
{
    int s = blockIdx.x;
    int t = threadIdx.x;
    __shared__ float f[64];
    if (t < 64) f[t] = feat[s * 64 + t];
    __syncthreads();
    float acc0 = in_b[t], acc1 = in_b[t + 256];
#pragma unroll 8
    for (int c = 0; c < 64; ++c) {
        float fv = f[c];
        acc0 = fmaf(fv, in_w[c * kD + t], acc0);
        acc1 = fmaf(fv, in_w[c * kD + 256 + t], acc1);
    }
    float pe0 = 0.f, pe1 = 0.f;
    {
        int d = t;
        if (d < 6 * kNF) {
            int seg = d / kNF, idx = d - seg * kNF;
            float cs = pos[s * 3 + (seg >> 1)] * fb[idx];
            pe0 = (seg & 1) ? cosf(cs) : sinf(cs);
        }
        d = t + 256;
        if (d < 6 * kNF) {
            int seg = d / kNF, idx = d - seg * kNF;
            float cs = pos[s * 3 + (seg >> 1)] * fb[idx];
            pe1 = (seg & 1) ? cosf(cs) : sinf(cs);
        }
    }
    x[s * kD + t]       = acc0 + pe0;
    x[s * kD + 256 + t] = acc1 + pe1;
}

// ---------------- pairwise distance matrix ----------------
__global__ __launch_bounds__(256)
void dist_k(const float* __restrict__ pos, float* __restrict__ dist)
{
    int i = blockIdx.x;
    float px = pos[i * 3], py = pos[i * 3 + 1], pz = pos[i * 3 + 2];
    for (int j = threadIdx.x; j < kS; j += 256) {
        float dx = px - pos[j * 3], dy = py - pos[j * 3 + 1], dz = pz - pos[j * 3 + 2];
        float sq = dx * dx + dy * dy + dz * dz;
        dist[(long)i * kS + j] = sq > 0.f ? sqrtf(sq) : 0.f;
    }
}

// ---------------- PWL: sort breakpoints only (tiny) ----------------
__global__ __launch_bounds__(128)
void pwl_sort_k(const float* __restrict__ a_, const float* __restrict__ b_,
                float* __restrict__ bp_out)
{
    int l = blockIdx.x;
    a_ += l * 128; b_ += l * 128; bp_out += l * 128;
    __shared__ float key[128];
    int t = threadIdx.x;
    float a = a_[t], b = b_[t];
    key[t] = (a != 0.f) ? (-b / a) : 3.0e38f;
    __syncthreads();
    for (int ksz = 2; ksz <= 128; ksz <<= 1) {
        for (int j = ksz >> 1; j > 0; j >>= 1) {
            int ixj = t ^ j;
            if (ixj > t) {
                bool up = ((t & ksz) == 0);
                float x0 = key[t], x1 = key[ixj];
                if ((x0 > x1) == up) { key[t] = x1; key[ixj] = x0; }
            }
            __syncthreads();
        }
    }
    bp_out[t] = key[t];
}

// ---------------- PWL: per-segment table build ----------------
__global__ __launch_bounds__(256)
void pwl_tab_k(const float* __restrict__ a_, const float* __restrict__ b_,
               const float* __restrict__ w2, const float* __restrict__ b2,
               const float* __restrict__ bp, float* __restrict__ Atab,
               float* __restrict__ Btab)
{
    int l = blockIdx.y;
    int seg = blockIdx.x;   // 0..128
    a_ += l * 128; b_ += l * 128; w2 += l * 1024; b2 += l * 8;
    bp += l * 128; Atab += l * 1040; Btab += l * 1040;

    float m;
    if (seg == 0)        m = bp[0] - 1.0f;
    else if (seg == 128) m = bp[127] + 1.0f;
    else                 m = 0.5f * (bp[seg - 1] + bp[seg]);

    int t = threadIdx.x;
    int h = t & 7, cg = t >> 3;
    float A = 0.f, B = 0.f;
#pragma unroll
    for (int j = 0; j < 4; ++j) {
        int c = cg * 4 + j;
        float a = a_[c], b = b_[c];
        if (fmaf(a, m, b) > 0.f) {
            float w = w2[c * 8 + h];
            A = fmaf(a, w, A);
            B = fmaf(b, w, B);
        }
    }
#pragma unroll
    for (int off = 8; off < 64; off <<= 1) {
        A += __shfl_xor(A, off, 64);
        B += __shfl_xor(B, off, 64);
    }
    __shared__ float sA[4][8], sB[4][8];
    int w = t >> 6, lane = t & 63;
    if (lane < 8) { sA[w][lane] = A; sB[w][lane] = B; }
    __syncthreads();
    if (t < 8) {
        float At = sA[0][t] + sA[1][t] + sA[2][t] + sA[3][t];
        float Bt = sB[0][t] + sB[1][t] + sB[2][t] + sB[3][t];
        Atab[seg * 8 + t] = At;
        Btab[seg * 8 + t] = Bt + b2[t];
    }
}

// ---------------- per-layer bias map: one search -> all 8 heads ----------------
__global__ __launch_bounds__(256)
void biasmap_k(const float* __restrict__ dist, const float* __restrict__ bp,
               const float* __restrict__ Atab, const float* __restrict__ Btab,
               unsigned short* __restrict__ bmap)
{
    __shared__ float bps[128], Ah[1032], Bh[1032];
    int t = threadIdx.x;
    if (t < 128) bps[t] = bp[t];
    for (int i = t; i < 1032; i += 256) { Ah[i] = Atab[i]; Bh[i] = Btab[i]; }
    __syncthreads();
    long i = ((long)blockIdx.x * 256 + t) * 4;
    float4 d4 = *reinterpret_cast<const float4*>(dist + i);
    float dv[4] = {d4.x, d4.y, d4.z, d4.w};
    int seg[4];
#pragma unroll
    for (int j = 0; j < 4; ++j) {
        float tv = dv[j];
        int lo = 0, hi = 128;
        while (lo < hi) { int mid = (lo + hi) >> 1; if (bps[mid] < tv) lo = mid + 1; else hi = mid; }
        seg[j] = lo;
    }
#pragma unroll
    for (int h = 0; h < 8; ++h) {
        unsigned short o[4];
#pragma unroll
        for (int j = 0; j < 4; ++j)
            o[j] = f2h(fmaf(Ah[seg[j] * 8 + h], dv[j], Bh[seg[j] * 8 + h]));
        *reinterpret_cast<ushort4*>(bmap + (long)h * 1048576 + i) =
            make_ushort4(o[0], o[1], o[2], o[3]);
    }
}

// ---------------- fp32 -> f16 plain, contiguous ----------------
__global__ __launch_bounds__(256)
void tof16_k(const float* __restrict__ in, unsigned short* __restrict__ out, long total)
{
    long i = ((long)blockIdx.x * 256 + threadIdx.x) * 4;
    if (i >= total) return;
    float4 v = *reinterpret_cast<const float4*>(in + i);
    *reinterpret_cast<ushort4*>(out + i) =
        make_ushort4(f2h(v.x), f2h(v.y), f2h(v.z), f2h(v.w));
}

// ---------------- fp32 K x N -> f16 N x K transpose (weights, layer-batched) ----
__global__ __launch_bounds__(256)
void trw_f16_k(const float* __restrict__ in, unsigned short* __restrict__ out,
               int K, int N, long szIn, long szOut)
{
    __shared__ float tile[32][33];
    int z = blockIdx.z;
    in  += (long)z * szIn;
    out += (long)z * szOut;
    int k0 = blockIdx.x * 32, n0 = blockIdx.y * 32;
    int t = threadIdx.x;
    int r = t >> 3, c4 = (t & 7) * 4;
    float4 v = *reinterpret_cast<const float4*>(&in[(long)(k0 + r) * N + n0 + c4]);
    tile[r][c4] = v.x; tile[r][c4 + 1] = v.y; tile[r][c4 + 2] = v.z; tile[r][c4 + 3] = v.w;
    __syncthreads();
    int nr = t >> 3, kq = (t & 7) * 4;
    unsigned short h[4];
#pragma unroll
    for (int j = 0; j < 4; ++j) h[j] = f2h(tile[kq + j][nr]);
    *reinterpret_cast<ushort4*>(&out[(long)(n0 + nr) * K + k0 + kq]) =
        make_ushort4(h[0], h[1], h[2], h[3]);
}

// ---------------- fp32 K x N -> f16 N x K transpose with scale (V matrix) -------
__global__ __launch_bounds__(256)
void tr_f16_k(const float* __restrict__ in, unsigned short* __restrict__ out,
              int K, int N, float scl)
{
    __shared__ float tile[32][33];
    int k0 = blockIdx.x * 32, n0 = blockIdx.y * 32;
    int t = threadIdx.x;
    int r = t >> 3, c4 = (t & 7) * 4;
    float4 v = *reinterpret_cast<const float4*>(&in[(long)(k0 + r) * N + n0 + c4]);
    tile[r][c4] = v.x; tile[r][c4 + 1] = v.y; tile[r][c4 + 2] = v.z; tile[r][c4 + 3] = v.w;
    __syncthreads();
    int nr = t >> 3, kq = (t & 7) * 4;
    unsigned short h[4];
#pragma unroll
    for (int j = 0; j < 4; ++j) h[j] = f2h(tile[kq + j][nr] * scl);
    *reinterpret_cast<ushort4*>(&out[(long)(n0 + nr) * K + k0 + kq]) =
        make_ushort4(h[0], h[1], h[2], h[3]);
}

// ---------------- f16 MFMA GEMM, split-K f16 partial writer ----------------
// A: M x K f16 row-major, B: N x K f16 row-major. 64x128 tile, 4 waves of 32x64.
// Partials stored as f16 (halves round-trip traffic; reduce accumulates in f32).
__global__ __launch_bounds__(256, 4)
void bgemm_k(const unsigned short* __restrict__ A,
             const unsigned short* __restrict__ B0, const unsigned short* __restrict__ B1,
             const unsigned short* __restrict__ B2,
             int M, int N, int K, int lda, int ldb,
             long sA, int splitk,
             unsigned short* __restrict__ Cpart)
{
    constexpr int BKp = 40;
    int tid = threadIdx.x;
    int bz = blockIdx.z;
    int z  = bz / splitk;
    int ks = bz - z * splitk;

    const unsigned short* Ap = A + (long)z * sA + (long)ks * K;
    const unsigned short* Bp = ((z == 1) ? B1 : (z == 2) ? B2 : B0) + (long)ks * K;

    __shared__ unsigned short As[64 * BKp];
    __shared__ unsigned short Bs[128 * BKp];

    int bm = blockIdx.x * 64;
    int bn = blockIdx.y * 128;
    int w = tid >> 6, lane = tid & 63, quad = lane >> 4, l16 = lane & 15;
    int wm = (w >> 1) * 32;
    int wn = (w & 1) * 64;

    int ar = tid >> 2, ac = (tid & 3) * 8;
    int br = tid >> 1, bc = (tid & 1) * 16;

    f32x4_t acc[2][4] = {};
    bhalf8_t aS0, bS0, bS1;

    auto ldgA = [&](int k0) {
        aS0 = *reinterpret_cast<const bhalf8_t*>(Ap + (long)(bm + ar) * lda + k0 + ac);
    };
    auto ldgB = [&](int k0) {
        const unsigned short* p = Bp + (long)(bn + br) * ldb + k0 + bc;
        bS0 = *reinterpret_cast<const bhalf8_t*>(p);
        bS1 = *reinterpret_cast<const bhalf8_t*>(p + 8);
    };

    ldgA(0); ldgB(0);

    for (int k0 = 0; k0 < K; k0 += 32) {
        *reinterpret_cast<bhalf8_t*>(&As[ar * BKp + ac])     = aS0;
        *reinterpret_cast<bhalf8_t*>(&Bs[br * BKp + bc])     = bS0;
        *reinterpret_cast<bhalf8_t*>(&Bs[br * BKp + bc + 8]) = bS1;
        __syncthreads();
        if (k0 + 32 < K) { ldgA(k0 + 32); ldgB(k0 + 32); }
        bhalf8_t af[2], bf[4];
#pragma unroll
        for (int i = 0; i < 2; ++i)
            af[i] = *reinterpret_cast<const bhalf8_t*>(&As[(wm + i * 16 + l16) * BKp + quad * 8]);
#pragma unroll
        for (int j = 0; j < 4; ++j)
            bf[j] = *reinterpret_cast<const bhalf8_t*>(&Bs[(wn + j * 16 + l16) * BKp + quad * 8]);
#pragma unroll
        for (int i = 0; i < 2; ++i)
#pragma unroll
            for (int j = 0; j < 4; ++j)
                acc[i][j] = __builtin_amdgcn_mfma_f32_16x16x32_f16(
                    __builtin_bit_cast(half8_t, af[i]), __builtin_bit_cast(half8_t, bf[j]),
                    acc[i][j], 0, 0, 0);
        __syncthreads();
    }

    unsigned short* Cp = Cpart + (long)bz * M * N;
#pragma unroll
    for (int i = 0; i < 2; ++i)
#pragma unroll
        for (int j = 0; j < 4; ++j)
#pragma unroll
            for (int r = 0; r < 4; ++r) {
                int m = bm + wm + i * 16 + quad * 4 + r;
                int n = bn + wn + j * 16 + l16;
                Cp[(long)m * N + n] = f2h(acc[i][j][r]);
            }
}

// ---------------- flash partial: one wave = (16 Q-rows, 128 keys, 1 head) --------
// Q/K per-head 1024x128 f16 2-seg (Q [hi|lo], K [hi|hi]).
// po stored as f16 (descaled by 2^-24 before convert).
__global__ __launch_bounds__(64)
void flash_part_k(const unsigned short* __restrict__ qb2, const unsigned short* __restrict__ kb2,
                  const unsigned short* __restrict__ vtb, const unsigned short* __restrict__ bmap,
                  unsigned short* __restrict__ po, float* __restrict__ pm, float* __restrict__ pl)
{
    __shared__ unsigned short Ps[16 * 136];

    int tid = threadIdx.x;
    int qb = blockIdx.x;            // 64 Q-blocks of 16 rows
    int h  = blockIdx.y;            // 8 heads
    int z  = blockIdx.z;            // 8 key-slices of 128
    int bm = qb * 16;
    int k0 = z * 128;

    const unsigned short* Qh = qb2 + (long)h * 131072;
    const unsigned short* Kh = kb2 + (long)h * 131072;
    const unsigned short* Vh = vtb + (long)h * 65536;
    const unsigned short* Bm = bmap + (long)h * 1048576;

    int quad = tid >> 4, l16 = tid & 15;

    bhalf8_t aq[4];
#pragma unroll
    for (int kq = 0; kq < 4; ++kq)
        aq[kq] = *reinterpret_cast<const bhalf8_t*>(
            &Qh[(long)(bm + l16) * 128 + kq * 32 + quad * 8]);

    f32x4_t sacc[8] = {};
#pragma unroll
    for (int kq = 0; kq < 4; ++kq) {
        bhalf8_t bk[8];
#pragma unroll
        for (int nb = 0; nb < 8; ++nb)
            bk[nb] = *reinterpret_cast<const bhalf8_t*>(
                &Kh[(long)(k0 + nb * 16 + l16) * 128 + kq * 32 + quad * 8]);
#pragma unroll
        for (int nb = 0; nb < 8; ++nb)
            sacc[nb] = __builtin_amdgcn_mfma_f32_16x16x32_f16(
                __builtin_bit_cast(half8_t, aq[kq]), __builtin_bit_cast(half8_t, bk[nb]),
                sacc[nb], 0, 0, 0);
    }

    float m_r[4] = {-3.0e38f, -3.0e38f, -3.0e38f, -3.0e38f};
#pragma unroll
    for (int nb = 0; nb < 8; ++nb)
#pragma unroll
        for (int r = 0; r < 4; ++r) {
            int gm = bm + quad * 4 + r;
            int gn = k0 + nb * 16 + l16;
            float bias = h2f(Bm[(long)gm * kS + gn]);
            float s = fmaf(sacc[nb][r], 0.125f, bias);
            sacc[nb][r] = s;
            m_r[r] = fmaxf(m_r[r], s);
        }
#pragma unroll
    for (int r = 0; r < 4; ++r) {
        float m_ = m_r[r];
#pragma unroll
        for (int off = 1; off < 16; off <<= 1) m_ = fmaxf(m_, __shfl_xor(m_, off, 64));
        m_r[r] = m_;
    }

    float l_r[4];
#pragma unroll
    for (int r = 0; r < 4; ++r) {
        int row = quad * 4 + r;
        float mN = m_r[r];
        float s_ = 0.f;
#pragma unroll
        for (int nb = 0; nb < 8; ++nb) {
            float p = __expf(sacc[nb][r] - mN);
            Ps[row * 136 + nb * 16 + l16] = f2h(p * 16384.f);
            s_ += p;
        }
#pragma unroll
        for (int off = 1; off < 16; off <<= 1) s_ += __shfl_xor(s_, off, 64);
        l_r[r] = s_;
    }

    long sbase = (((long)z * 8 + h) * 64 + qb) * 16;
    if (l16 == 0) {
#pragma unroll
        for (int r = 0; r < 4; ++r) {
            pm[sbase + quad * 4 + r] = m_r[r];
            pl[sbase + quad * 4 + r] = l_r[r];
        }
    }
    __syncthreads();

    f32x4_t oacc[4] = {};
#pragma unroll
    for (int kq2 = 0; kq2 < 4; ++kq2) {
        bhalf8_t ap = *reinterpret_cast<const bhalf8_t*>(&Ps[l16 * 136 + kq2 * 32 + quad * 8]);
#pragma unroll
        for (int j2 = 0; j2 < 4; ++j2) {
            bhalf8_t bv = *reinterpret_cast<const bhalf8_t*>(
                &Vh[(long)(j2 * 16 + l16) * 1024 + k0 + kq2 * 32 + quad * 8]);
            oacc[j2] = __builtin_amdgcn_mfma_f32_16x16x32_f16(
                __builtin_bit_cast(half8_t, ap), __builtin_bit_cast(half8_t, bv),
                oacc[j2], 0, 0, 0);
        }
    }

    unsigned short* pob = po + sbase * 64;
#pragma unroll
    for (int j2 = 0; j2 < 4; ++j2)
#pragma unroll
        for (int r = 0; r < 4; ++r)
            pob[(quad * 4 + r) * 64 + j2 * 16 + l16] =
                f2h(oacc[j2][r] * (1.f / 16777216.f));
}

// ---------------- flash merge: combine 8 key-slice f16 partials -> aob f16 -------
__global__ __launch_bounds__(256)
void flash_merge_k(const unsigned short* __restrict__ po, const float* __restrict__ pm,
                   const float* __restrict__ pl, unsigned short* __restrict__ aob)
{
    int t = blockIdx.x * 256 + threadIdx.x;
    int c8  = t & 7;
    int row = (t >> 3) & 15;
    int qb  = (t >> 7) & 63;
    int h   = t >> 13;
    long sidx = (((long)h * 64) + qb) * 16 + row;

    float m[8];
    float M = -3.0e38f;
#pragma unroll
    for (int z = 0; z < 8; ++z) { m[z] = pm[z * 8192 + sidx]; M = fmaxf(M, m[z]); }
    float w[8], lt = 0.f;
#pragma unroll
    for (int z = 0; z < 8; ++z) {
        w[z] = __expf(m[z] - M);
        lt = fmaf(pl[z * 8192 + sidx], w[z], lt);
    }
    float acc[8] = {};
#pragma unroll
    for (int z = 0; z < 8; ++z) {
        const unsigned short* p = po + (z * 8192 + sidx) * 64 + c8 * 8;
        ushort4 a = *reinterpret_cast<const ushort4*>(p);
        ushort4 b = *reinterpret_cast<const ushort4*>(p + 4);
        acc[0] = fmaf(h2f(a.x), w[z], acc[0]); acc[1] = fmaf(h2f(a.y), w[z], acc[1]);
        acc[2] = fmaf(h2f(a.z), w[z], acc[2]); acc[3] = fmaf(h2f(a.w), w[z], acc[3]);
        acc[4] = fmaf(h2f(b.x), w[z], acc[4]); acc[5] = fmaf(h2f(b.y), w[z], acc[5]);
        acc[6] = fmaf(h2f(b.z), w[z], acc[6]); acc[7] = fmaf(h2f(b.w), w[z], acc[7]);
    }
    float inv = 1.f / lt;
    unsigned short hi[8];
#pragma unroll
    for (int j = 0; j < 8; ++j) hi[j] = f2h(acc[j] * inv);
    long base = ((long)qb * 16 + row) * 512 + h * 64 + c8 * 8;
    *reinterpret_cast<ushort4*>(&aob[base])     = make_ushort4(hi[0], hi[1], hi[2], hi[3]);
    *reinterpret_cast<ushort4*>(&aob[base + 4]) = make_ushort4(hi[4], hi[5], hi[6], hi[7]);
}

// ---------------- QKV split-K reduce (f16 partials): bias + 2-seg q/k, v f32 ----
__global__ __launch_bounds__(256)
void reduce_qkv_k(const unsigned short* __restrict__ part,
                  unsigned short* __restrict__ qb2, unsigned short* __restrict__ kb2,
                  float* __restrict__ v,
                  const float* __restrict__ qbias, const float* __restrict__ kbias,
                  const float* __restrict__ vbias, int splitk)
{
    int z = blockIdx.y;
    const long MN = (long)kS * kD;
    long idx = ((long)blockIdx.x * 256 + threadIdx.x) * 4;
    const unsigned short* pz = part + (long)z * splitk * MN + idx;
    float s0 = 0.f, s1 = 0.f, s2 = 0.f, s3 = 0.f;
    for (int t = 0; t < splitk; ++t) {
        ushort4 u = *reinterpret_cast<const ushort4*>(pz + (long)t * MN);
        s0 += h2f(u.x); s1 += h2f(u.y); s2 += h2f(u.z); s3 += h2f(u.w);
    }
    int m = (int)(idx >> 9), n = (int)(idx & 511);
    const float* bzp = (z == 1) ? kbias : (z == 2) ? vbias : qbias;
    s0 += bzp[n]; s1 += bzp[n + 1]; s2 += bzp[n + 2]; s3 += bzp[n + 3];
    if (z == 2) {
        *reinterpret_cast<float4*>(v + idx) = make_float4(s0, s1, s2, s3);
        return;
    }
    float fv[4] = {s0, s1, s2, s3};
    unsigned short h[4], lo[4];
#pragma unroll
    for (int j = 0; j < 4; ++j) {
        h[j] = f2h(fv[j]);
        lo[j] = f2h(fv[j] - h2f(h[j]));
    }
    int head = n >> 6, hc = n & 63;
    unsigned short* dst = ((z == 1) ? kb2 : qb2) + (long)head * 131072 + (long)m * 128 + hc;
    ushort4 hv = make_ushort4(h[0], h[1], h[2], h[3]);
    *reinterpret_cast<ushort4*>(dst) = hv;
    if (z == 0) {  // Q: A-side [hi|lo]
        *reinterpret_cast<ushort4*>(dst + 64) = make_ushort4(lo[0], lo[1], lo[2], lo[3]);
    } else {       // K: B-side [hi|hi]
        *reinterpret_cast<ushort4*>(dst + 64) = hv;
    }
}

// ---------------- FFN1 reduce (f16 partials): bias + relu + f16 to hb -----------
__global__ __launch_bounds__(256)
void reduce3_k(const unsigned short* __restrict__ part, unsigned short* __restrict__ hb,
               const float* __restrict__ bias, int splitk)
{
    const long MN = (long)kS * kDFF;
    long idx = ((long)blockIdx.x * 256 + threadIdx.x) * 4;
    const unsigned short* pz = part + idx;
    float s0 = 0.f, s1 = 0.f, s2 = 0.f, s3 = 0.f;
    for (int t = 0; t < splitk; ++t) {
        ushort4 u = *reinterpret_cast<const ushort4*>(pz + (long)t * MN);
        s0 += h2f(u.x); s1 += h2f(u.y); s2 += h2f(u.z); s3 += h2f(u.w);
    }
    int n = (int)(idx & 2047);
    unsigned short h[4];
    h[0] = f2h(fmaxf(s0 + bias[n], 0.f));
    h[1] = f2h(fmaxf(s1 + bias[n + 1], 0.f));
    h[2] = f2h(fmaxf(s2 + bias[n + 2], 0.f));
    h[3] = f2h(fmaxf(s3 + bias[n + 3], 0.f));
    *reinterpret_cast<ushort4*>(hb + idx) = make_ushort4(h[0], h[1], h[2], h[3]);
}

// ---------------- fused: f16 split-K reduce + bias + residual + LN + f16 xb -----
__global__ __launch_bounds__(256)
void add_ln_fused_k(const unsigned short* __restrict__ part, float* __restrict__ x,
                    const float* __restrict__ bias,
                    const float* __restrict__ g, const float* __restrict__ b,
                    unsigned short* __restrict__ xb, int splitk)
{
    __shared__ float sm[4];
    int row = blockIdx.x, t = threadIdx.x;
    const long MN = (long)kS * kD;
    float* xr = x + (long)row * kD;
    float s0 = 0.f, s1 = 0.f;
    const unsigned short* pr = part + (long)row * kD;
    for (int sl = 0; sl < splitk; ++sl) {
        s0 += h2f(pr[(long)sl * MN + t]);
        s1 += h2f(pr[(long)sl * MN + t + 256]);
    }
    s0 += bias[t] + xr[t];
    s1 += bias[t + 256] + xr[t + 256];
    float sum = wave_sum(s0 + s1);
    if ((t & 63) == 0) sm[t >> 6] = sum;
    __syncthreads();
    sum = sm[0] + sm[1] + sm[2] + sm[3];
    float mu = sum * (1.f / kD);
    float d0 = s0 - mu, d1 = s1 - mu;
    __syncthreads();
    float vs = wave_sum(d0 * d0 + d1 * d1);
    if ((t & 63) == 0) sm[t >> 6] = vs;
    __syncthreads();
    vs = sm[0] + sm[1] + sm[2] + sm[3];
    float rs = rsqrtf(vs * (1.f / kD) + 1e-5f);
    float o0 = fmaf(d0 * rs, g[t], b[t]);
    float o1 = fmaf(d1 * rs, g[t + 256], b[t + 256]);
    xr[t]       = o0;
    xr[t + 256] = o1;
    unsigned short* xrow = xb + (long)row * 512;
    xrow[t]       = f2h(o0);
    xrow[t + 256] = f2h(o1);
}

// ---------------- mean-pool partials ----------------
__global__ __launch_bounds__(256)
void pool_k(const float* __restrict__ x, float* __restrict__ partial)
{
    int col = blockIdx.x * 256 + threadIdx.x;
    int rb = blockIdx.y;
    float s = 0.f;
    for (int r = rb * 128; r < rb * 128 + 128; ++r) s += x[(long)r * kD + col];
    partial[rb * kD + col] = s;
}

// ---------------- classifier head ----------------
__global__ __launch_bounds__(256)
void head_k(const float* __restrict__ partial,
            const float* __restrict__ c1w, const float* __restrict__ c1b,
            const float* __restrict__ c2w, const float* __restrict__ c2b,
            float* __restrict__ out)
{
    __shared__ float pooled[kD];
    __shared__ float h1[256];
    int t = threadIdx.x;
    for (int d = t; d < kD; d += 256) {
        float s = 0.f;
        for (int r = 0; r < 8; ++r) s += partial[r * kD + d];
        pooled[d] = s * (1.0f / kS);
    }
    __syncthreads();
    float acc = c1b[t];
    for (int f = 0; f < kD; ++f) acc = fmaf(pooled[f], c1w[f * 256 + t], acc);
    h1[t] = fmaxf(acc, 0.f);
    __syncthreads();
    if (t < 10) {
        float o = c2b[t];
        for (int f = 0; f < 256; ++f) o = fmaf(h1[f], c2w[f * 10 + t], o);
        out[t] = o;
    }
}

// ---------------- launch ----------------
extern "C" void kernel_launch(void* const* d_in, const int* in_sizes, int n_in,
                              void* d_out, int out_size, void* d_ws, size_t ws_size,
                              hipStream_t stream)
{
    (void)in_sizes; (void)n_in; (void)out_size; (void)ws_size;
    const float* features = (const float*)d_in[0];
    const float* positions= (const float*)d_in[1];
    const float* fb       = (const float*)d_in[2];
    const float* in_w     = (const float*)d_in[3];
    const float* in_b     = (const float*)d_in[4];
    const float* qw  = (const float*)d_in[5];
    const float* qb  = (const float*)d_in[6];
    const float* kw  = (const float*)d_in[7];
    const float* kb  = (const float*)d_in[8];
    const float* vw  = (const float*)d_in[9];
    const float* vb  = (const float*)d_in[10];
    const float* ow  = (const float*)d_in[11];
    const float* ob  = (const float*)d_in[12];
    const float* db1w= (const float*)d_in[13];
    const float* db1b= (const float*)d_in[14];
    const float* db2w= (const float*)d_in[15];
    const float* db2b= (const float*)d_in[16];
    const float* n1g = (const float*)d_in[17];
    const float* n1b = (const float*)d_in[18];
    const float* n2g = (const float*)d_in[19];
    const float* n2b = (const float*)d_in[20];
    const float* f1w = (const float*)d_in[21];
    const float* f1b = (const float*)d_in[22];
    const float* f2w = (const float*)d_in[23];
    const float* f2b = (const float*)d_in[24];
    const float* c1w = (const float*)d_in[25];
    const float* c1b = (const float*)d_in[26];
    const float* c2w = (const float*)d_in[27];
    const float* c2b = (const float*)d_in[28];

    float* ws = (float*)d_ws;
    const long SD = (long)kS * kD;            // 524288
    float* x      = ws;
    float* v      = ws + 1 * SD;
    float* dist   = ws + 3 * SD;              // 2*SD
    float* part_f = ws + 5 * SD;              // scratch region (reused)
    float* bpw    = ws + 17 * SD;
    float* Atab   = bpw + 256;
    float* Btab   = Atab + 2080;
    float* partial= Btab + 2080;

    // f16 partial overlays inside scratch
    unsigned short* part16 = (unsigned short*)part_f;      // GEMM partials (f16)
    unsigned short* po     = (unsigned short*)part_f;      // flash O partials (f16, 4M)
    float* pmv = part_f + 4194304 / 2 + 65536;             // after po (8MB = 2M floats)
    float* plv = pmv + 65536;

    unsigned short* ub = (unsigned short*)(ws + 17 * SD + 8512);
    unsigned short* xb   = ub;                       // 1024*512 (f16)
    unsigned short* aob  = xb   + 524288;
    unsigned short* qb2  = aob  + 524288;            // 8*1024*128 (2-seg)
    unsigned short* kb2  = qb2  + 1048576;
    unsigned short* vtb  = kb2  + 1048576;           // 512*1024 (f16)
    unsigned short* hb   = vtb  + 524288;            // 1024*2048
    unsigned short* qwb  = hb   + 2097152;           // 2 x 512*512
    unsigned short* kwb  = qwb  + 524288;
    unsigned short* vwb  = kwb  + 524288;
    unsigned short* owb  = vwb  + 524288;
    unsigned short* f1wb = owb  + 524288;            // 2 x 2048*512
    unsigned short* f2wb = f1wb + 2097152;           // 2 x 512*2048
    unsigned short* bmap = f2wb + 2097152;           // 8*1024*1024 f16

    input_pe_k<<<kS, 256, 0, stream>>>(features, positions, fb, in_w, in_b, x);
    dist_k<<<kS, 256, 0, stream>>>(positions, dist);
    pwl_sort_k<<<2, 128, 0, stream>>>(db1w, db1b, bpw);
    pwl_tab_k<<<dim3(129, 2), 256, 0, stream>>>(db1w, db1b, db2w, db2b, bpw, Atab, Btab);
    tof16_k<<<512, 256, 0, stream>>>(x, xb, 524288);

    trw_f16_k<<<dim3(16, 16, 2), 256, 0, stream>>>(qw, qwb, 512, 512, 262144, 262144);
    trw_f16_k<<<dim3(16, 16, 2), 256, 0, stream>>>(kw, kwb, 512, 512, 262144, 262144);
    trw_f16_k<<<dim3(16, 16, 2), 256, 0, stream>>>(vw, vwb, 512, 512, 262144, 262144);
    trw_f16_k<<<dim3(16, 16, 2), 256, 0, stream>>>(ow, owb, 512, 512, 262144, 262144);
    trw_f16_k<<<dim3(16, 64, 2), 256, 0, stream>>>(f1w, f1wb, 512, 2048, 1048576, 1048576);
    trw_f16_k<<<dim3(64, 16, 2), 256, 0, stream>>>(f2w, f2wb, 2048, 512, 1048576, 1048576);

    for (int l = 0; l < 2; ++l) {
        biasmap_k<<<1024, 256, 0, stream>>>(
            dist, bpw + l * 128, Atab + l * 1040, Btab + l * 1040, bmap);

        // QKV: A=xb (1024x512 f16), split-K x2 (384 blocks), f16 partials
        bgemm_k<<<dim3(16, 4, 6), 256, 0, stream>>>(
            xb, qwb + l * 262144, kwb + l * 262144, vwb + l * 262144,
            1024, 512, 256, 512, 512, 0, 2, part16);
        reduce_qkv_k<<<dim3(512, 3), 256, 0, stream>>>(
            part16, qb2, kb2, v, qb + l * kD, kb + l * kD, vb + l * kD, 2);
        tr_f16_k<<<dim3(32, 16), 256, 0, stream>>>(v, vtb, 1024, 512, 1024.f);

        // fused attention (Q 2-seg kept for accuracy), f16 O-partials
        flash_part_k<<<dim3(64, 8, 8), 64, 0, stream>>>(
            qb2, kb2, vtb, bmap, po, pmv, plv);
        flash_merge_k<<<256, 256, 0, stream>>>(po, pmv, plv, aob);

        // O-proj: K=512, split-K x4 (256 blocks); reduce fused into add_ln
        bgemm_k<<<dim3(16, 4, 4), 256, 0, stream>>>(
            aob, owb + l * 262144, owb + l * 262144, owb + l * 262144,
            1024, 512, 128, 512, 512, 0, 4, part16);
        add_ln_fused_k<<<kS, 256, 0, stream>>>(
            part16, x, ob + l * kD, n1g + l * kD, n1b + l * kD, xb, 4);

        // FFN1: K=512, split-K x2 (512 blocks), f16 partials -> hb f16
        bgemm_k<<<dim3(16, 16, 2), 256, 0, stream>>>(
            xb, f1wb + l * 1048576, f1wb + l * 1048576, f1wb + l * 1048576,
            1024, 2048, 256, 512, 512, 0, 2, part16);
        reduce3_k<<<2048, 256, 0, stream>>>(part16, hb, f1b + l * kDFF, 2);

        // FFN2: K=2048, split-K x4 (256 blocks); reduce fused into add_ln
        bgemm_k<<<dim3(16, 4, 4), 256, 0, stream>>>(
            hb, f2wb + l * 1048576, f2wb + l * 1048576, f2wb + l * 1048576,
            1024, 512, 512, 2048, 2048, 0, 4, part16);
        add_ln_fused_k<<<kS, 256, 0, stream>>>(
            part16, x, f2b + l * kD, n2g + l * kD, n2b + l * kD, xb, 4);
    }

    pool_k<<<dim3(2, 8), 256, 0, stream>>>(x, partial);
    head_k<<<1, 256, 0, stream>>>(partial, c1w, c1b, c2w, c2b, (float*)d_out);
}